// Round 4
// baseline (526.914 us; speedup 1.0000x reference)
//
#include <hip/hip_runtime.h>
#include <cstdint>
#include <cstddef>

// ---------- types ----------
typedef __attribute__((ext_vector_type(8))) __bf16 bf8_t;   // MFMA A/B frag (4 VGPR)
typedef __attribute__((ext_vector_type(8))) short s8_t;     // 16B raw copy
typedef __attribute__((ext_vector_type(4))) short s4_t;     // 8B raw
typedef __attribute__((ext_vector_type(4))) float f4_t;     // MFMA C/D frag

__device__ __forceinline__ float bf2f(unsigned short h) {
  union { unsigned u; float f; } v; v.u = (unsigned)h << 16; return v.f;
}
__device__ __forceinline__ unsigned short f2bf(float f) {
  union { float f; unsigned u; } v; v.f = f;
  return (unsigned short)((v.u + 0x7FFFu + ((v.u >> 16) & 1u)) >> 16);
}

#define GL16(gp, lp) __builtin_amdgcn_global_load_lds( \
    (__attribute__((address_space(1))) void*)(gp),     \
    (__attribute__((address_space(3))) void*)(lp), 16, 0, 0)

#define WAITV(N) do { asm volatile("s_waitcnt vmcnt(" #N ")" ::: "memory"); \
                      __builtin_amdgcn_sched_barrier(0); } while (0)
#define BAR() do { __builtin_amdgcn_s_barrier(); \
                   __builtin_amdgcn_sched_barrier(0); } while (0)

// ---------- fp32 -> bf16 conversion ----------
__global__ void k_f32_to_bf16(const float* __restrict__ in,
                              unsigned short* __restrict__ out, int n4) {
  int i = blockIdx.x * blockDim.x + threadIdx.x;
  if (i >= n4) return;
  float4 v = reinterpret_cast<const float4*>(in)[i];
  s4_t o;
  o.x = (short)f2bf(v.x); o.y = (short)f2bf(v.y);
  o.z = (short)f2bf(v.z); o.w = (short)f2bf(v.w);
  reinterpret_cast<s4_t*>(out)[i] = o;
}

// ---------- RoPE cos/sin table ----------
__global__ void k_rope_table(float* __restrict__ cosT, float* __restrict__ sinT) {
  int t = blockIdx.x, d = threadIdx.x;            // 1024 x 64
  float inv = exp2f(-(float)d * (13.287712379549449f / 64.0f)); // 10000^(-d/64)
  float ang = (float)t * inv;
  cosT[t * 64 + d] = cosf(ang);
  sinT[t * 64 + d] = sinf(ang);
}

// ---------- LoRA u = X @ dA^T via MFMA (u: [B][4][16][1024] f32) ----------
__global__ __launch_bounds__(256) void k_lora_mfma(
    const unsigned short* __restrict__ X,    // (B,1024,2048) bf16
    const unsigned short* __restrict__ dlb,  // (B,128,2048) bf16
    float* __restrict__ u, int pstart, int pcount) {
  __shared__ __align__(16) unsigned short Xs[64 * 64];
  __shared__ __align__(16) unsigned short Da[64 * 64];
  const int t = threadIdx.x;
  const int b = blockIdx.y;
  const int m0 = blockIdx.x * 64;
  const int w = t >> 6, lane = t & 63, lr = lane & 15, lg = lane >> 4;
  const int nrow = pcount * 16;
  f4_t acc[4] = {};
  for (int k0 = 0; k0 < 2048; k0 += 64) {
    __syncthreads();
#pragma unroll
    for (int i = 0; i < 2; ++i) {
      int idx = i * 256 + t;
      int row = idx >> 3, c = idx & 7;
      GL16(X + ((size_t)b * 1024 + m0 + row) * 2048 + k0 + ((c ^ (row & 7)) * 8),
           Xs + (size_t)idx * 8);
      int ric = row < nrow ? row : nrow - 1;
      int g = (pstart + (ric >> 4)) * 32 + (ric & 15);
      GL16(dlb + ((size_t)b * 128 + g) * 2048 + k0 + ((c ^ (ric & 7)) * 8),
           Da + (size_t)idx * 8);
    }
    __syncthreads();
#pragma unroll
    for (int kk = 0; kk < 2; ++kk) {
      bf8_t af = *(const bf8_t*)&Xs[(w * 16 + lr) * 64 + (((kk * 4 + lg) ^ (lr & 7)) * 8)];
#pragma unroll
      for (int n = 0; n < 4; ++n) {
        if (n < pcount) {
          bf8_t bfv = *(const bf8_t*)&Da[(n * 16 + lr) * 64 + (((kk * 4 + lg) ^ (lr & 7)) * 8)];
          acc[n] = __builtin_amdgcn_mfma_f32_16x16x32_bf16(af, bfv, acc[n], 0, 0, 0);
        }
      }
    }
  }
#pragma unroll
  for (int n = 0; n < 4; ++n) {
    if (n < pcount) {
#pragma unroll
      for (int j = 0; j < 4; ++j)
        u[(((size_t)b * 4 + pstart + n) * 16 + lr) * 1024 + m0 + w * 16 + lg * 4 + j] = acc[n][j];
    }
  }
}

// ---------- 256x256 8-phase bf16 GEMM (T2+T3+T4+T5) + LoRA epilogue ----------
// A:(4096,2048) bf16 K-major. Weights: NxK bf16. K=2048 -> 32 K-tiles of 64.
// fused=1: N=6144 over {W0,W1,W2}, z=n0>>11, modes {0,0,1}, p=z.
// fused=0: N=2048, W0 only, mode 2 (f32 out), p=3.
struct G8 {
  const unsigned short *W0, *W1, *W2;
  void *o0, *o1, *o2;
  int n_nt, fused;
};

__global__ __launch_bounds__(512, 2) void k_gemm8(
    const unsigned short* __restrict__ Ag, G8 ga,
    const float* __restrict__ u, const float* __restrict__ dl) {
  __shared__ unsigned short Ab[2][256 * 64];   // 64 KB
  __shared__ unsigned short Bb[2][256 * 64];   // 64 KB
  const int t = threadIdx.x;
  const int w = t >> 6, l = t & 63;
  const int lr = l & 15, lg = l >> 4;
  const int wm = w >> 2, wn = w & 3;

  const int nwg = 16 * ga.n_nt;
  const int wg = ((int)blockIdx.x & 7) * (nwg >> 3) + ((int)blockIdx.x >> 3);
  const int m0 = (wg / ga.n_nt) * 256;
  const int n0 = (wg % ga.n_nt) * 256;
  const int z = n0 >> 11;
  const unsigned short* Bg;
  void* ov;
  int mode, p, n0i;
  if (ga.fused) {
    Bg = z == 0 ? ga.W0 : (z == 1 ? ga.W1 : ga.W2);
    ov = z == 0 ? ga.o0 : (z == 1 ? ga.o1 : ga.o2);
    mode = (z == 2) ? 1 : 0; p = z; n0i = n0 & 2047;
  } else {
    Bg = ga.W0; ov = ga.o0; mode = 2; p = 3; n0i = n0;
  }

  f4_t acc[8][4] = {};

// stage one 16KB chunk (2 issues/thread). A chunk par: rows {par*64.., par*64+128..}
#define STAGE_A(tt, par, c) do { \
  const int k0_ = (tt) * 64; \
  _Pragma("unroll") for (int rr = 0; rr < 2; ++rr) { \
    int row_ = (par) * 64 + rr * 128 + w * 8 + (l >> 3); \
    int col_ = ((l & 7) * 8) ^ ((row_ & 4) ? 16 : 0); \
    GL16(Ag + (size_t)(m0 + row_) * 2048 + k0_ + col_, \
         &Ab[c][row_ * 64 + (l & 7) * 8]); \
  } } while (0)

// B chunk par: rows {par*32 + {0,64,128,192}..+32}
#define STAGE_B(tt, par, c) do { \
  const int k0_ = (tt) * 64; \
  _Pragma("unroll") for (int rr = 0; rr < 2; ++rr) { \
    int row_ = (par) * 32 + (w & 3) * 8 + (w >> 2) * 64 + rr * 128 + (l >> 3); \
    int col_ = ((l & 7) * 8) ^ ((row_ & 4) ? 16 : 0); \
    GL16(Bg + (size_t)(n0i + row_) * 2048 + k0_ + col_, \
         &Bb[c][row_ * 64 + (l & 7) * 8]); \
  } } while (0)

// one C-quadrant (mh,nh) x K=64: 12 ds_read_b128 + 16 MFMA
#define QUAD(c, mh, nh) do { \
  const int kc_ = (lr & 4) ? 16 : 0; \
  bf8_t af_[4][2], bf_[2][2]; \
  _Pragma("unroll") for (int i = 0; i < 4; ++i) { \
    int row_ = wm * 128 + (mh) * 64 + i * 16 + lr; \
    af_[i][0] = *(const bf8_t*)&Ab[c][row_ * 64 + ((lg * 8) ^ kc_)]; \
    af_[i][1] = *(const bf8_t*)&Ab[c][row_ * 64 + 32 + ((lg * 8) ^ kc_)]; \
  } \
  _Pragma("unroll") for (int j = 0; j < 2; ++j) { \
    int row_ = wn * 64 + (nh) * 32 + j * 16 + lr; \
    bf_[j][0] = *(const bf8_t*)&Bb[c][row_ * 64 + ((lg * 8) ^ kc_)]; \
    bf_[j][1] = *(const bf8_t*)&Bb[c][row_ * 64 + 32 + ((lg * 8) ^ kc_)]; \
  } \
  __builtin_amdgcn_s_setprio(1); \
  _Pragma("unroll") for (int kk = 0; kk < 2; ++kk) \
  _Pragma("unroll") for (int i = 0; i < 4; ++i) \
  _Pragma("unroll") for (int j = 0; j < 2; ++j) \
    acc[(mh)*4+i][(nh)*2+j] = __builtin_amdgcn_mfma_f32_16x16x32_bf16( \
        af_[i][kk], bf_[j][kk], acc[(mh)*4+i][(nh)*2+j], 0, 0, 0); \
  __builtin_amdgcn_s_setprio(0); \
} while (0)

  // prologue: queue order per tile = B0,A0,B1,A1; t0 full + t1 first half
  STAGE_B(0, 0, 0); STAGE_A(0, 0, 0); STAGE_B(0, 1, 0); STAGE_A(0, 1, 0);
  STAGE_B(1, 0, 1); STAGE_A(1, 0, 1);
  WAITV(8); BAR();

#pragma unroll 1
  for (int tt = 0; tt < 30; tt += 2) {
    // tile tt (buf 0)
    STAGE_B(tt + 1, 1, 1); QUAD(0, 0, 0); WAITV(6); BAR();
    STAGE_A(tt + 1, 1, 1); QUAD(0, 1, 0); BAR();
    STAGE_B(tt + 2, 0, 0); QUAD(0, 0, 1); BAR();
    STAGE_A(tt + 2, 0, 0); QUAD(0, 1, 1); WAITV(8); BAR();
    // tile tt+1 (buf 1)
    STAGE_B(tt + 2, 1, 0); QUAD(1, 0, 0); WAITV(6); BAR();
    STAGE_A(tt + 2, 1, 0); QUAD(1, 1, 0); BAR();
    STAGE_B(tt + 3, 0, 1); QUAD(1, 0, 1); BAR();
    STAGE_A(tt + 3, 0, 1); QUAD(1, 1, 1); WAITV(8); BAR();
  }
  // tile 30 (buf 0): only t31 second-half staging remains
  STAGE_B(31, 1, 1); QUAD(0, 0, 0); WAITV(6); BAR();
  STAGE_A(31, 1, 1); QUAD(0, 1, 0); BAR();
  QUAD(0, 0, 1); BAR();
  QUAD(0, 1, 1); WAITV(4); BAR();
  // tile 31 (buf 1): no staging
  QUAD(1, 0, 0); WAITV(0); BAR();
  QUAD(1, 1, 0); BAR();
  QUAD(1, 0, 1); BAR();
  QUAD(1, 1, 1); BAR();

  // ---- LoRA rank-16 epilogue: one zero-padded K=32 MFMA step ----
  const int b = m0 >> 10;
  const int t0r = m0 & 1023;
  {
    int row = t >> 1, cb = (t & 1) * 16;
    s8_t v0, v1;
#pragma unroll
    for (int r = 0; r < 8; ++r) {
      int cc = cb + r;
      v0[r] = (short)((cc < 16) ? f2bf(u[(((size_t)b * 4 + p) * 16 + cc) * 1024 + t0r + row]) : 0);
    }
#pragma unroll
    for (int r = 0; r < 8; ++r) {
      int cc = cb + 8 + r;
      v1[r] = (short)((cc < 16) ? f2bf(u[(((size_t)b * 4 + p) * 16 + cc) * 1024 + t0r + row]) : 0);
    }
    *(s8_t*)&Ab[0][row * 32 + cb] = v0;
    *(s8_t*)&Ab[0][row * 32 + cb + 8] = v1;
    s8_t w0, w1;
#pragma unroll
    for (int r = 0; r < 8; ++r) {
      int cc = cb + r;
      w0[r] = (short)((cc < 16) ? f2bf(dl[((size_t)b * 128 + p * 32 + 16 + cc) * 2048 + n0i + row]) : 0);
    }
#pragma unroll
    for (int r = 0; r < 8; ++r) {
      int cc = cb + 8 + r;
      w1[r] = (short)((cc < 16) ? f2bf(dl[((size_t)b * 128 + p * 32 + 16 + cc) * 2048 + n0i + row]) : 0);
    }
    *(s8_t*)&Bb[0][row * 32 + cb] = w0;
    *(s8_t*)&Bb[0][row * 32 + cb + 8] = w1;
  }
  __syncthreads();
  {
    bf8_t afl[8], bfl[4];
#pragma unroll
    for (int i = 0; i < 8; ++i)
      afl[i] = *(const bf8_t*)&Ab[0][(wm * 128 + i * 16 + lr) * 32 + lg * 8];
#pragma unroll
    for (int j = 0; j < 4; ++j)
      bfl[j] = *(const bf8_t*)&Bb[0][(wn * 64 + j * 16 + lr) * 32 + lg * 8];
#pragma unroll
    for (int i = 0; i < 8; ++i)
#pragma unroll
      for (int j = 0; j < 4; ++j)
        acc[i][j] = __builtin_amdgcn_mfma_f32_16x16x32_bf16(afl[i], bfl[j], acc[i][j], 0, 0, 0);
  }

  // ---- write C (C/D map: col = lane&15, row = (lane>>4)*4 + reg) ----
  unsigned short* out16 = (unsigned short*)ov;
  float* out32 = (float*)ov;
#pragma unroll
  for (int i = 0; i < 8; ++i) {
    int ri = wm * 128 + i * 16 + lg * 4;
#pragma unroll
    for (int j = 0; j < 4; ++j) {
      int grow = m0 + ri + j;
      int gb = grow >> 10, gt = grow & 1023;
#pragma unroll
      for (int n = 0; n < 4; ++n) {
        int gc = n0i + wn * 64 + n * 16 + lr;
        float fv = acc[i][n][j];
        if (mode == 0) {
          size_t dst = (((size_t)gb * 16 + (gc >> 7)) * 1024 + gt) * 128 + (gc & 127);
          out16[dst] = f2bf(fv);
        } else if (mode == 1) {
          size_t dst = (((size_t)gb * 16 + (gc >> 7)) * 128 + (gc & 127)) * 1024 + gt;
          out16[dst] = f2bf(fv);
        } else {
          out32[(size_t)grow * 2048 + gc] = fv;
        }
      }
    }
  }
#undef STAGE_A
#undef STAGE_B
#undef QUAD
}

// ---------- in-place RoPE on (B,H,T,128) bf16 ----------
__global__ void k_rope(unsigned short* __restrict__ X,
                       const float* __restrict__ cosT, const float* __restrict__ sinT) {
  int idx = blockIdx.x * 256 + threadIdx.x;     // B*H*T*8 = 524288
  int d0 = (idx & 7) * 8;
  int tt = (idx >> 3) & 1023;
  size_t base = (size_t)(idx >> 3) * 128 + d0;
  s8_t a = *(s8_t*)&X[base];
  s8_t bb = *(s8_t*)&X[base + 64];
  float4 c0 = *(const float4*)&cosT[tt * 64 + d0];
  float4 c1 = *(const float4*)&cosT[tt * 64 + d0 + 4];
  float4 sv0 = *(const float4*)&sinT[tt * 64 + d0];
  float4 sv1 = *(const float4*)&sinT[tt * 64 + d0 + 4];
  float cv[8] = {c0.x, c0.y, c0.z, c0.w, c1.x, c1.y, c1.z, c1.w};
  float sw[8] = {sv0.x, sv0.y, sv0.z, sv0.w, sv1.x, sv1.y, sv1.z, sv1.w};
  s8_t ra, rb;
#pragma unroll
  for (int j = 0; j < 8; ++j) {
    float av = bf2f((unsigned short)a[j]);
    float bv = bf2f((unsigned short)bb[j]);
    ra[j] = (short)f2bf(av * cv[j] - bv * sw[j]);
    rb[j] = (short)f2bf(bv * cv[j] + av * sw[j]);
  }
  *(s8_t*)&X[base] = ra;
  *(s8_t*)&X[base + 64] = rb;
}

// ---------- fused attention: LDS-staged K/V, 8 waves, online softmax ----------
__global__ __launch_bounds__(512, 4) void k_attn(
    const unsigned short* __restrict__ Qg,
    const unsigned short* __restrict__ Kg,
    const unsigned short* __restrict__ Vt,
    unsigned short* __restrict__ Y) {
  const float scale = 0.08838834764831845f;  // 1/sqrt(128)
  const float L2E = 1.4426950408889634f;
  const int bid = blockIdx.x;
  const int wg = (bid & 7) * 64 + (bid >> 3);   // bijective, 8 XCD chunks of 64
  const int bh = wg >> 3;
  const int b = bh >> 4, h = bh & 15;
  const int t = threadIdx.x;
  const int w = t >> 6, lane = t & 63;
  const int lr = lane & 15, lg = lane >> 4;
  const int q0 = (wg & 7) * 128 + w * 16;
  const unsigned short* Q  = Qg + (size_t)bh * 131072;
  const unsigned short* Kp = Kg + (size_t)bh * 131072;
  const unsigned short* Vp = Vt + (size_t)bh * 131072;
  __shared__ __align__(16) unsigned short Ks[64 * 128];
  __shared__ __align__(16) unsigned short Vs[128 * 64];
  __shared__ __align__(16) unsigned short Ps[8][16 * 80];
  unsigned short* Pw = Ps[w];

  bf8_t qf[4];
#pragma unroll
  for (int kk = 0; kk < 4; ++kk)
    qf[kk] = *(const bf8_t*)&Q[(size_t)(q0 + lr) * 128 + kk * 32 + lg * 8];

  f4_t o[8] = {};
  float m_run = -1e30f, l_run = 0.0f;

  for (int s0 = 0; s0 < 1024; s0 += 64) {
    __syncthreads();
#pragma unroll
    for (int i = 0; i < 2; ++i) {          // K tile: [64 s][128 d]
      int idx = i * 512 + t;
      int s = idx >> 4, c = t & 15;
      GL16(Kp + (size_t)(s0 + s) * 128 + ((c ^ (s & 7)) * 8), Ks + (size_t)idx * 8);
    }
#pragma unroll
    for (int i = 0; i < 2; ++i) {          // V tile: [128 d][64 s]
      int idx = i * 512 + t;
      int d = idx >> 3, c = t & 7;
      GL16(Vp + (size_t)d * 1024 + s0 + ((c ^ (d & 7)) * 8), Vs + (size_t)idx * 8);
    }
    __syncthreads();

    f4_t sf[4];
#pragma unroll
    for (int ss = 0; ss < 4; ++ss) {
      f4_t c = {0.0f, 0.0f, 0.0f, 0.0f};
#pragma unroll
      for (int kk = 0; kk < 4; ++kk) {
        bf8_t kf = *(const bf8_t*)&Ks[(ss * 16 + lr) * 128 + (((kk * 4 + lg) ^ (lr & 7)) * 8)];
        c = __builtin_amdgcn_mfma_f32_16x16x32_bf16(kf, qf[kk], c, 0, 0, 0);
      }
      sf[ss] = c;
    }
    float vmax = -1e30f;
#pragma unroll
    for (int ss = 0; ss < 4; ++ss)
#pragma unroll
      for (int j = 0; j < 4; ++j) vmax = fmaxf(vmax, sf[ss][j]);
    vmax = fmaxf(vmax, __shfl_xor(vmax, 16));
    vmax = fmaxf(vmax, __shfl_xor(vmax, 32));
    float m_new = fmaxf(m_run, vmax * scale);
    float ratio = exp2f((m_run - m_new) * L2E);
    float lsum = 0.0f;
    float ps[4][4];
#pragma unroll
    for (int ss = 0; ss < 4; ++ss)
#pragma unroll
      for (int j = 0; j < 4; ++j) {
        float pv = exp2f((sf[ss][j] * scale - m_new) * L2E);
        ps[ss][j] = pv; lsum += pv;
      }
    lsum += __shfl_xor(lsum, 16);
    lsum += __shfl_xor(lsum, 32);
    l_run = l_run * ratio + lsum;
    m_run = m_new;
    float rq[4];
#pragma unroll
    for (int j = 0; j < 4; ++j) rq[j] = __shfl(ratio, lg * 4 + j);
#pragma unroll
    for (int n = 0; n < 8; ++n)
#pragma unroll
      for (int j = 0; j < 4; ++j) o[n][j] *= rq[j];
#pragma unroll
    for (int ss = 0; ss < 4; ++ss) {
      s4_t pk;
      pk.x = (short)f2bf(ps[ss][0]); pk.y = (short)f2bf(ps[ss][1]);
      pk.z = (short)f2bf(ps[ss][2]); pk.w = (short)f2bf(ps[ss][3]);
      *(s4_t*)&Pw[lr * 80 + ss * 16 + lg * 4] = pk;
    }
    bf8_t pa0 = *(const bf8_t*)&Pw[lr * 80 + lg * 8];
    bf8_t pa1 = *(const bf8_t*)&Pw[lr * 80 + 32 + lg * 8];
#pragma unroll
    for (int n = 0; n < 8; ++n) {
      int d = n * 16 + lr;
      bf8_t v0 = *(const bf8_t*)&Vs[d * 64 + (((0 + lg) ^ (lr & 7)) * 8)];
      bf8_t v1 = *(const bf8_t*)&Vs[d * 64 + (((4 + lg) ^ (lr & 7)) * 8)];
      o[n] = __builtin_amdgcn_mfma_f32_16x16x32_bf16(pa0, v0, o[n], 0, 0, 0);
      o[n] = __builtin_amdgcn_mfma_f32_16x16x32_bf16(pa1, v1, o[n], 0, 0, 0);
    }
  }

  float linv[4];
#pragma unroll
  for (int j = 0; j < 4; ++j) linv[j] = 1.0f / __shfl(l_run, lg * 4 + j);
#pragma unroll
  for (int n = 0; n < 8; ++n)
#pragma unroll
    for (int j = 0; j < 4; ++j) {
      int qg = q0 + lg * 4 + j;
      Y[((size_t)b * 1024 + qg) * 2048 + h * 128 + n * 16 + lr] =
          f2bf(o[n][j] * linv[j]);
    }
}

// ---------- launch ----------
extern "C" void kernel_launch(void* const* d_in, const int* in_sizes, int n_in,
                              void* d_out, int out_size, void* d_ws, size_t ws_size,
                              hipStream_t stream) {
  const float* x  = (const float*)d_in[0];
  const float* dl = (const float*)d_in[1];
  const float* W[4] = {(const float*)d_in[2], (const float*)d_in[3],
                       (const float*)d_in[4], (const float*)d_in[5]};
  char* ws = (char*)d_ws;
  size_t off = 0;
  auto take = [&](size_t bytes) {
    void* p = ws + off; off += (bytes + 255) & ~(size_t)255; return p;
  };
  unsigned short* xb = (unsigned short*)take(8388608ull * 2);
  unsigned short* Wb[4];
  for (int i = 0; i < 4; ++i) Wb[i] = (unsigned short*)take(4194304ull * 2);
  unsigned short* qb = (unsigned short*)take(8388608ull * 2);
  unsigned short* kb = (unsigned short*)take(8388608ull * 2);
  unsigned short* vT = (unsigned short*)take(8388608ull * 2);
  unsigned short* y  = (unsigned short*)take(8388608ull * 2);
  float* u    = (float*)take(4ull * 4 * 16 * 1024 * 4);
  float* cosT = (float*)take(1024ull * 64 * 4);
  float* sinT = (float*)take(1024ull * 64 * 4);
  unsigned short* dlb = (unsigned short*)take(1048576ull * 2);
  if (off > ws_size) return;

  k_f32_to_bf16<<<8192, 256, 0, stream>>>(x, xb, 2097152);
  for (int i = 0; i < 4; ++i)
    k_f32_to_bf16<<<4096, 256, 0, stream>>>(W[i], Wb[i], 1048576);
  k_f32_to_bf16<<<1024, 256, 0, stream>>>(dl, dlb, 262144);
  k_rope_table<<<1024, 64, 0, stream>>>(cosT, sinT);
  k_lora_mfma<<<dim3(16, 4), 256, 0, stream>>>(xb, dlb, u, 0, 3);

  G8 gq;
  gq.W0 = Wb[0]; gq.W1 = Wb[1]; gq.W2 = Wb[2];
  gq.o0 = qb;    gq.o1 = kb;    gq.o2 = vT;
  gq.n_nt = 24;  gq.fused = 1;
  k_gemm8<<<384, 512, 0, stream>>>(xb, gq, u, dl);

  k_rope<<<2048, 256, 0, stream>>>(qb, cosT, sinT);
  k_rope<<<2048, 256, 0, stream>>>(kb, cosT, sinT);
  k_attn<<<512, 512, 0, stream>>>(qb, kb, vT, y);
  k_lora_mfma<<<dim3(16, 4), 256, 0, stream>>>(y, dlb, u, 3, 1);

  G8 go;
  go.W0 = Wb[3]; go.W1 = Wb[3]; go.W2 = Wb[3];
  go.o0 = d_out; go.o1 = d_out; go.o2 = d_out;
  go.n_nt = 8;   go.fused = 0;
  k_gemm8<<<128, 512, 0, stream>>>(y, go, u, dl);
}

// Round 6
// 446.878 us; speedup vs baseline: 1.1791x; 1.1791x over previous
//
#include <hip/hip_runtime.h>
#include <cstdint>
#include <cstddef>

// ---------- types ----------
typedef __attribute__((ext_vector_type(8))) __bf16 bf8_t;
typedef __attribute__((ext_vector_type(8))) short s8_t;
typedef __attribute__((ext_vector_type(4))) short s4_t;
typedef __attribute__((ext_vector_type(4))) float f4_t;

__device__ __forceinline__ float bf2f(unsigned short h) {
  union { unsigned u; float f; } v; v.u = (unsigned)h << 16; return v.f;
}
__device__ __forceinline__ unsigned short f2bf(float f) {
  union { float f; unsigned u; } v; v.f = f;
  return (unsigned short)((v.u + 0x7FFFu + ((v.u >> 16) & 1u)) >> 16);
}

#define GL16(gp, lp) __builtin_amdgcn_global_load_lds( \
    (__attribute__((address_space(1))) void*)(gp),     \
    (__attribute__((address_space(3))) void*)(lp), 16, 0, 0)

// ---------- fp32 -> bf16 conversion ----------
__global__ void k_f32_to_bf16(const float* __restrict__ in,
                              unsigned short* __restrict__ out, int n4) {
  int i = blockIdx.x * blockDim.x + threadIdx.x;
  if (i >= n4) return;
  float4 v = reinterpret_cast<const float4*>(in)[i];
  s4_t o;
  o.x = (short)f2bf(v.x); o.y = (short)f2bf(v.y);
  o.z = (short)f2bf(v.z); o.w = (short)f2bf(v.w);
  reinterpret_cast<s4_t*>(out)[i] = o;
}

// ---------- RoPE cos/sin table ----------
__global__ void k_rope_table(float* __restrict__ cosT, float* __restrict__ sinT) {
  int t = blockIdx.x, d = threadIdx.x;            // 1024 x 64
  float inv = exp2f(-(float)d * (13.287712379549449f / 64.0f));
  float ang = (float)t * inv;
  cosT[t * 64 + d] = cosf(ang);
  sinT[t * 64 + d] = sinf(ang);
}

// ---------- LoRA u = X @ dA^T via MFMA (u: [B][4][16][1024] f32) ----------
__global__ __launch_bounds__(256) void k_lora_mfma(
    const unsigned short* __restrict__ X,
    const unsigned short* __restrict__ dlb,
    float* __restrict__ u, int pstart, int pcount) {
  __shared__ __align__(16) unsigned short Xs[64 * 64];
  __shared__ __align__(16) unsigned short Da[64 * 64];
  const int t = threadIdx.x;
  const int b = blockIdx.y;
  const int m0 = blockIdx.x * 64;
  const int w = t >> 6, lane = t & 63, lr = lane & 15, lg = lane >> 4;
  const int nrow = pcount * 16;
  f4_t acc[4] = {};
  for (int k0 = 0; k0 < 2048; k0 += 64) {
    __syncthreads();
#pragma unroll
    for (int i = 0; i < 2; ++i) {
      int idx = i * 256 + t;
      int row = idx >> 3, c = idx & 7;
      GL16(X + ((size_t)b * 1024 + m0 + row) * 2048 + k0 + ((c ^ (row & 7)) * 8),
           Xs + (size_t)idx * 8);
      int ric = row < nrow ? row : nrow - 1;
      int g = (pstart + (ric >> 4)) * 32 + (ric & 15);
      GL16(dlb + ((size_t)b * 128 + g) * 2048 + k0 + ((c ^ (ric & 7)) * 8),
           Da + (size_t)idx * 8);
    }
    __syncthreads();
#pragma unroll
    for (int kk = 0; kk < 2; ++kk) {
      bf8_t af = *(const bf8_t*)&Xs[(w * 16 + lr) * 64 + (((kk * 4 + lg) ^ (lr & 7)) * 8)];
#pragma unroll
      for (int n = 0; n < 4; ++n) {
        if (n < pcount) {
          bf8_t bfv = *(const bf8_t*)&Da[(n * 16 + lr) * 64 + (((kk * 4 + lg) ^ (lr & 7)) * 8)];
          acc[n] = __builtin_amdgcn_mfma_f32_16x16x32_bf16(af, bfv, acc[n], 0, 0, 0);
        }
      }
    }
  }
#pragma unroll
  for (int n = 0; n < 4; ++n) {
    if (n < pcount) {
#pragma unroll
      for (int j = 0; j < 4; ++j)
        u[(((size_t)b * 4 + pstart + n) * 16 + lr) * 1024 + m0 + w * 16 + lg * 4 + j] = acc[n][j];
    }
  }
}

// ---------- 256x256 8-phase bf16 GEMM + LoRA epilogue ----------
// Slots: half h of K-tile tt -> slot (2*tt+h)&3. Quad order (0,0),(0,1),(1,0),(1,1).
// Last reads: A0@E2 B0@E3 A1@E4 B1@E4 A2@O2 B2@O3 A3@O4 B3@O4.
// Stages (one per phase, strictly after slot death):
//   E1:A(t+1)h1->A3  E2:B(t+1)h1->B3  E3:A(t+2)h0->A0  E4:B(t+2)h0->B0 [vm4]
//   O1:A(t+2)h1->A1  O2:B(t+2)h1->B1  O3:A(t+3)h0->A2  O4:B(t+3)h0->B2 [vm4]
// vmcnt(4)@E4 covers odd-tile slots; vmcnt(4)@O4 covers next even-tile slots.
struct G8 {
  const unsigned short *W0, *W1, *W2;
  void *o0, *o1, *o2;
  int n_nt, fused;
};

__global__ __launch_bounds__(512, 2) void k_gemm8(
    const unsigned short* __restrict__ Ag, G8 ga,
    const float* __restrict__ u, const float* __restrict__ dl) {
  __shared__ unsigned short As[4][128 * 64];   // 64 KB (4 slots)
  __shared__ unsigned short Bs[4][128 * 64];   // 64 KB
  const int t = threadIdx.x;
  const int w = t >> 6, l = t & 63;
  const int lr = l & 15, lg = l >> 4;
  const int wm = w >> 2, wn = w & 3;

  const int nwg = 16 * ga.n_nt;
  const int wg = ((int)blockIdx.x & 7) * (nwg >> 3) + ((int)blockIdx.x >> 3);
  const int m0 = (wg / ga.n_nt) * 256;
  const int n0 = (wg % ga.n_nt) * 256;
  const int z = n0 >> 11;
  const unsigned short* Bg;
  void* ov;
  int mode, p, n0i;
  if (ga.fused) {
    Bg = z == 0 ? ga.W0 : (z == 1 ? ga.W1 : ga.W2);
    ov = z == 0 ? ga.o0 : (z == 1 ? ga.o1 : ga.o2);
    mode = (z == 2) ? 1 : 0; p = z; n0i = n0 & 2047;
  } else {
    Bg = ga.W0; ov = ga.o0; mode = 2; p = 3; n0i = n0;
  }

  f4_t acc[8][4] = {};

#define STAGE_A(tt, hh, slot) do { \
  const int k0_ = (tt) * 64; \
  _Pragma("unroll") for (int rr_ = 0; rr_ < 2; ++rr_) { \
    int q_ = t >> 3; \
    int grow_ = (hh) * 64 + q_ + rr_ * 128; \
    int csrc_ = ((t & 7) ^ (q_ & 7)) * 8; \
    GL16(Ag + (size_t)(m0 + grow_) * 2048 + k0_ + csrc_, \
         &As[slot][rr_ * 4096 + t * 8]); \
  } } while (0)

#define STAGE_B(tt, hh, slot) do { \
  const int k0_ = (tt) * 64; \
  _Pragma("unroll") for (int rr_ = 0; rr_ < 2; ++rr_) { \
    int q_ = t >> 3; \
    int grow_ = (hh) * 32 + (q_ & 31) + (rr_ * 2 + (q_ >> 5)) * 64; \
    int csrc_ = ((t & 7) ^ (q_ & 7)) * 8; \
    GL16(Bg + (size_t)(n0i + grow_) * 2048 + k0_ + csrc_, \
         &Bs[slot][rr_ * 4096 + t * 8]); \
  } } while (0)

#define VM4 asm volatile("s_waitcnt vmcnt(4)" ::: "memory")
#define VM0 asm volatile("s_waitcnt vmcnt(0)" ::: "memory")
#define NOSTAGE (void)0

// phase: ds_read(12) ; stage ; lgkmcnt(8) ; barrier ; lgkmcnt(0) ;
//        setprio(1) MFMA x16 setprio(0) ; [vmcnt] ; barrier ; sched_fence
#define PHASE(sA, sB, mh, nh, STAGE_STMT, VMSTMT) do { \
  bf8_t af_[4][2], bf_[2][2]; \
  _Pragma("unroll") for (int i = 0; i < 4; ++i) { \
    int lrow_ = wm * 64 + i * 16 + lr; \
    af_[i][0] = *(const bf8_t*)&As[sA][lrow_ * 64 + ((lg ^ (lr & 7)) * 8)]; \
    af_[i][1] = *(const bf8_t*)&As[sA][lrow_ * 64 + (((4 + lg) ^ (lr & 7)) * 8)]; \
  } \
  _Pragma("unroll") for (int j = 0; j < 2; ++j) { \
    int lrow_ = wn * 32 + j * 16 + lr; \
    bf_[j][0] = *(const bf8_t*)&Bs[sB][lrow_ * 64 + ((lg ^ (lr & 7)) * 8)]; \
    bf_[j][1] = *(const bf8_t*)&Bs[sB][lrow_ * 64 + (((4 + lg) ^ (lr & 7)) * 8)]; \
  } \
  STAGE_STMT; \
  asm volatile("s_waitcnt lgkmcnt(8)" ::: "memory"); \
  __builtin_amdgcn_s_barrier(); \
  asm volatile("s_waitcnt lgkmcnt(0)" ::: "memory"); \
  __builtin_amdgcn_sched_barrier(0); \
  __builtin_amdgcn_s_setprio(1); \
  _Pragma("unroll") for (int kk = 0; kk < 2; ++kk) \
  _Pragma("unroll") for (int i = 0; i < 4; ++i) \
  _Pragma("unroll") for (int j = 0; j < 2; ++j) \
    acc[(mh) * 4 + i][(nh) * 2 + j] = __builtin_amdgcn_mfma_f32_16x16x32_bf16( \
        af_[i][kk], bf_[j][kk], acc[(mh) * 4 + i][(nh) * 2 + j], 0, 0, 0); \
  __builtin_amdgcn_s_setprio(0); \
  VMSTMT; \
  __builtin_amdgcn_s_barrier(); \
  __builtin_amdgcn_sched_barrier(0); \
} while (0)

  // prologue: A(0)h0->A0, B(0)h0->B0, A(0)h1->A1, B(0)h1->B1, A(1)h0->A2, B(1)h0->B2
  STAGE_A(0, 0, 0); STAGE_B(0, 0, 0); STAGE_A(0, 1, 1); STAGE_B(0, 1, 1);
  STAGE_A(1, 0, 2); STAGE_B(1, 0, 2);
  VM4;                                   // tile 0 fully arrived
  __builtin_amdgcn_s_barrier();
  __builtin_amdgcn_sched_barrier(0);

#pragma unroll 1
  for (int tb = 0; tb < 30; tb += 2) {
    // even tile tb (A0,A1,B0,B1)
    PHASE(0, 0, 0, 0, STAGE_A(tb + 1, 1, 3), NOSTAGE);
    PHASE(0, 1, 0, 1, STAGE_B(tb + 1, 1, 3), NOSTAGE);
    PHASE(1, 0, 1, 0, STAGE_A(tb + 2, 0, 0), NOSTAGE);
    PHASE(1, 1, 1, 1, STAGE_B(tb + 2, 0, 0), VM4);
    // odd tile tb+1 (A2,A3,B2,B3)
    PHASE(2, 2, 0, 0, STAGE_A(tb + 2, 1, 1), NOSTAGE);
    PHASE(2, 3, 0, 1, STAGE_B(tb + 2, 1, 1), NOSTAGE);
    PHASE(3, 2, 1, 0, STAGE_A(tb + 3, 0, 2), NOSTAGE);
    PHASE(3, 3, 1, 1, STAGE_B(tb + 3, 0, 2), VM4);
  }
  // last group: tiles 30,31
  PHASE(0, 0, 0, 0, STAGE_A(31, 1, 3), NOSTAGE);
  PHASE(0, 1, 0, 1, STAGE_B(31, 1, 3), NOSTAGE);
  PHASE(1, 0, 1, 0, NOSTAGE, NOSTAGE);
  PHASE(1, 1, 1, 1, NOSTAGE, VM0);
  PHASE(2, 2, 0, 0, NOSTAGE, NOSTAGE);
  PHASE(2, 3, 0, 1, NOSTAGE, NOSTAGE);
  PHASE(3, 2, 1, 0, NOSTAGE, NOSTAGE);
  PHASE(3, 3, 1, 1, NOSTAGE, NOSTAGE);

  __syncthreads();

  // ---- LoRA rank-16 epilogue: one zero-padded K=32 MFMA step ----
  unsigned short* LA = &As[0][0];   // 256 rows x 32
  unsigned short* LB = &Bs[0][0];
  const int b = m0 >> 10;
  const int t0r = m0 & 1023;
  {
    int row = t >> 1, cb = (t & 1) * 16;
    s8_t v0, v1;
#pragma unroll
    for (int r = 0; r < 8; ++r) {
      int cc = cb + r;
      v0[r] = (short)((cc < 16) ? f2bf(u[(((size_t)b * 4 + p) * 16 + cc) * 1024 + t0r + row]) : 0);
    }
#pragma unroll
    for (int r = 0; r < 8; ++r) {
      int cc = cb + 8 + r;
      v1[r] = (short)((cc < 16) ? f2bf(u[(((size_t)b * 4 + p) * 16 + cc) * 1024 + t0r + row]) : 0);
    }
    *(s8_t*)&LA[row * 32 + cb] = v0;
    *(s8_t*)&LA[row * 32 + cb + 8] = v1;
    s8_t w0, w1;
#pragma unroll
    for (int r = 0; r < 8; ++r) {
      int cc = cb + r;
      w0[r] = (short)((cc < 16) ? f2bf(dl[((size_t)b * 128 + p * 32 + 16 + cc) * 2048 + n0i + row]) : 0);
    }
#pragma unroll
    for (int r = 0; r < 8; ++r) {
      int cc = cb + 8 + r;
      w1[r] = (short)((cc < 16) ? f2bf(dl[((size_t)b * 128 + p * 32 + 16 + cc) * 2048 + n0i + row]) : 0);
    }
    *(s8_t*)&LB[row * 32 + cb] = w0;
    *(s8_t*)&LB[row * 32 + cb + 8] = w1;
  }
  __syncthreads();
  {
    bf8_t afl[8], bfl[4];
#pragma unroll
    for (int i = 0; i < 8; ++i)
      afl[i] = *(const bf8_t*)&LA[(wm * 128 + i * 16 + lr) * 32 + lg * 8];
#pragma unroll
    for (int j = 0; j < 4; ++j)
      bfl[j] = *(const bf8_t*)&LB[(wn * 64 + j * 16 + lr) * 32 + lg * 8];
#pragma unroll
    for (int i = 0; i < 8; ++i)
#pragma unroll
      for (int j = 0; j < 4; ++j)
        acc[i][j] = __builtin_amdgcn_mfma_f32_16x16x32_bf16(afl[i], bfl[j], acc[i][j], 0, 0, 0);
  }

  // ---- write C (C/D map: col = lane&15, row = (lane>>4)*4 + reg) ----
  unsigned short* out16 = (unsigned short*)ov;
  float* out32 = (float*)ov;
#pragma unroll
  for (int i = 0; i < 8; ++i) {
    int ri = wm * 128 + i * 16 + lg * 4;
#pragma unroll
    for (int j = 0; j < 4; ++j) {
      int grow = m0 + ri + j;
      int gb = grow >> 10, gt = grow & 1023;
#pragma unroll
      for (int n = 0; n < 4; ++n) {
        int gc = n0i + wn * 64 + n * 16 + lr;
        float fv = acc[i][n][j];
        if (mode == 0) {
          size_t dst = (((size_t)gb * 16 + (gc >> 7)) * 1024 + gt) * 128 + (gc & 127);
          out16[dst] = f2bf(fv);
        } else if (mode == 1) {
          size_t dst = (((size_t)gb * 16 + (gc >> 7)) * 128 + (gc & 127)) * 1024 + gt;
          out16[dst] = f2bf(fv);
        } else {
          out32[(size_t)grow * 2048 + gc] = fv;
        }
      }
    }
  }
#undef STAGE_A
#undef STAGE_B
#undef PHASE
#undef VM4
#undef VM0
#undef NOSTAGE
}

// ---------- in-place RoPE on (B,H,T,128) bf16 ----------
__global__ void k_rope(unsigned short* __restrict__ X,
                       const float* __restrict__ cosT, const float* __restrict__ sinT) {
  int idx = blockIdx.x * 256 + threadIdx.x;
  int d0 = (idx & 7) * 8;
  int tt = (idx >> 3) & 1023;
  size_t base = (size_t)(idx >> 3) * 128 + d0;
  s8_t a = *(s8_t*)&X[base];
  s8_t bb = *(s8_t*)&X[base + 64];
  float4 c0 = *(const float4*)&cosT[tt * 64 + d0];
  float4 c1 = *(const float4*)&cosT[tt * 64 + d0 + 4];
  float4 sv0 = *(const float4*)&sinT[tt * 64 + d0];
  float4 sv1 = *(const float4*)&sinT[tt * 64 + d0 + 4];
  float cv[8] = {c0.x, c0.y, c0.z, c0.w, c1.x, c1.y, c1.z, c1.w};
  float sw[8] = {sv0.x, sv0.y, sv0.z, sv0.w, sv1.x, sv1.y, sv1.z, sv1.w};
  s8_t ra, rb;
#pragma unroll
  for (int j = 0; j < 8; ++j) {
    float av = bf2f((unsigned short)a[j]);
    float bv = bf2f((unsigned short)bb[j]);
    ra[j] = (short)f2bf(av * cv[j] - bv * sw[j]);
    rb[j] = (short)f2bf(bv * cv[j] + av * sw[j]);
  }
  *(s8_t*)&X[base] = ra;
  *(s8_t*)&X[base + 64] = rb;
}

// ---------- fused attention: LDS-staged K/V, 8 waves, online softmax ----------
__global__ __launch_bounds__(512, 4) void k_attn(
    const unsigned short* __restrict__ Qg,
    const unsigned short* __restrict__ Kg,
    const unsigned short* __restrict__ Vt,
    unsigned short* __restrict__ Y) {
  const float scale = 0.08838834764831845f;
  const float L2E = 1.4426950408889634f;
  const int bid = blockIdx.x;
  const int wg = (bid & 7) * 64 + (bid >> 3);
  const int bh = wg >> 3;
  const int b = bh >> 4, h = bh & 15;
  const int t = threadIdx.x;
  const int w = t >> 6, lane = t & 63;
  const int lr = lane & 15, lg = lane >> 4;
  const int q0 = (wg & 7) * 128 + w * 16;
  const unsigned short* Q  = Qg + (size_t)bh * 131072;
  const unsigned short* Kp = Kg + (size_t)bh * 131072;
  const unsigned short* Vp = Vt + (size_t)bh * 131072;
  __shared__ __align__(16) unsigned short Ks[64 * 128];
  __shared__ __align__(16) unsigned short Vs[128 * 64];
  __shared__ __align__(16) unsigned short Ps[8][16 * 80];
  unsigned short* Pw = Ps[w];

  bf8_t qf[4];
#pragma unroll
  for (int kk = 0; kk < 4; ++kk)
    qf[kk] = *(const bf8_t*)&Q[(size_t)(q0 + lr) * 128 + kk * 32 + lg * 8];

  f4_t o[8] = {};
  float m_run = -1e30f, l_run = 0.0f;

  for (int s0 = 0; s0 < 1024; s0 += 64) {
    __syncthreads();
#pragma unroll
    for (int i = 0; i < 2; ++i) {
      int idx = i * 512 + t;
      int s = idx >> 4, c = t & 15;
      GL16(Kp + (size_t)(s0 + s) * 128 + ((c ^ (s & 7)) * 8), Ks + (size_t)idx * 8);
    }
#pragma unroll
    for (int i = 0; i < 2; ++i) {
      int idx = i * 512 + t;
      int d = idx >> 3, c = t & 7;
      GL16(Vp + (size_t)d * 1024 + s0 + ((c ^ (d & 7)) * 8), Vs + (size_t)idx * 8);
    }
    __syncthreads();

    f4_t sf[4];
#pragma unroll
    for (int ss = 0; ss < 4; ++ss) {
      f4_t c = {0.0f, 0.0f, 0.0f, 0.0f};
#pragma unroll
      for (int kk = 0; kk < 4; ++kk) {
        bf8_t kf = *(const bf8_t*)&Ks[(ss * 16 + lr) * 128 + (((kk * 4 + lg) ^ (lr & 7)) * 8)];
        c = __builtin_amdgcn_mfma_f32_16x16x32_bf16(kf, qf[kk], c, 0, 0, 0);
      }
      sf[ss] = c;
    }
    float vmax = -1e30f;
#pragma unroll
    for (int ss = 0; ss < 4; ++ss)
#pragma unroll
      for (int j = 0; j < 4; ++j) vmax = fmaxf(vmax, sf[ss][j]);
    vmax = fmaxf(vmax, __shfl_xor(vmax, 16));
    vmax = fmaxf(vmax, __shfl_xor(vmax, 32));
    float m_new = fmaxf(m_run, vmax * scale);
    float ratio = exp2f((m_run - m_new) * L2E);
    float lsum = 0.0f;
    float ps[4][4];
#pragma unroll
    for (int ss = 0; ss < 4; ++ss)
#pragma unroll
      for (int j = 0; j < 4; ++j) {
        float pv = exp2f((sf[ss][j] * scale - m_new) * L2E);
        ps[ss][j] = pv; lsum += pv;
      }
    lsum += __shfl_xor(lsum, 16);
    lsum += __shfl_xor(lsum, 32);
    l_run = l_run * ratio + lsum;
    m_run = m_new;
    float rq[4];
#pragma unroll
    for (int j = 0; j < 4; ++j) rq[j] = __shfl(ratio, lg * 4 + j);
#pragma unroll
    for (int n = 0; n < 8; ++n)
#pragma unroll
      for (int j = 0; j < 4; ++j) o[n][j] *= rq[j];
#pragma unroll
    for (int ss = 0; ss < 4; ++ss) {
      s4_t pk;
      pk.x = (short)f2bf(ps[ss][0]); pk.y = (short)f2bf(ps[ss][1]);
      pk.z = (short)f2bf(ps[ss][2]); pk.w = (short)f2bf(ps[ss][3]);
      *(s4_t*)&Pw[lr * 80 + ss * 16 + lg * 4] = pk;
    }
    bf8_t pa0 = *(const bf8_t*)&Pw[lr * 80 + lg * 8];
    bf8_t pa1 = *(const bf8_t*)&Pw[lr * 80 + 32 + lg * 8];
#pragma unroll
    for (int n = 0; n < 8; ++n) {
      int d = n * 16 + lr;
      bf8_t v0 = *(const bf8_t*)&Vs[d * 64 + (((0 + lg) ^ (lr & 7)) * 8)];
      bf8_t v1 = *(const bf8_t*)&Vs[d * 64 + (((4 + lg) ^ (lr & 7)) * 8)];
      o[n] = __builtin_amdgcn_mfma_f32_16x16x32_bf16(pa0, v0, o[n], 0, 0, 0);
      o[n] = __builtin_amdgcn_mfma_f32_16x16x32_bf16(pa1, v1, o[n], 0, 0, 0);
    }
  }

  float linv[4];
#pragma unroll
  for (int j = 0; j < 4; ++j) linv[j] = 1.0f / __shfl(l_run, lg * 4 + j);
#pragma unroll
  for (int n = 0; n < 8; ++n)
#pragma unroll
    for (int j = 0; j < 4; ++j) {
      int qg = q0 + lg * 4 + j;
      Y[((size_t)b * 1024 + qg) * 2048 + h * 128 + n * 16 + lr] =
          f2bf(o[n][j] * linv[j]);
    }
}

// ---------- launch ----------
extern "C" void kernel_launch(void* const* d_in, const int* in_sizes, int n_in,
                              void* d_out, int out_size, void* d_ws, size_t ws_size,
                              hipStream_t stream) {
  const float* x  = (const float*)d_in[0];
  const float* dl = (const float*)d_in[1];
  const float* W[4] = {(const float*)d_in[2], (const float*)d_in[3],
                       (const float*)d_in[4], (const float*)d_in[5]};
  char* ws = (char*)d_ws;
  size_t off = 0;
  auto take = [&](size_t bytes) {
    void* p = ws + off; off += (bytes + 255) & ~(size_t)255; return p;
  };
  unsigned short* xb = (unsigned short*)take(8388608ull * 2);
  unsigned short* Wb[4];
  for (int i = 0; i < 4; ++i) Wb[i] = (unsigned short*)take(4194304ull * 2);
  unsigned short* qb = (unsigned short*)take(8388608ull * 2);
  unsigned short* kb = (unsigned short*)take(8388608ull * 2);
  unsigned short* vT = (unsigned short*)take(8388608ull * 2);
  unsigned short* y  = (unsigned short*)take(8388608ull * 2);
  float* u    = (float*)take(4ull * 4 * 16 * 1024 * 4);
  float* cosT = (float*)take(1024ull * 64 * 4);
  float* sinT = (float*)take(1024ull * 64 * 4);
  unsigned short* dlb = (unsigned short*)take(1048576ull * 2);
  if (off > ws_size) return;

  k_f32_to_bf16<<<8192, 256, 0, stream>>>(x, xb, 2097152);
  for (int i = 0; i < 4; ++i)
    k_f32_to_bf16<<<4096, 256, 0, stream>>>(W[i], Wb[i], 1048576);
  k_f32_to_bf16<<<1024, 256, 0, stream>>>(dl, dlb, 262144);
  k_rope_table<<<1024, 64, 0, stream>>>(cosT, sinT);
  k_lora_mfma<<<dim3(16, 4), 256, 0, stream>>>(xb, dlb, u, 0, 3);

  G8 gq;
  gq.W0 = Wb[0]; gq.W1 = Wb[1]; gq.W2 = Wb[2];
  gq.o0 = qb;    gq.o1 = kb;    gq.o2 = vT;
  gq.n_nt = 24;  gq.fused = 1;
  k_gemm8<<<384, 512, 0, stream>>>(xb, gq, u, dl);

  k_rope<<<2048, 256, 0, stream>>>(qb, cosT, sinT);
  k_rope<<<2048, 256, 0, stream>>>(kb, cosT, sinT);
  k_attn<<<512, 512, 0, stream>>>(qb, kb, vT, y);
  k_lora_mfma<<<dim3(16, 4), 256, 0, stream>>>(y, dlb, u, 3, 1);

  G8 go;
  go.W0 = Wb[3]; go.W1 = Wb[3]; go.W2 = Wb[3];
  go.o0 = d_out; go.o1 = d_out; go.o2 = d_out;
  go.n_nt = 8;   go.fused = 0;
  k_gemm8<<<128, 512, 0, stream>>>(y, go, u, dl);
}

// Round 7
// 404.714 us; speedup vs baseline: 1.3019x; 1.1042x over previous
//
#include <hip/hip_runtime.h>
#include <cstdint>
#include <cstddef>

// ---------- types ----------
typedef __attribute__((ext_vector_type(8))) __bf16 bf8_t;
typedef __attribute__((ext_vector_type(8))) short s8_t;
typedef __attribute__((ext_vector_type(4))) short s4_t;
typedef __attribute__((ext_vector_type(4))) float f4_t;

__device__ __forceinline__ float bf2f(unsigned short h) {
  union { unsigned u; float f; } v; v.u = (unsigned)h << 16; return v.f;
}
__device__ __forceinline__ unsigned short f2bf(float f) {
  union { float f; unsigned u; } v; v.f = f;
  return (unsigned short)((v.u + 0x7FFFu + ((v.u >> 16) & 1u)) >> 16);
}

#define GL16(gp, lp) __builtin_amdgcn_global_load_lds( \
    (__attribute__((address_space(1))) void*)(gp),     \
    (__attribute__((address_space(3))) void*)(lp), 16, 0, 0)

// ---------- fp32 -> bf16 conversion ----------
__global__ void k_f32_to_bf16(const float* __restrict__ in,
                              unsigned short* __restrict__ out, int n4) {
  int i = blockIdx.x * blockDim.x + threadIdx.x;
  if (i >= n4) return;
  float4 v = reinterpret_cast<const float4*>(in)[i];
  s4_t o;
  o.x = (short)f2bf(v.x); o.y = (short)f2bf(v.y);
  o.z = (short)f2bf(v.z); o.w = (short)f2bf(v.w);
  reinterpret_cast<s4_t*>(out)[i] = o;
}

// ---------- RoPE cos/sin table ----------
__global__ void k_rope_table(float* __restrict__ cosT, float* __restrict__ sinT) {
  int t = blockIdx.x, d = threadIdx.x;            // 1024 x 64
  float inv = exp2f(-(float)d * (13.287712379549449f / 64.0f));
  float ang = (float)t * inv;
  cosT[t * 64 + d] = cosf(ang);
  sinT[t * 64 + d] = sinf(ang);
}

// ---------- LoRA u = X @ dA^T via MFMA (u: [B][4][16][1024] f32) ----------
__global__ __launch_bounds__(256) void k_lora_mfma(
    const unsigned short* __restrict__ X,
    const unsigned short* __restrict__ dlb,
    float* __restrict__ u, int pstart, int pcount) {
  __shared__ __align__(16) unsigned short Xs[64 * 64];
  __shared__ __align__(16) unsigned short Da[64 * 64];
  const int t = threadIdx.x;
  const int b = blockIdx.y;
  const int m0 = blockIdx.x * 64;
  const int w = t >> 6, lane = t & 63, lr = lane & 15, lg = lane >> 4;
  const int nrow = pcount * 16;
  f4_t acc[4] = {};
  for (int k0 = 0; k0 < 2048; k0 += 64) {
    __syncthreads();
#pragma unroll
    for (int i = 0; i < 2; ++i) {
      int idx = i * 256 + t;
      int row = idx >> 3, c = idx & 7;
      GL16(X + ((size_t)b * 1024 + m0 + row) * 2048 + k0 + ((c ^ (row & 7)) * 8),
           Xs + (size_t)idx * 8);
      int ric = row < nrow ? row : nrow - 1;
      int g = (pstart + (ric >> 4)) * 32 + (ric & 15);
      GL16(dlb + ((size_t)b * 128 + g) * 2048 + k0 + ((c ^ (ric & 7)) * 8),
           Da + (size_t)idx * 8);
    }
    __syncthreads();
#pragma unroll
    for (int kk = 0; kk < 2; ++kk) {
      bf8_t af = *(const bf8_t*)&Xs[(w * 16 + lr) * 64 + (((kk * 4 + lg) ^ (lr & 7)) * 8)];
#pragma unroll
      for (int n = 0; n < 4; ++n) {
        if (n < pcount) {
          bf8_t bfv = *(const bf8_t*)&Da[(n * 16 + lr) * 64 + (((kk * 4 + lg) ^ (lr & 7)) * 8)];
          acc[n] = __builtin_amdgcn_mfma_f32_16x16x32_bf16(af, bfv, acc[n], 0, 0, 0);
        }
      }
    }
  }
#pragma unroll
  for (int n = 0; n < 4; ++n) {
    if (n < pcount) {
#pragma unroll
      for (int j = 0; j < 4; ++j)
        u[(((size_t)b * 4 + pstart + n) * 16 + lr) * 1024 + m0 + w * 16 + lg * 4 + j] = acc[n][j];
    }
  }
}

// ---------- 256x256 8-phase bf16 GEMM (dedup frags, 1 barrier/phase) ----------
// Slots/tile: Ah0,Ah1,Bh0,Bh1 (16KB). Even tile: A0,A1,B0,B1; odd: A2,A3,B2,B3.
// Reads: P1 A+B0 (12 ds), P2 B1 (4), P3 A' (8), P4 none. bf0/bf1 stay in regs.
// Deaths: A0@E1 B0@E1 B1@E2 A1@E3 | A2@O1 B2@O1 B3@O2 A3@O3.
// Stages: E1:A3<-A(t+1)h1  E2:A0<-A(t+2)h0  E3:B0<-B(t+2)h0  E4:B1<-B(t+2)h1 [vm6]
//         O1:A1<-A(t+2)h1  O2:A2<-A(t+3)h0  O3:B2<-B(t+3)h0  O4:B3<-B(t+3)h1 [vm6]
// vm6@E4 drains {A,B,B,A}(t+1); vm6@O4 drains {A,B,B,A}(t+2). Invariant: 3 stages in flight.
struct G8 {
  const unsigned short *W0, *W1, *W2;
  void *o0, *o1, *o2;
  int n_nt, fused;
};

__global__ __launch_bounds__(512, 2) void k_gemm8(
    const unsigned short* __restrict__ Ag, G8 ga,
    const float* __restrict__ u, const float* __restrict__ dl) {
  __shared__ unsigned short As[4][128 * 64];   // 64 KB (4 slots)
  __shared__ unsigned short Bs[4][128 * 64];   // 64 KB
  const int t = threadIdx.x;
  const int w = t >> 6, l = t & 63;
  const int lr = l & 15, lg = l >> 4;
  const int wm = w >> 2, wn = w & 3;

  const int nwg = 16 * ga.n_nt;
  const int wg = ((int)blockIdx.x & 7) * (nwg >> 3) + ((int)blockIdx.x >> 3);
  const int m0 = (wg / ga.n_nt) * 256;
  const int n0 = (wg % ga.n_nt) * 256;
  const int z = n0 >> 11;
  const unsigned short* Bg;
  void* ov;
  int mode, p, n0i;
  if (ga.fused) {
    Bg = z == 0 ? ga.W0 : (z == 1 ? ga.W1 : ga.W2);
    ov = z == 0 ? ga.o0 : (z == 1 ? ga.o1 : ga.o2);
    mode = (z == 2) ? 1 : 0; p = z; n0i = n0 & 2047;
  } else {
    Bg = ga.W0; ov = ga.o0; mode = 2; p = 3; n0i = n0;
  }

  f4_t acc[8][4] = {};

#define STAGE_A(tt, hh, slot) do { \
  const int k0_ = (tt) * 64; \
  _Pragma("unroll") for (int rr_ = 0; rr_ < 2; ++rr_) { \
    int q_ = t >> 3; \
    int grow_ = (hh) * 64 + q_ + rr_ * 128; \
    int csrc_ = ((t & 7) ^ (q_ & 7)) * 8; \
    GL16(Ag + (size_t)(m0 + grow_) * 2048 + k0_ + csrc_, \
         &As[slot][rr_ * 4096 + t * 8]); \
  } } while (0)

#define STAGE_B(tt, hh, slot) do { \
  const int k0_ = (tt) * 64; \
  _Pragma("unroll") for (int rr_ = 0; rr_ < 2; ++rr_) { \
    int q_ = t >> 3; \
    int grow_ = (hh) * 32 + (q_ & 31) + (rr_ * 2 + (q_ >> 5)) * 64; \
    int csrc_ = ((t & 7) ^ (q_ & 7)) * 8; \
    GL16(Bg + (size_t)(n0i + grow_) * 2048 + k0_ + csrc_, \
         &Bs[slot][rr_ * 4096 + t * 8]); \
  } } while (0)

#define READ_A(sa) do { \
  _Pragma("unroll") for (int i = 0; i < 4; ++i) { \
    int lrow_ = wm * 64 + i * 16 + lr; \
    af[i][0] = *(const bf8_t*)&As[sa][lrow_ * 64 + ((lg ^ (lr & 7)) * 8)]; \
    af[i][1] = *(const bf8_t*)&As[sa][lrow_ * 64 + (((4 + lg) ^ (lr & 7)) * 8)]; \
  } } while (0)

#define READ_B(sb, bfr) do { \
  _Pragma("unroll") for (int j = 0; j < 2; ++j) { \
    int lrow_ = wn * 32 + j * 16 + lr; \
    bfr[j][0] = *(const bf8_t*)&Bs[sb][lrow_ * 64 + ((lg ^ (lr & 7)) * 8)]; \
    bfr[j][1] = *(const bf8_t*)&Bs[sb][lrow_ * 64 + (((4 + lg) ^ (lr & 7)) * 8)]; \
  } } while (0)

#define MFMA_Q(mh, nh, bfr) do { \
  __builtin_amdgcn_s_setprio(1); \
  _Pragma("unroll") for (int kk = 0; kk < 2; ++kk) \
  _Pragma("unroll") for (int i = 0; i < 4; ++i) \
  _Pragma("unroll") for (int j = 0; j < 2; ++j) \
    acc[(mh) * 4 + i][(nh) * 2 + j] = __builtin_amdgcn_mfma_f32_16x16x32_bf16( \
        af[i][kk], bfr[j][kk], acc[(mh) * 4 + i][(nh) * 2 + j], 0, 0, 0); \
  __builtin_amdgcn_s_setprio(0); \
} while (0)

#define VM6 asm volatile("s_waitcnt vmcnt(6)" ::: "memory")
#define VM0 asm volatile("s_waitcnt vmcnt(0)" ::: "memory")
#define BARRIER __builtin_amdgcn_s_barrier()

  bf8_t af[4][2], bf0[2][2], bf1[2][2];

  // prologue: A(0)h0,B(0)h0,B(0)h1,A(0)h1,A(1)h0,B(1)h0,B(1)h1 (7 stages)
  STAGE_A(0, 0, 0); STAGE_B(0, 0, 0); STAGE_B(0, 1, 1); STAGE_A(0, 1, 1);
  STAGE_A(1, 0, 2); STAGE_B(1, 0, 2); STAGE_B(1, 1, 3);
  VM6; BARRIER;

#pragma unroll 1
  for (int tb = 0; tb < 30; tb += 2) {
    // even tile tb (A0,A1,B0,B1)
    STAGE_A(tb + 1, 1, 3); READ_A(0); READ_B(0, bf0); MFMA_Q(0, 0, bf0); BARRIER;
    STAGE_A(tb + 2, 0, 0); READ_B(1, bf1);            MFMA_Q(0, 1, bf1); BARRIER;
    STAGE_B(tb + 2, 0, 0); READ_A(1);                 MFMA_Q(1, 0, bf0); BARRIER;
    STAGE_B(tb + 2, 1, 1);                            MFMA_Q(1, 1, bf1); VM6; BARRIER;
    // odd tile tb+1 (A2,A3,B2,B3)
    STAGE_A(tb + 2, 1, 1); READ_A(2); READ_B(2, bf0); MFMA_Q(0, 0, bf0); BARRIER;
    STAGE_A(tb + 3, 0, 2); READ_B(3, bf1);            MFMA_Q(0, 1, bf1); BARRIER;
    STAGE_B(tb + 3, 0, 2); READ_A(3);                 MFMA_Q(1, 0, bf0); BARRIER;
    STAGE_B(tb + 3, 1, 3);                            MFMA_Q(1, 1, bf1); VM6; BARRIER;
  }
  // tile 30 (even): only A(31)h1 left to stage; drain fully at E4
  STAGE_A(31, 1, 3); READ_A(0); READ_B(0, bf0); MFMA_Q(0, 0, bf0); BARRIER;
  READ_B(1, bf1); MFMA_Q(0, 1, bf1); BARRIER;
  READ_A(1);      MFMA_Q(1, 0, bf0); BARRIER;
  MFMA_Q(1, 1, bf1); VM0; BARRIER;
  // tile 31 (odd): no stages
  READ_A(2); READ_B(2, bf0); MFMA_Q(0, 0, bf0); BARRIER;
  READ_B(3, bf1); MFMA_Q(0, 1, bf1); BARRIER;
  READ_A(3);      MFMA_Q(1, 0, bf0); BARRIER;
  MFMA_Q(1, 1, bf1); BARRIER;

  __syncthreads();

  // ---- LoRA rank-16 epilogue: one zero-padded K=32 MFMA step ----
  unsigned short* LA = &As[0][0];   // 256 rows x 32
  unsigned short* LB = &Bs[0][0];
  const int b = m0 >> 10;
  const int t0r = m0 & 1023;
  {
    int row = t >> 1, cb = (t & 1) * 16;
    s8_t v0, v1;
#pragma unroll
    for (int r = 0; r < 8; ++r) {
      int cc = cb + r;
      v0[r] = (short)((cc < 16) ? f2bf(u[(((size_t)b * 4 + p) * 16 + cc) * 1024 + t0r + row]) : 0);
    }
#pragma unroll
    for (int r = 0; r < 8; ++r) {
      int cc = cb + 8 + r;
      v1[r] = (short)((cc < 16) ? f2bf(u[(((size_t)b * 4 + p) * 16 + cc) * 1024 + t0r + row]) : 0);
    }
    *(s8_t*)&LA[row * 32 + cb] = v0;
    *(s8_t*)&LA[row * 32 + cb + 8] = v1;
    s8_t w0, w1;
#pragma unroll
    for (int r = 0; r < 8; ++r) {
      int cc = cb + r;
      w0[r] = (short)((cc < 16) ? f2bf(dl[((size_t)b * 128 + p * 32 + 16 + cc) * 2048 + n0i + row]) : 0);
    }
#pragma unroll
    for (int r = 0; r < 8; ++r) {
      int cc = cb + 8 + r;
      w1[r] = (short)((cc < 16) ? f2bf(dl[((size_t)b * 128 + p * 32 + 16 + cc) * 2048 + n0i + row]) : 0);
    }
    *(s8_t*)&LB[row * 32 + cb] = w0;
    *(s8_t*)&LB[row * 32 + cb + 8] = w1;
  }
  __syncthreads();
  {
    bf8_t afl[8], bfl[4];
#pragma unroll
    for (int i = 0; i < 8; ++i)
      afl[i] = *(const bf8_t*)&LA[(wm * 128 + i * 16 + lr) * 32 + lg * 8];
#pragma unroll
    for (int j = 0; j < 4; ++j)
      bfl[j] = *(const bf8_t*)&LB[(wn * 64 + j * 16 + lr) * 32 + lg * 8];
#pragma unroll
    for (int i = 0; i < 8; ++i)
#pragma unroll
      for (int j = 0; j < 4; ++j)
        acc[i][j] = __builtin_amdgcn_mfma_f32_16x16x32_bf16(afl[i], bfl[j], acc[i][j], 0, 0, 0);
  }

  // ---- write C (C/D map: col = lane&15, row = (lane>>4)*4 + reg) ----
  unsigned short* out16 = (unsigned short*)ov;
  float* out32 = (float*)ov;
#pragma unroll
  for (int i = 0; i < 8; ++i) {
    int ri = wm * 128 + i * 16 + lg * 4;
#pragma unroll
    for (int j = 0; j < 4; ++j) {
      int grow = m0 + ri + j;
      int gb = grow >> 10, gt = grow & 1023;
#pragma unroll
      for (int n = 0; n < 4; ++n) {
        int gc = n0i + wn * 64 + n * 16 + lr;
        float fv = acc[i][n][j];
        if (mode == 0) {
          size_t dst = (((size_t)gb * 16 + (gc >> 7)) * 1024 + gt) * 128 + (gc & 127);
          out16[dst] = f2bf(fv);
        } else if (mode == 1) {
          size_t dst = (((size_t)gb * 16 + (gc >> 7)) * 128 + (gc & 127)) * 1024 + gt;
          out16[dst] = f2bf(fv);
        } else {
          out32[(size_t)grow * 2048 + gc] = fv;
        }
      }
    }
  }
#undef STAGE_A
#undef STAGE_B
#undef READ_A
#undef READ_B
#undef MFMA_Q
#undef VM6
#undef VM0
#undef BARRIER
}

// ---------- in-place RoPE on (B,H,T,128) bf16 ----------
__global__ void k_rope(unsigned short* __restrict__ X,
                       const float* __restrict__ cosT, const float* __restrict__ sinT) {
  int idx = blockIdx.x * 256 + threadIdx.x;
  int d0 = (idx & 7) * 8;
  int tt = (idx >> 3) & 1023;
  size_t base = (size_t)(idx >> 3) * 128 + d0;
  s8_t a = *(s8_t*)&X[base];
  s8_t bb = *(s8_t*)&X[base + 64];
  float4 c0 = *(const float4*)&cosT[tt * 64 + d0];
  float4 c1 = *(const float4*)&cosT[tt * 64 + d0 + 4];
  float4 sv0 = *(const float4*)&sinT[tt * 64 + d0];
  float4 sv1 = *(const float4*)&sinT[tt * 64 + d0 + 4];
  float cv[8] = {c0.x, c0.y, c0.z, c0.w, c1.x, c1.y, c1.z, c1.w};
  float sw[8] = {sv0.x, sv0.y, sv0.z, sv0.w, sv1.x, sv1.y, sv1.z, sv1.w};
  s8_t ra, rb;
#pragma unroll
  for (int j = 0; j < 8; ++j) {
    float av = bf2f((unsigned short)a[j]);
    float bv = bf2f((unsigned short)bb[j]);
    ra[j] = (short)f2bf(av * cv[j] - bv * sw[j]);
    rb[j] = (short)f2bf(bv * cv[j] + av * sw[j]);
  }
  *(s8_t*)&X[base] = ra;
  *(s8_t*)&X[base + 64] = rb;
}

// ---------- fused attention: LDS-staged K/V, 8 waves, online softmax ----------
__global__ __launch_bounds__(512, 4) void k_attn(
    const unsigned short* __restrict__ Qg,
    const unsigned short* __restrict__ Kg,
    const unsigned short* __restrict__ Vt,
    unsigned short* __restrict__ Y) {
  const float scale = 0.08838834764831845f;
  const float L2E = 1.4426950408889634f;
  const int bid = blockIdx.x;
  const int wg = (bid & 7) * 64 + (bid >> 3);
  const int bh = wg >> 3;
  const int b = bh >> 4, h = bh & 15;
  const int t = threadIdx.x;
  const int w = t >> 6, lane = t & 63;
  const int lr = lane & 15, lg = lane >> 4;
  const int q0 = (wg & 7) * 128 + w * 16;
  const unsigned short* Q  = Qg + (size_t)bh * 131072;
  const unsigned short* Kp = Kg + (size_t)bh * 131072;
  const unsigned short* Vp = Vt + (size_t)bh * 131072;
  __shared__ __align__(16) unsigned short Ks[64 * 128];
  __shared__ __align__(16) unsigned short Vs[128 * 64];
  __shared__ __align__(16) unsigned short Ps[8][16 * 80];
  unsigned short* Pw = Ps[w];

  bf8_t qf[4];
#pragma unroll
  for (int kk = 0; kk < 4; ++kk)
    qf[kk] = *(const bf8_t*)&Q[(size_t)(q0 + lr) * 128 + kk * 32 + lg * 8];

  f4_t o[8] = {};
  float m_run = -1e30f, l_run = 0.0f;

  for (int s0 = 0; s0 < 1024; s0 += 64) {
    __syncthreads();
#pragma unroll
    for (int i = 0; i < 2; ++i) {
      int idx = i * 512 + t;
      int s = idx >> 4, c = t & 15;
      GL16(Kp + (size_t)(s0 + s) * 128 + ((c ^ (s & 7)) * 8), Ks + (size_t)idx * 8);
    }
#pragma unroll
    for (int i = 0; i < 2; ++i) {
      int idx = i * 512 + t;
      int d = idx >> 3, c = t & 7;
      GL16(Vp + (size_t)d * 1024 + s0 + ((c ^ (d & 7)) * 8), Vs + (size_t)idx * 8);
    }
    __syncthreads();

    f4_t sf[4];
#pragma unroll
    for (int ss = 0; ss < 4; ++ss) {
      f4_t c = {0.0f, 0.0f, 0.0f, 0.0f};
#pragma unroll
      for (int kk = 0; kk < 4; ++kk) {
        bf8_t kf = *(const bf8_t*)&Ks[(ss * 16 + lr) * 128 + (((kk * 4 + lg) ^ (lr & 7)) * 8)];
        c = __builtin_amdgcn_mfma_f32_16x16x32_bf16(kf, qf[kk], c, 0, 0, 0);
      }
      sf[ss] = c;
    }
    float vmax = -1e30f;
#pragma unroll
    for (int ss = 0; ss < 4; ++ss)
#pragma unroll
      for (int j = 0; j < 4; ++j) vmax = fmaxf(vmax, sf[ss][j]);
    vmax = fmaxf(vmax, __shfl_xor(vmax, 16));
    vmax = fmaxf(vmax, __shfl_xor(vmax, 32));
    float m_new = fmaxf(m_run, vmax * scale);
    float ratio = exp2f((m_run - m_new) * L2E);
    float lsum = 0.0f;
    float ps[4][4];
#pragma unroll
    for (int ss = 0; ss < 4; ++ss)
#pragma unroll
      for (int j = 0; j < 4; ++j) {
        float pv = exp2f((sf[ss][j] * scale - m_new) * L2E);
        ps[ss][j] = pv; lsum += pv;
      }
    lsum += __shfl_xor(lsum, 16);
    lsum += __shfl_xor(lsum, 32);
    l_run = l_run * ratio + lsum;
    m_run = m_new;
    float rq[4];
#pragma unroll
    for (int j = 0; j < 4; ++j) rq[j] = __shfl(ratio, lg * 4 + j);
#pragma unroll
    for (int n = 0; n < 8; ++n)
#pragma unroll
      for (int j = 0; j < 4; ++j) o[n][j] *= rq[j];
#pragma unroll
    for (int ss = 0; ss < 4; ++ss) {
      s4_t pk;
      pk.x = (short)f2bf(ps[ss][0]); pk.y = (short)f2bf(ps[ss][1]);
      pk.z = (short)f2bf(ps[ss][2]); pk.w = (short)f2bf(ps[ss][3]);
      *(s4_t*)&Pw[lr * 80 + ss * 16 + lg * 4] = pk;
    }
    bf8_t pa0 = *(const bf8_t*)&Pw[lr * 80 + lg * 8];
    bf8_t pa1 = *(const bf8_t*)&Pw[lr * 80 + 32 + lg * 8];
#pragma unroll
    for (int n = 0; n < 8; ++n) {
      int d = n * 16 + lr;
      bf8_t v0 = *(const bf8_t*)&Vs[d * 64 + (((0 + lg) ^ (lr & 7)) * 8)];
      bf8_t v1 = *(const bf8_t*)&Vs[d * 64 + (((4 + lg) ^ (lr & 7)) * 8)];
      o[n] = __builtin_amdgcn_mfma_f32_16x16x32_bf16(pa0, v0, o[n], 0, 0, 0);
      o[n] = __builtin_amdgcn_mfma_f32_16x16x32_bf16(pa1, v1, o[n], 0, 0, 0);
    }
  }

  float linv[4];
#pragma unroll
  for (int j = 0; j < 4; ++j) linv[j] = 1.0f / __shfl(l_run, lg * 4 + j);
#pragma unroll
  for (int n = 0; n < 8; ++n)
#pragma unroll
    for (int j = 0; j < 4; ++j) {
      int qg = q0 + lg * 4 + j;
      Y[((size_t)b * 1024 + qg) * 2048 + h * 128 + n * 16 + lr] =
          f2bf(o[n][j] * linv[j]);
    }
}

// ---------- launch ----------
extern "C" void kernel_launch(void* const* d_in, const int* in_sizes, int n_in,
                              void* d_out, int out_size, void* d_ws, size_t ws_size,
                              hipStream_t stream) {
  const float* x  = (const float*)d_in[0];
  const float* dl = (const float*)d_in[1];
  const float* W[4] = {(const float*)d_in[2], (const float*)d_in[3],
                       (const float*)d_in[4], (const float*)d_in[5]};
  char* ws = (char*)d_ws;
  size_t off = 0;
  auto take = [&](size_t bytes) {
    void* p = ws + off; off += (bytes + 255) & ~(size_t)255; return p;
  };
  unsigned short* xb = (unsigned short*)take(8388608ull * 2);
  unsigned short* Wb[4];
  for (int i = 0; i < 4; ++i) Wb[i] = (unsigned short*)take(4194304ull * 2);
  unsigned short* qb = (unsigned short*)take(8388608ull * 2);
  unsigned short* kb = (unsigned short*)take(8388608ull * 2);
  unsigned short* vT = (unsigned short*)take(8388608ull * 2);
  unsigned short* y  = (unsigned short*)take(8388608ull * 2);
  float* u    = (float*)take(4ull * 4 * 16 * 1024 * 4);
  float* cosT = (float*)take(1024ull * 64 * 4);
  float* sinT = (float*)take(1024ull * 64 * 4);
  unsigned short* dlb = (unsigned short*)take(1048576ull * 2);
  if (off > ws_size) return;

  k_f32_to_bf16<<<8192, 256, 0, stream>>>(x, xb, 2097152);
  for (int i = 0; i < 4; ++i)
    k_f32_to_bf16<<<4096, 256, 0, stream>>>(W[i], Wb[i], 1048576);
  k_f32_to_bf16<<<1024, 256, 0, stream>>>(dl, dlb, 262144);
  k_rope_table<<<1024, 64, 0, stream>>>(cosT, sinT);
  k_lora_mfma<<<dim3(16, 4), 256, 0, stream>>>(xb, dlb, u, 0, 3);

  G8 gq;
  gq.W0 = Wb[0]; gq.W1 = Wb[1]; gq.W2 = Wb[2];
  gq.o0 = qb;    gq.o1 = kb;    gq.o2 = vT;
  gq.n_nt = 24;  gq.fused = 1;
  k_gemm8<<<384, 512, 0, stream>>>(xb, gq, u, dl);

  k_rope<<<2048, 256, 0, stream>>>(qb, cosT, sinT);
  k_rope<<<2048, 256, 0, stream>>>(kb, cosT, sinT);
  k_attn<<<512, 512, 0, stream>>>(qb, kb, vT, y);
  k_lora_mfma<<<dim3(16, 4), 256, 0, stream>>>(y, dlb, u, 3, 1);

  G8 go;
  go.W0 = Wb[3]; go.W1 = Wb[3]; go.W2 = Wb[3];
  go.o0 = d_out; go.o1 = d_out; go.o2 = d_out;
  go.n_nt = 8;   go.fused = 0;
  k_gemm8<<<128, 512, 0, stream>>>(y, go, u, dl);
}

// Round 8
// 360.454 us; speedup vs baseline: 1.4618x; 1.1228x over previous
//
#include <hip/hip_runtime.h>
#include <cstdint>
#include <cstddef>

// ---------- types ----------
typedef __attribute__((ext_vector_type(8))) __bf16 bf8_t;
typedef __attribute__((ext_vector_type(8))) short s8_t;
typedef __attribute__((ext_vector_type(4))) short s4_t;
typedef __attribute__((ext_vector_type(4))) float f4_t;

__device__ __forceinline__ float bf2f(unsigned short h) {
  union { unsigned u; float f; } v; v.u = (unsigned)h << 16; return v.f;
}
__device__ __forceinline__ unsigned short f2bf(float f) {
  union { float f; unsigned u; } v; v.f = f;
  return (unsigned short)((v.u + 0x7FFFu + ((v.u >> 16) & 1u)) >> 16);
}

#define GL16(gp, lp) __builtin_amdgcn_global_load_lds( \
    (__attribute__((address_space(1))) void*)(gp),     \
    (__attribute__((address_space(3))) void*)(lp), 16, 0, 0)

// ---------- fp32 -> bf16 conversion ----------
__global__ void k_f32_to_bf16(const float* __restrict__ in,
                              unsigned short* __restrict__ out, int n4) {
  int i = blockIdx.x * blockDim.x + threadIdx.x;
  if (i >= n4) return;
  float4 v = reinterpret_cast<const float4*>(in)[i];
  s4_t o;
  o.x = (short)f2bf(v.x); o.y = (short)f2bf(v.y);
  o.z = (short)f2bf(v.z); o.w = (short)f2bf(v.w);
  reinterpret_cast<s4_t*>(out)[i] = o;
}

// 4 weight matrices in one launch (blockIdx.y selects)
struct P4 { const float* in[4]; unsigned short* out[4]; };
__global__ void k_f32_to_bf16_4(P4 a, int n4) {
  int y = blockIdx.y;
  int i = blockIdx.x * blockDim.x + threadIdx.x;
  if (i >= n4) return;
  float4 v = reinterpret_cast<const float4*>(a.in[y])[i];
  s4_t o;
  o.x = (short)f2bf(v.x); o.y = (short)f2bf(v.y);
  o.z = (short)f2bf(v.z); o.w = (short)f2bf(v.w);
  reinterpret_cast<s4_t*>(a.out[y])[i] = o;
}

// ---------- RoPE cos/sin table ----------
__global__ void k_rope_table(float* __restrict__ cosT, float* __restrict__ sinT) {
  int t = blockIdx.x, d = threadIdx.x;            // 1024 x 64
  float inv = exp2f(-(float)d * (13.287712379549449f / 64.0f));
  float ang = (float)t * inv;
  cosT[t * 64 + d] = cosf(ang);
  sinT[t * 64 + d] = sinf(ang);
}

// ---------- LoRA u = X @ dA^T via MFMA (u: [B][4][16][1024] f32) ----------
__global__ __launch_bounds__(256) void k_lora_mfma(
    const unsigned short* __restrict__ X,
    const unsigned short* __restrict__ dlb,
    float* __restrict__ u, int pstart, int pcount) {
  __shared__ __align__(16) unsigned short Xs[64 * 64];
  __shared__ __align__(16) unsigned short Da[64 * 64];
  const int t = threadIdx.x;
  const int b = blockIdx.y;
  const int m0 = blockIdx.x * 64;
  const int w = t >> 6, lane = t & 63, lr = lane & 15, lg = lane >> 4;
  const int nrow = pcount * 16;
  f4_t acc[4] = {};
  for (int k0 = 0; k0 < 2048; k0 += 64) {
    __syncthreads();
#pragma unroll
    for (int i = 0; i < 2; ++i) {
      int idx = i * 256 + t;
      int row = idx >> 3, c = idx & 7;
      GL16(X + ((size_t)b * 1024 + m0 + row) * 2048 + k0 + ((c ^ (row & 7)) * 8),
           Xs + (size_t)idx * 8);
      int ric = row < nrow ? row : nrow - 1;
      int g = (pstart + (ric >> 4)) * 32 + (ric & 15);
      GL16(dlb + ((size_t)b * 128 + g) * 2048 + k0 + ((c ^ (ric & 7)) * 8),
           Da + (size_t)idx * 8);
    }
    __syncthreads();
#pragma unroll
    for (int kk = 0; kk < 2; ++kk) {
      bf8_t af = *(const bf8_t*)&Xs[(w * 16 + lr) * 64 + (((kk * 4 + lg) ^ (lr & 7)) * 8)];
#pragma unroll
      for (int n = 0; n < 4; ++n) {
        if (n < pcount) {
          bf8_t bfv = *(const bf8_t*)&Da[(n * 16 + lr) * 64 + (((kk * 4 + lg) ^ (lr & 7)) * 8)];
          acc[n] = __builtin_amdgcn_mfma_f32_16x16x32_bf16(af, bfv, acc[n], 0, 0, 0);
        }
      }
    }
  }
#pragma unroll
  for (int n = 0; n < 4; ++n) {
    if (n < pcount) {
#pragma unroll
      for (int j = 0; j < 4; ++j)
        u[(((size_t)b * 4 + pstart + n) * 16 + lr) * 1024 + m0 + w * 16 + lg * 4 + j] = acc[n][j];
    }
  }
}

// ---------- 128x128 bf16 GEMM, 2-phase m97 structure + XOR swizzle + LoRA ----
// mode 0: out (B,H,T,D) bf16   mode 1: out (B,H,D,T) bf16   mode 2: (B,T,C) f32
// LDS rows [128][64]; chunk c of row r holds global chunk c^(r&7) (16B chunks).
struct GArgs {
  const unsigned short *Bw0, *Bw1, *Bw2;
  void *o0, *o1, *o2;
  int m0_, m1_, m2_;
  int p0_, p1_, p2_;
};
#define BM 128
#define BN 128
#define BKK 64
__global__ __launch_bounds__(256, 2) void k_gemm(
    const unsigned short* __restrict__ A,
    GArgs ga,
    const float* __restrict__ u,
    const float* __restrict__ dl) {
  constexpr int K = 2048;
  const int z = blockIdx.z;
  const unsigned short* Bw = z == 0 ? ga.Bw0 : (z == 1 ? ga.Bw1 : ga.Bw2);
  void* outv = z == 0 ? ga.o0 : (z == 1 ? ga.o1 : ga.o2);
  const int mode = z == 0 ? ga.m0_ : (z == 1 ? ga.m1_ : ga.m2_);
  const int p = z == 0 ? ga.p0_ : (z == 1 ? ga.p1_ : ga.p2_);
  __shared__ unsigned short As[BM * BKK];   // 16 KB
  __shared__ unsigned short Bs[BN * BKK];   // 16 KB
  const int t = threadIdx.x;
  const int m0 = blockIdx.y * BM;
  const int n0 = blockIdx.x * BN;
  const int lane = t & 63;
  const int w = t >> 6;
  const int wr = (w >> 1) * 64, wc = (w & 1) * 64;
  const int lr = lane & 15;
  const int lg = lane >> 4;
  const int srow = t >> 3;                 // 0..31
  const int sdst = (t & 7) * 8;            // dest chunk (elems)
  const int ssrc = ((t & 7) ^ (srow & 7)) * 8;  // swizzled source col
  f4_t acc[4][4] = {};

  for (int k0 = 0; k0 < K; k0 += BKK) {
#pragma unroll
    for (int j = 0; j < 4; ++j) {
      int row = j * 32 + srow;
      GL16(A  + (size_t)(m0 + row) * K + k0 + ssrc, As + row * BKK + sdst);
      GL16(Bw + (size_t)(n0 + row) * K + k0 + ssrc, Bs + row * BKK + sdst);
    }
    __syncthreads();
#pragma unroll
    for (int kk = 0; kk < 2; ++kk) {       // k-half: chunk base {0,4}
      bf8_t af[4], bfr[4];
#pragma unroll
      for (int m = 0; m < 4; ++m) {
        int row_ = wr + m * 16 + lr;
        af[m] = *(const bf8_t*)&As[row_ * BKK + (((kk * 4 + lg) ^ (lr & 7)) * 8)];
      }
#pragma unroll
      for (int n = 0; n < 4; ++n) {
        int row_ = wc + n * 16 + lr;
        bfr[n] = *(const bf8_t*)&Bs[row_ * BKK + (((kk * 4 + lg) ^ (lr & 7)) * 8)];
      }
#pragma unroll
      for (int m = 0; m < 4; ++m)
#pragma unroll
        for (int n = 0; n < 4; ++n)
          acc[m][n] = __builtin_amdgcn_mfma_f32_16x16x32_bf16(af[m], bfr[n], acc[m][n], 0, 0, 0);
    }
    __syncthreads();
  }

  // LoRA rank-16 as one zero-padded K=32 MFMA step (linear LDS, one-shot)
  const int b = m0 >> 10;
  const int t0r = m0 & 1023;
  for (int idx = t; idx < 128 * 32; idx += 256) {
    int rr = idx >> 5, r = idx & 31;
    float val = (r < 16) ? u[(((size_t)b * 4 + p) * 16 + r) * 1024 + t0r + rr] : 0.0f;
    As[rr * 32 + r] = f2bf(val);
  }
  for (int idx = t; idx < 128 * 32; idx += 256) {
    int cc = idx >> 5, r = idx & 31;
    float val = (r < 16) ? dl[((size_t)b * 128 + p * 32 + 16 + r) * 2048 + n0 + cc] : 0.0f;
    Bs[cc * 32 + r] = f2bf(val);
  }
  __syncthreads();
  {
    bf8_t af[4], bfr[4];
#pragma unroll
    for (int m = 0; m < 4; ++m)
      af[m] = *(const bf8_t*)&As[(wr + m * 16 + lr) * 32 + lg * 8];
#pragma unroll
    for (int n = 0; n < 4; ++n)
      bfr[n] = *(const bf8_t*)&Bs[(wc + n * 16 + lr) * 32 + lg * 8];
#pragma unroll
    for (int m = 0; m < 4; ++m)
#pragma unroll
      for (int n = 0; n < 4; ++n)
        acc[m][n] = __builtin_amdgcn_mfma_f32_16x16x32_bf16(af[m], bfr[n], acc[m][n], 0, 0, 0);
  }

  // write C (C/D map: col = lane&15, row = (lane>>4)*4 + reg)
  unsigned short* out16 = (unsigned short*)outv;
  float* out32 = (float*)outv;
#pragma unroll
  for (int m = 0; m < 4; ++m) {
    int ri = wr + m * 16 + lg * 4;
#pragma unroll
    for (int j = 0; j < 4; ++j) {
      int grow = m0 + ri + j;
      int gb = grow >> 10, gt = grow & 1023;
#pragma unroll
      for (int n = 0; n < 4; ++n) {
        int gcol = n0 + wc + n * 16 + lr;
        float fv = acc[m][n][j];
        if (mode == 0) {
          size_t dst = (((size_t)gb * 16 + (gcol >> 7)) * 1024 + gt) * 128 + (gcol & 127);
          out16[dst] = f2bf(fv);
        } else if (mode == 1) {
          size_t dst = (((size_t)gb * 16 + (gcol >> 7)) * 128 + (gcol & 127)) * 1024 + gt;
          out16[dst] = f2bf(fv);
        } else {
          out32[(size_t)grow * 2048 + gcol] = fv;
        }
      }
    }
  }
}

// ---------- in-place RoPE on (B,H,T,128) bf16 ----------
__global__ void k_rope(unsigned short* __restrict__ X,
                       const float* __restrict__ cosT, const float* __restrict__ sinT) {
  int idx = blockIdx.x * 256 + threadIdx.x;
  int d0 = (idx & 7) * 8;
  int tt = (idx >> 3) & 1023;
  size_t base = (size_t)(idx >> 3) * 128 + d0;
  s8_t a = *(s8_t*)&X[base];
  s8_t bb = *(s8_t*)&X[base + 64];
  float4 c0 = *(const float4*)&cosT[tt * 64 + d0];
  float4 c1 = *(const float4*)&cosT[tt * 64 + d0 + 4];
  float4 sv0 = *(const float4*)&sinT[tt * 64 + d0];
  float4 sv1 = *(const float4*)&sinT[tt * 64 + d0 + 4];
  float cv[8] = {c0.x, c0.y, c0.z, c0.w, c1.x, c1.y, c1.z, c1.w};
  float sw[8] = {sv0.x, sv0.y, sv0.z, sv0.w, sv1.x, sv1.y, sv1.z, sv1.w};
  s8_t ra, rb;
#pragma unroll
  for (int j = 0; j < 8; ++j) {
    float av = bf2f((unsigned short)a[j]);
    float bv = bf2f((unsigned short)bb[j]);
    ra[j] = (short)f2bf(av * cv[j] - bv * sw[j]);
    rb[j] = (short)f2bf(bv * cv[j] + av * sw[j]);
  }
  *(s8_t*)&X[base] = ra;
  *(s8_t*)&X[base + 64] = rb;
}

// ---------- fused attention: LDS-staged K/V, 8 waves, online softmax ----------
__global__ __launch_bounds__(512, 4) void k_attn(
    const unsigned short* __restrict__ Qg,
    const unsigned short* __restrict__ Kg,
    const unsigned short* __restrict__ Vt,
    unsigned short* __restrict__ Y) {
  const float scale = 0.08838834764831845f;
  const float L2E = 1.4426950408889634f;
  const int bid = blockIdx.x;
  const int wg = (bid & 7) * 64 + (bid >> 3);
  const int bh = wg >> 3;
  const int b = bh >> 4, h = bh & 15;
  const int t = threadIdx.x;
  const int w = t >> 6, lane = t & 63;
  const int lr = lane & 15, lg = lane >> 4;
  const int q0 = (wg & 7) * 128 + w * 16;
  const unsigned short* Q  = Qg + (size_t)bh * 131072;
  const unsigned short* Kp = Kg + (size_t)bh * 131072;
  const unsigned short* Vp = Vt + (size_t)bh * 131072;
  __shared__ __align__(16) unsigned short Ks[64 * 128];
  __shared__ __align__(16) unsigned short Vs[128 * 64];
  __shared__ __align__(16) unsigned short Ps[8][16 * 72];   // stride 144B: 2-way banks
  unsigned short* Pw = Ps[w];

  bf8_t qf[4];
#pragma unroll
  for (int kk = 0; kk < 4; ++kk)
    qf[kk] = *(const bf8_t*)&Q[(size_t)(q0 + lr) * 128 + kk * 32 + lg * 8];

  f4_t o[8] = {};
  float m_run = -1e30f, l_run = 0.0f;

  for (int s0 = 0; s0 < 1024; s0 += 64) {
    __syncthreads();
#pragma unroll
    for (int i = 0; i < 2; ++i) {
      int idx = i * 512 + t;
      int s = idx >> 4, c = t & 15;
      GL16(Kp + (size_t)(s0 + s) * 128 + ((c ^ (s & 7)) * 8), Ks + (size_t)idx * 8);
    }
#pragma unroll
    for (int i = 0; i < 2; ++i) {
      int idx = i * 512 + t;
      int d = idx >> 3, c = t & 7;
      GL16(Vp + (size_t)d * 1024 + s0 + ((c ^ (d & 7)) * 8), Vs + (size_t)idx * 8);
    }
    __syncthreads();

    f4_t sf[4];
#pragma unroll
    for (int ss = 0; ss < 4; ++ss) {
      f4_t c = {0.0f, 0.0f, 0.0f, 0.0f};
#pragma unroll
      for (int kk = 0; kk < 4; ++kk) {
        bf8_t kf = *(const bf8_t*)&Ks[(ss * 16 + lr) * 128 + (((kk * 4 + lg) ^ (lr & 7)) * 8)];
        c = __builtin_amdgcn_mfma_f32_16x16x32_bf16(kf, qf[kk], c, 0, 0, 0);
      }
      sf[ss] = c;
    }
    float vmax = -1e30f;
#pragma unroll
    for (int ss = 0; ss < 4; ++ss)
#pragma unroll
      for (int j = 0; j < 4; ++j) vmax = fmaxf(vmax, sf[ss][j]);
    vmax = fmaxf(vmax, __shfl_xor(vmax, 16));
    vmax = fmaxf(vmax, __shfl_xor(vmax, 32));
    float m_new = fmaxf(m_run, vmax * scale);
    float ratio = exp2f((m_run - m_new) * L2E);
    float lsum = 0.0f;
    float ps[4][4];
#pragma unroll
    for (int ss = 0; ss < 4; ++ss)
#pragma unroll
      for (int j = 0; j < 4; ++j) {
        float pv = exp2f((sf[ss][j] * scale - m_new) * L2E);
        ps[ss][j] = pv; lsum += pv;
      }
    lsum += __shfl_xor(lsum, 16);
    lsum += __shfl_xor(lsum, 32);
    l_run = l_run * ratio + lsum;
    m_run = m_new;
    float rq[4];
#pragma unroll
    for (int j = 0; j < 4; ++j) rq[j] = __shfl(ratio, lg * 4 + j);
#pragma unroll
    for (int n = 0; n < 8; ++n)
#pragma unroll
      for (int j = 0; j < 4; ++j) o[n][j] *= rq[j];
#pragma unroll
    for (int ss = 0; ss < 4; ++ss) {
      s4_t pk;
      pk.x = (short)f2bf(ps[ss][0]); pk.y = (short)f2bf(ps[ss][1]);
      pk.z = (short)f2bf(ps[ss][2]); pk.w = (short)f2bf(ps[ss][3]);
      *(s4_t*)&Pw[lr * 72 + ss * 16 + lg * 4] = pk;
    }
    bf8_t pa0 = *(const bf8_t*)&Pw[lr * 72 + lg * 8];
    bf8_t pa1 = *(const bf8_t*)&Pw[lr * 72 + 32 + lg * 8];
#pragma unroll
    for (int n = 0; n < 8; ++n) {
      int d = n * 16 + lr;
      bf8_t v0 = *(const bf8_t*)&Vs[d * 64 + (((0 + lg) ^ (lr & 7)) * 8)];
      bf8_t v1 = *(const bf8_t*)&Vs[d * 64 + (((4 + lg) ^ (lr & 7)) * 8)];
      o[n] = __builtin_amdgcn_mfma_f32_16x16x32_bf16(pa0, v0, o[n], 0, 0, 0);
      o[n] = __builtin_amdgcn_mfma_f32_16x16x32_bf16(pa1, v1, o[n], 0, 0, 0);
    }
  }

  float linv[4];
#pragma unroll
  for (int j = 0; j < 4; ++j) linv[j] = 1.0f / __shfl(l_run, lg * 4 + j);
#pragma unroll
  for (int n = 0; n < 8; ++n)
#pragma unroll
    for (int j = 0; j < 4; ++j) {
      int qg = q0 + lg * 4 + j;
      Y[((size_t)b * 1024 + qg) * 2048 + h * 128 + n * 16 + lr] =
          f2bf(o[n][j] * linv[j]);
    }
}

// ---------- launch ----------
extern "C" void kernel_launch(void* const* d_in, const int* in_sizes, int n_in,
                              void* d_out, int out_size, void* d_ws, size_t ws_size,
                              hipStream_t stream) {
  const float* x  = (const float*)d_in[0];
  const float* dl = (const float*)d_in[1];
  const float* W[4] = {(const float*)d_in[2], (const float*)d_in[3],
                       (const float*)d_in[4], (const float*)d_in[5]};
  char* ws = (char*)d_ws;
  size_t off = 0;
  auto take = [&](size_t bytes) {
    void* p = ws + off; off += (bytes + 255) & ~(size_t)255; return p;
  };
  unsigned short* xb = (unsigned short*)take(8388608ull * 2);
  unsigned short* Wb[4];
  for (int i = 0; i < 4; ++i) Wb[i] = (unsigned short*)take(4194304ull * 2);
  unsigned short* qb = (unsigned short*)take(8388608ull * 2);
  unsigned short* kb = (unsigned short*)take(8388608ull * 2);
  unsigned short* vT = (unsigned short*)take(8388608ull * 2);
  unsigned short* y  = (unsigned short*)take(8388608ull * 2);
  float* u    = (float*)take(4ull * 4 * 16 * 1024 * 4);
  float* cosT = (float*)take(1024ull * 64 * 4);
  float* sinT = (float*)take(1024ull * 64 * 4);
  unsigned short* dlb = (unsigned short*)take(1048576ull * 2);
  if (off > ws_size) return;

  k_f32_to_bf16<<<8192, 256, 0, stream>>>(x, xb, 2097152);
  P4 pw;
  for (int i = 0; i < 4; ++i) { pw.in[i] = W[i]; pw.out[i] = Wb[i]; }
  k_f32_to_bf16_4<<<dim3(4096, 4), 256, 0, stream>>>(pw, 1048576);
  k_f32_to_bf16<<<1024, 256, 0, stream>>>(dl, dlb, 262144);
  k_rope_table<<<1024, 64, 0, stream>>>(cosT, sinT);
  k_lora_mfma<<<dim3(16, 4), 256, 0, stream>>>(xb, dlb, u, 0, 3);

  GArgs gq;
  gq.Bw0 = Wb[0]; gq.o0 = qb;    gq.m0_ = 0; gq.p0_ = 0;
  gq.Bw1 = Wb[1]; gq.o1 = kb;    gq.m1_ = 0; gq.p1_ = 1;
  gq.Bw2 = Wb[2]; gq.o2 = vT;    gq.m2_ = 1; gq.p2_ = 2;
  k_gemm<<<dim3(16, 32, 3), 256, 0, stream>>>(xb, gq, u, dl);

  k_rope<<<2048, 256, 0, stream>>>(qb, cosT, sinT);
  k_rope<<<2048, 256, 0, stream>>>(kb, cosT, sinT);
  k_attn<<<512, 512, 0, stream>>>(qb, kb, vT, y);
  k_lora_mfma<<<dim3(16, 4), 256, 0, stream>>>(y, dlb, u, 3, 1);

  GArgs go;
  go.Bw0 = Wb[3]; go.o0 = d_out; go.m0_ = 2; go.p0_ = 3;
  go.Bw1 = Wb[3]; go.o1 = d_out; go.m1_ = 2; go.p1_ = 3;
  go.Bw2 = Wb[3]; go.o2 = d_out; go.m2_ = 2; go.p2_ = 3;
  k_gemm<<<dim3(16, 32, 1), 256, 0, stream>>>(y, go, u, dl);
}

// Round 9
// 329.903 us; speedup vs baseline: 1.5972x; 1.0926x over previous
//
#include <hip/hip_runtime.h>
#include <cstdint>
#include <cstddef>

// ---------- types ----------
typedef __attribute__((ext_vector_type(8))) __bf16 bf8_t;
typedef __attribute__((ext_vector_type(8))) short s8_t;
typedef __attribute__((ext_vector_type(4))) short s4_t;
typedef __attribute__((ext_vector_type(4))) float f4_t;

__device__ __forceinline__ float bf2f(unsigned short h) {
  union { unsigned u; float f; } v; v.u = (unsigned)h << 16; return v.f;
}
__device__ __forceinline__ unsigned short f2bf(float f) {
  union { float f; unsigned u; } v; v.f = f;
  return (unsigned short)((v.u + 0x7FFFu + ((v.u >> 16) & 1u)) >> 16);
}

#define GL16(gp, lp) __builtin_amdgcn_global_load_lds( \
    (__attribute__((address_space(1))) void*)(gp),     \
    (__attribute__((address_space(3))) void*)(lp), 16, 0, 0)

// ---------- fused fp32 -> bf16 conversion (x, W0..3, dl in one launch) ----------
struct ConvArgs {
  const float* src[6];
  unsigned short* dst[6];
  int n4[6];
  int thr[5];   // cumulative block thresholds for segments 1..5
};
__global__ void k_conv_all(ConvArgs a) {
  int blk = blockIdx.x, seg = 0;
#pragma unroll
  for (int s = 0; s < 5; ++s) seg += (blk >= a.thr[s]);
  int base = (seg == 0) ? 0 : a.thr[seg - 1];
  int i = (blk - base) * 256 + threadIdx.x;
  if (i >= a.n4[seg]) return;
  float4 v = reinterpret_cast<const float4*>(a.src[seg])[i];
  s4_t o;
  o.x = (short)f2bf(v.x); o.y = (short)f2bf(v.y);
  o.z = (short)f2bf(v.z); o.w = (short)f2bf(v.w);
  reinterpret_cast<s4_t*>(a.dst[seg])[i] = o;
}

// ---------- RoPE cos/sin table ----------
__global__ void k_rope_table(float* __restrict__ cosT, float* __restrict__ sinT) {
  int t = blockIdx.x, d = threadIdx.x;            // 1024 x 64
  float inv = exp2f(-(float)d * (13.287712379549449f / 64.0f));
  float ang = (float)t * inv;
  cosT[t * 64 + d] = cosf(ang);
  sinT[t * 64 + d] = sinf(ang);
}

// ---------- LoRA u = X @ dA^T via MFMA, split-K (u: [2][B][4][16][1024] f32) ----
#define UOFF 262144
__global__ __launch_bounds__(256) void k_lora_mfma(
    const unsigned short* __restrict__ X,
    const unsigned short* __restrict__ dlb,
    float* __restrict__ u, int pstart, int pcount) {
  __shared__ __align__(16) unsigned short Xs[64 * 64];
  __shared__ __align__(16) unsigned short Da[64 * 64];
  const int t = threadIdx.x;
  const int b = blockIdx.y;
  const int z = blockIdx.z;          // K half
  const int m0 = blockIdx.x * 64;
  const int w = t >> 6, lane = t & 63, lr = lane & 15, lg = lane >> 4;
  const int nrow = pcount * 16;
  f4_t acc[4] = {};
  for (int k0 = z * 1024; k0 < z * 1024 + 1024; k0 += 64) {
    __syncthreads();
#pragma unroll
    for (int i = 0; i < 2; ++i) {
      int idx = i * 256 + t;
      int row = idx >> 3, c = idx & 7;
      GL16(X + ((size_t)b * 1024 + m0 + row) * 2048 + k0 + ((c ^ (row & 7)) * 8),
           Xs + (size_t)idx * 8);
      int ric = row < nrow ? row : nrow - 1;
      int g = (pstart + (ric >> 4)) * 32 + (ric & 15);
      GL16(dlb + ((size_t)b * 128 + g) * 2048 + k0 + ((c ^ (ric & 7)) * 8),
           Da + (size_t)idx * 8);
    }
    __syncthreads();
#pragma unroll
    for (int kk = 0; kk < 2; ++kk) {
      bf8_t af = *(const bf8_t*)&Xs[(w * 16 + lr) * 64 + (((kk * 4 + lg) ^ (lr & 7)) * 8)];
#pragma unroll
      for (int n = 0; n < 4; ++n) {
        if (n < pcount) {
          bf8_t bfv = *(const bf8_t*)&Da[(n * 16 + lr) * 64 + (((kk * 4 + lg) ^ (lr & 7)) * 8)];
          acc[n] = __builtin_amdgcn_mfma_f32_16x16x32_bf16(af, bfv, acc[n], 0, 0, 0);
        }
      }
    }
  }
#pragma unroll
  for (int n = 0; n < 4; ++n) {
    if (n < pcount) {
#pragma unroll
      for (int j = 0; j < 4; ++j)
        u[(size_t)z * UOFF +
          (((size_t)b * 4 + pstart + n) * 16 + lr) * 1024 + m0 + w * 16 + lg * 4 + j] = acc[n][j];
    }
  }
}

// ---------- 128x128 bf16 GEMM, 2-phase m97 structure + XOR swizzle + LoRA ----
struct GArgs {
  const unsigned short *Bw0, *Bw1, *Bw2;
  void *o0, *o1, *o2;
  int m0_, m1_, m2_;
  int p0_, p1_, p2_;
};
#define BM 128
#define BN 128
#define BKK 64
__global__ __launch_bounds__(256, 2) void k_gemm(
    const unsigned short* __restrict__ A,
    GArgs ga,
    const float* __restrict__ u,
    const float* __restrict__ dl) {
  constexpr int K = 2048;
  const int z = blockIdx.z;
  const unsigned short* Bw = z == 0 ? ga.Bw0 : (z == 1 ? ga.Bw1 : ga.Bw2);
  void* outv = z == 0 ? ga.o0 : (z == 1 ? ga.o1 : ga.o2);
  const int mode = z == 0 ? ga.m0_ : (z == 1 ? ga.m1_ : ga.m2_);
  const int p = z == 0 ? ga.p0_ : (z == 1 ? ga.p1_ : ga.p2_);
  __shared__ unsigned short As[BM * BKK];   // 16 KB
  __shared__ unsigned short Bs[BN * BKK];   // 16 KB
  const int t = threadIdx.x;
  const int m0 = blockIdx.y * BM;
  const int n0 = blockIdx.x * BN;
  const int lane = t & 63;
  const int w = t >> 6;
  const int wr = (w >> 1) * 64, wc = (w & 1) * 64;
  const int lr = lane & 15;
  const int lg = lane >> 4;
  const int srow = t >> 3;
  const int sdst = (t & 7) * 8;
  const int ssrc = ((t & 7) ^ (srow & 7)) * 8;
  f4_t acc[4][4] = {};

  for (int k0 = 0; k0 < K; k0 += BKK) {
#pragma unroll
    for (int j = 0; j < 4; ++j) {
      int row = j * 32 + srow;
      GL16(A  + (size_t)(m0 + row) * K + k0 + ssrc, As + row * BKK + sdst);
      GL16(Bw + (size_t)(n0 + row) * K + k0 + ssrc, Bs + row * BKK + sdst);
    }
    __syncthreads();
#pragma unroll
    for (int kk = 0; kk < 2; ++kk) {
      bf8_t af[4], bfr[4];
#pragma unroll
      for (int m = 0; m < 4; ++m) {
        int row_ = wr + m * 16 + lr;
        af[m] = *(const bf8_t*)&As[row_ * BKK + (((kk * 4 + lg) ^ (lr & 7)) * 8)];
      }
#pragma unroll
      for (int n = 0; n < 4; ++n) {
        int row_ = wc + n * 16 + lr;
        bfr[n] = *(const bf8_t*)&Bs[row_ * BKK + (((kk * 4 + lg) ^ (lr & 7)) * 8)];
      }
#pragma unroll
      for (int m = 0; m < 4; ++m)
#pragma unroll
        for (int n = 0; n < 4; ++n)
          acc[m][n] = __builtin_amdgcn_mfma_f32_16x16x32_bf16(af[m], bfr[n], acc[m][n], 0, 0, 0);
    }
    __syncthreads();
  }

  // LoRA rank-16 as one zero-padded K=32 MFMA step (sum of both u K-halves)
  const int b = m0 >> 10;
  const int t0r = m0 & 1023;
  for (int idx = t; idx < 128 * 32; idx += 256) {
    int rr = idx >> 5, r = idx & 31;
    float val = 0.0f;
    if (r < 16) {
      size_t ub = (((size_t)b * 4 + p) * 16 + r) * 1024 + t0r + rr;
      val = u[ub] + u[UOFF + ub];
    }
    As[rr * 32 + r] = f2bf(val);
  }
  for (int idx = t; idx < 128 * 32; idx += 256) {
    int cc = idx >> 5, r = idx & 31;
    float val = (r < 16) ? dl[((size_t)b * 128 + p * 32 + 16 + r) * 2048 + n0 + cc] : 0.0f;
    Bs[cc * 32 + r] = f2bf(val);
  }
  __syncthreads();
  {
    bf8_t af[4], bfr[4];
#pragma unroll
    for (int m = 0; m < 4; ++m)
      af[m] = *(const bf8_t*)&As[(wr + m * 16 + lr) * 32 + lg * 8];
#pragma unroll
    for (int n = 0; n < 4; ++n)
      bfr[n] = *(const bf8_t*)&Bs[(wc + n * 16 + lr) * 32 + lg * 8];
#pragma unroll
    for (int m = 0; m < 4; ++m)
#pragma unroll
      for (int n = 0; n < 4; ++n)
        acc[m][n] = __builtin_amdgcn_mfma_f32_16x16x32_bf16(af[m], bfr[n], acc[m][n], 0, 0, 0);
  }

  // write C (C/D map: col = lane&15, row = (lane>>4)*4 + reg)
  unsigned short* out16 = (unsigned short*)outv;
  float* out32 = (float*)outv;
#pragma unroll
  for (int m = 0; m < 4; ++m) {
    int ri = wr + m * 16 + lg * 4;
#pragma unroll
    for (int j = 0; j < 4; ++j) {
      int grow = m0 + ri + j;
      int gb = grow >> 10, gt = grow & 1023;
#pragma unroll
      for (int n = 0; n < 4; ++n) {
        int gcol = n0 + wc + n * 16 + lr;
        float fv = acc[m][n][j];
        if (mode == 0) {
          size_t dst = (((size_t)gb * 16 + (gcol >> 7)) * 1024 + gt) * 128 + (gcol & 127);
          out16[dst] = f2bf(fv);
        } else if (mode == 1) {
          size_t dst = (((size_t)gb * 16 + (gcol >> 7)) * 128 + (gcol & 127)) * 1024 + gt;
          out16[dst] = f2bf(fv);
        } else {
          out32[(size_t)grow * 2048 + gcol] = fv;
        }
      }
    }
  }
}

// ---------- in-place RoPE on q AND k (B,H,T,128) bf16, one launch ----------
__global__ void k_rope2(unsigned short* __restrict__ Xq,
                        unsigned short* __restrict__ Xk,
                        const float* __restrict__ cosT, const float* __restrict__ sinT) {
  int gb = blockIdx.x;                          // 0..4095
  unsigned short* X = (gb < 2048) ? Xq : Xk;
  int idx = (gb & 2047) * 256 + threadIdx.x;
  int d0 = (idx & 7) * 8;
  int tt = (idx >> 3) & 1023;
  size_t base = (size_t)(idx >> 3) * 128 + d0;
  s8_t a = *(s8_t*)&X[base];
  s8_t bb = *(s8_t*)&X[base + 64];
  float4 c0 = *(const float4*)&cosT[tt * 64 + d0];
  float4 c1 = *(const float4*)&cosT[tt * 64 + d0 + 4];
  float4 sv0 = *(const float4*)&sinT[tt * 64 + d0];
  float4 sv1 = *(const float4*)&sinT[tt * 64 + d0 + 4];
  float cv[8] = {c0.x, c0.y, c0.z, c0.w, c1.x, c1.y, c1.z, c1.w};
  float sw[8] = {sv0.x, sv0.y, sv0.z, sv0.w, sv1.x, sv1.y, sv1.z, sv1.w};
  s8_t ra, rb;
#pragma unroll
  for (int j = 0; j < 8; ++j) {
    float av = bf2f((unsigned short)a[j]);
    float bv = bf2f((unsigned short)bb[j]);
    ra[j] = (short)f2bf(av * cv[j] - bv * sw[j]);
    rb[j] = (short)f2bf(bv * cv[j] + av * sw[j]);
  }
  *(s8_t*)&X[base] = ra;
  *(s8_t*)&X[base + 64] = rb;
}

// ---------- fused attention: reg-staged K/V prefetch (T14), raw barriers ----------
__global__ __launch_bounds__(512, 4) void k_attn(
    const unsigned short* __restrict__ Qg,
    const unsigned short* __restrict__ Kg,
    const unsigned short* __restrict__ Vt,
    unsigned short* __restrict__ Y) {
  const float scale = 0.08838834764831845f;
  const float L2E = 1.4426950408889634f;
  const int bid = blockIdx.x;
  const int wg = (bid & 7) * 64 + (bid >> 3);
  const int bh = wg >> 3;
  const int b = bh >> 4, h = bh & 15;
  const int t = threadIdx.x;
  const int w = t >> 6, lane = t & 63;
  const int lr = lane & 15, lg = lane >> 4;
  const int q0 = (wg & 7) * 128 + w * 16;
  const unsigned short* Q  = Qg + (size_t)bh * 131072;
  const unsigned short* Kp = Kg + (size_t)bh * 131072;
  const unsigned short* Vp = Vt + (size_t)bh * 131072;
  __shared__ __align__(16) unsigned short Ks[64 * 128];
  __shared__ __align__(16) unsigned short Vs[128 * 64];
  __shared__ __align__(16) unsigned short Ps[8][16 * 72];
  unsigned short* Pw = Ps[w];

  bf8_t qf[4];
#pragma unroll
  for (int kk = 0; kk < 4; ++kk)
    qf[kk] = *(const bf8_t*)&Q[(size_t)(q0 + lr) * 128 + kk * 32 + lg * 8];

  f4_t o[8] = {};
  float m_run = -1e30f, l_run = 0.0f;

  // reg-staged prefetch: load tile s0 K/V to VGPRs, ds_write at tile start
  auto ldK = [&](int s0, int i) {
    int idx = i * 512 + t, s = idx >> 4, c = t & 15;
    return *(const s8_t*)&Kp[(size_t)(s0 + s) * 128 + ((c ^ (s & 7)) * 8)];
  };
  auto ldV = [&](int s0, int i) {
    int idx = i * 512 + t, d = idx >> 3, c = t & 7;
    return *(const s8_t*)&Vp[(size_t)d * 1024 + s0 + ((c ^ (d & 7)) * 8)];
  };
  s8_t kr0 = ldK(0, 0), kr1 = ldK(0, 1), vr0 = ldV(0, 0), vr1 = ldV(0, 1);

  for (int s0 = 0; s0 < 1024; s0 += 64) {
    __builtin_amdgcn_s_barrier();          // all waves done reading prev tile
    *(s8_t*)&Ks[((size_t)t) * 8]        = kr0;
    *(s8_t*)&Ks[((size_t)512 + t) * 8]  = kr1;
    *(s8_t*)&Vs[((size_t)t) * 8]        = vr0;
    *(s8_t*)&Vs[((size_t)512 + t) * 8]  = vr1;
    int sn = (s0 < 960) ? s0 + 64 : 0;     // clamped redundant last prefetch
    kr0 = ldK(sn, 0); kr1 = ldK(sn, 1); vr0 = ldV(sn, 0); vr1 = ldV(sn, 1);
    asm volatile("s_waitcnt lgkmcnt(0)" ::: "memory");  // ds_writes done; loads stay in flight
    __builtin_amdgcn_s_barrier();          // writes visible to all waves

    f4_t sf[4];
#pragma unroll
    for (int ss = 0; ss < 4; ++ss) {
      f4_t c = {0.0f, 0.0f, 0.0f, 0.0f};
#pragma unroll
      for (int kk = 0; kk < 4; ++kk) {
        bf8_t kf = *(const bf8_t*)&Ks[(ss * 16 + lr) * 128 + (((kk * 4 + lg) ^ (lr & 7)) * 8)];
        c = __builtin_amdgcn_mfma_f32_16x16x32_bf16(kf, qf[kk], c, 0, 0, 0);
      }
      sf[ss] = c;
    }
    float vmax = -1e30f;
#pragma unroll
    for (int ss = 0; ss < 4; ++ss)
#pragma unroll
      for (int j = 0; j < 4; ++j) vmax = fmaxf(vmax, sf[ss][j]);
    vmax = fmaxf(vmax, __shfl_xor(vmax, 16));
    vmax = fmaxf(vmax, __shfl_xor(vmax, 32));
    float m_new = fmaxf(m_run, vmax * scale);
    float ratio = exp2f((m_run - m_new) * L2E);
    float lsum = 0.0f;
    float ps[4][4];
#pragma unroll
    for (int ss = 0; ss < 4; ++ss)
#pragma unroll
      for (int j = 0; j < 4; ++j) {
        float pv = exp2f((sf[ss][j] * scale - m_new) * L2E);
        ps[ss][j] = pv; lsum += pv;
      }
    lsum += __shfl_xor(lsum, 16);
    lsum += __shfl_xor(lsum, 32);
    l_run = l_run * ratio + lsum;
    m_run = m_new;
    float rq[4];
#pragma unroll
    for (int j = 0; j < 4; ++j) rq[j] = __shfl(ratio, lg * 4 + j);
#pragma unroll
    for (int n = 0; n < 8; ++n)
#pragma unroll
      for (int j = 0; j < 4; ++j) o[n][j] *= rq[j];
#pragma unroll
    for (int ss = 0; ss < 4; ++ss) {
      s4_t pk;
      pk.x = (short)f2bf(ps[ss][0]); pk.y = (short)f2bf(ps[ss][1]);
      pk.z = (short)f2bf(ps[ss][2]); pk.w = (short)f2bf(ps[ss][3]);
      *(s4_t*)&Pw[lr * 72 + ss * 16 + lg * 4] = pk;
    }
    bf8_t pa0 = *(const bf8_t*)&Pw[lr * 72 + lg * 8];
    bf8_t pa1 = *(const bf8_t*)&Pw[lr * 72 + 32 + lg * 8];
#pragma unroll
    for (int n = 0; n < 8; ++n) {
      int d = n * 16 + lr;
      bf8_t v0 = *(const bf8_t*)&Vs[d * 64 + (((0 + lg) ^ (lr & 7)) * 8)];
      bf8_t v1 = *(const bf8_t*)&Vs[d * 64 + (((4 + lg) ^ (lr & 7)) * 8)];
      o[n] = __builtin_amdgcn_mfma_f32_16x16x32_bf16(pa0, v0, o[n], 0, 0, 0);
      o[n] = __builtin_amdgcn_mfma_f32_16x16x32_bf16(pa1, v1, o[n], 0, 0, 0);
    }
  }

  float linv[4];
#pragma unroll
  for (int j = 0; j < 4; ++j) linv[j] = 1.0f / __shfl(l_run, lg * 4 + j);
#pragma unroll
  for (int n = 0; n < 8; ++n)
#pragma unroll
    for (int j = 0; j < 4; ++j) {
      int qg = q0 + lg * 4 + j;
      Y[((size_t)b * 1024 + qg) * 2048 + h * 128 + n * 16 + lr] =
          f2bf(o[n][j] * linv[j]);
    }
}

// ---------- launch ----------
extern "C" void kernel_launch(void* const* d_in, const int* in_sizes, int n_in,
                              void* d_out, int out_size, void* d_ws, size_t ws_size,
                              hipStream_t stream) {
  const float* x  = (const float*)d_in[0];
  const float* dl = (const float*)d_in[1];
  const float* W[4] = {(const float*)d_in[2], (const float*)d_in[3],
                       (const float*)d_in[4], (const float*)d_in[5]};
  char* ws = (char*)d_ws;
  size_t off = 0;
  auto take = [&](size_t bytes) {
    void* p = ws + off; off += (bytes + 255) & ~(size_t)255; return p;
  };
  unsigned short* xb = (unsigned short*)take(8388608ull * 2);
  unsigned short* Wb[4];
  for (int i = 0; i < 4; ++i) Wb[i] = (unsigned short*)take(4194304ull * 2);
  unsigned short* qb = (unsigned short*)take(8388608ull * 2);
  unsigned short* kb = (unsigned short*)take(8388608ull * 2);
  unsigned short* vT = (unsigned short*)take(8388608ull * 2);
  unsigned short* y  = (unsigned short*)take(8388608ull * 2);
  float* u    = (float*)take(2ull * UOFF * 4);
  float* cosT = (float*)take(1024ull * 64 * 4);
  float* sinT = (float*)take(1024ull * 64 * 4);
  unsigned short* dlb = (unsigned short*)take(1048576ull * 2);
  if (off > ws_size) return;

  ConvArgs ca;
  ca.src[0] = x;  ca.dst[0] = xb;  ca.n4[0] = 2097152;
  for (int i = 0; i < 4; ++i) { ca.src[1 + i] = W[i]; ca.dst[1 + i] = Wb[i]; ca.n4[1 + i] = 1048576; }
  ca.src[5] = dl; ca.dst[5] = dlb; ca.n4[5] = 262144;
  ca.thr[0] = 8192; ca.thr[1] = 12288; ca.thr[2] = 16384; ca.thr[3] = 20480; ca.thr[4] = 24576;
  k_conv_all<<<25600, 256, 0, stream>>>(ca);
  k_rope_table<<<1024, 64, 0, stream>>>(cosT, sinT);
  k_lora_mfma<<<dim3(16, 4, 2), 256, 0, stream>>>(xb, dlb, u, 0, 3);

  GArgs gq;
  gq.Bw0 = Wb[0]; gq.o0 = qb;    gq.m0_ = 0; gq.p0_ = 0;
  gq.Bw1 = Wb[1]; gq.o1 = kb;    gq.m1_ = 0; gq.p1_ = 1;
  gq.Bw2 = Wb[2]; gq.o2 = vT;    gq.m2_ = 1; gq.p2_ = 2;
  k_gemm<<<dim3(16, 32, 3), 256, 0, stream>>>(xb, gq, u, dl);

  k_rope2<<<4096, 256, 0, stream>>>(qb, kb, cosT, sinT);
  k_attn<<<512, 512, 0, stream>>>(qb, kb, vT, y);
  k_lora_mfma<<<dim3(16, 4, 2), 256, 0, stream>>>(y, dlb, u, 3, 1);

  GArgs go;
  go.Bw0 = Wb[3]; go.o0 = d_out; go.m0_ = 2; go.p0_ = 3;
  go.Bw1 = Wb[3]; go.o1 = d_out; go.m1_ = 2; go.p1_ = 3;
  go.Bw2 = Wb[3]; go.o2 = d_out; go.m2_ = 2; go.p2_ = 3;
  k_gemm<<<dim3(16, 32, 1), 256, 0, stream>>>(y, go, u, dl);
}

// Round 11
// 312.300 us; speedup vs baseline: 1.6872x; 1.0564x over previous
//
#include <hip/hip_runtime.h>
#include <cstdint>
#include <cstddef>

// ---------- types ----------
typedef __attribute__((ext_vector_type(8))) __bf16 bf8_t;
typedef __attribute__((ext_vector_type(8))) short s8_t;
typedef __attribute__((ext_vector_type(4))) short s4_t;
typedef __attribute__((ext_vector_type(4))) float f4_t;

__device__ __forceinline__ float bf2f(unsigned short h) {
  union { unsigned u; float f; } v; v.u = (unsigned)h << 16; return v.f;
}
__device__ __forceinline__ unsigned short f2bf(float f) {
  union { float f; unsigned u; } v; v.f = f;
  return (unsigned short)((v.u + 0x7FFFu + ((v.u >> 16) & 1u)) >> 16);
}

#define GL16(gp, lp) __builtin_amdgcn_global_load_lds( \
    (__attribute__((address_space(1))) void*)(gp),     \
    (__attribute__((address_space(3))) void*)(lp), 16, 0, 0)

// ---------- fused fp32 -> bf16 conversion (x, W0..3, dl in one launch) ----------
struct ConvArgs {
  const float* src[6];
  unsigned short* dst[6];
  int n4[6];
  int thr[5];
};
__global__ void k_conv_all(ConvArgs a) {
  int blk = blockIdx.x, seg = 0;
#pragma unroll
  for (int s = 0; s < 5; ++s) seg += (blk >= a.thr[s]);
  int base = (seg == 0) ? 0 : a.thr[seg - 1];
  int i = (blk - base) * 256 + threadIdx.x;
  if (i >= a.n4[seg]) return;
  float4 v = reinterpret_cast<const float4*>(a.src[seg])[i];
  s4_t o;
  o.x = (short)f2bf(v.x); o.y = (short)f2bf(v.y);
  o.z = (short)f2bf(v.z); o.w = (short)f2bf(v.w);
  reinterpret_cast<s4_t*>(a.dst[seg])[i] = o;
}

// ---------- RoPE cos/sin table ----------
__global__ void k_rope_table(float* __restrict__ cosT, float* __restrict__ sinT) {
  int t = blockIdx.x, d = threadIdx.x;            // 1024 x 64
  float inv = exp2f(-(float)d * (13.287712379549449f / 64.0f));
  float ang = (float)t * inv;
  cosT[t * 64 + d] = cosf(ang);
  sinT[t * 64 + d] = sinf(ang);
}

// ---------- LoRA u = X @ dA^T via MFMA, split-K (u: [2][B][4][16][1024] f32) ----
#define UOFF 262144
__global__ __launch_bounds__(256) void k_lora_mfma(
    const unsigned short* __restrict__ X,
    const unsigned short* __restrict__ dlb,
    float* __restrict__ u, int pstart, int pcount) {
  __shared__ __align__(16) unsigned short Xs[64 * 64];
  __shared__ __align__(16) unsigned short Da[64 * 64];
  const int t = threadIdx.x;
  const int b = blockIdx.y;
  const int z = blockIdx.z;          // K half
  const int m0 = blockIdx.x * 64;
  const int w = t >> 6, lane = t & 63, lr = lane & 15, lg = lane >> 4;
  const int nrow = pcount * 16;
  f4_t acc[4] = {};
  for (int k0 = z * 1024; k0 < z * 1024 + 1024; k0 += 64) {
    __syncthreads();
#pragma unroll
    for (int i = 0; i < 2; ++i) {
      int idx = i * 256 + t;
      int row = idx >> 3, c = idx & 7;
      GL16(X + ((size_t)b * 1024 + m0 + row) * 2048 + k0 + ((c ^ (row & 7)) * 8),
           Xs + (size_t)idx * 8);
      int ric = row < nrow ? row : nrow - 1;
      int g = (pstart + (ric >> 4)) * 32 + (ric & 15);
      GL16(dlb + ((size_t)b * 128 + g) * 2048 + k0 + ((c ^ (ric & 7)) * 8),
           Da + (size_t)idx * 8);
    }
    __syncthreads();
#pragma unroll
    for (int kk = 0; kk < 2; ++kk) {
      bf8_t af = *(const bf8_t*)&Xs[(w * 16 + lr) * 64 + (((kk * 4 + lg) ^ (lr & 7)) * 8)];
#pragma unroll
      for (int n = 0; n < 4; ++n) {
        if (n < pcount) {
          bf8_t bfv = *(const bf8_t*)&Da[(n * 16 + lr) * 64 + (((kk * 4 + lg) ^ (lr & 7)) * 8)];
          acc[n] = __builtin_amdgcn_mfma_f32_16x16x32_bf16(af, bfv, acc[n], 0, 0, 0);
        }
      }
    }
  }
#pragma unroll
  for (int n = 0; n < 4; ++n) {
    if (n < pcount) {
#pragma unroll
      for (int j = 0; j < 4; ++j)
        u[(size_t)z * UOFF +
          (((size_t)b * 4 + pstart + n) * 16 + lr) * 1024 + m0 + w * 16 + lg * 4 + j] = acc[n][j];
    }
  }
}

// ---------- 128x128 bf16 GEMM, 2-phase + XOR swizzle + XCD chunking + LoRA ----
struct GArgs {
  const unsigned short *Bw0, *Bw1, *Bw2;
  void *o0, *o1, *o2;
  int m0_, m1_, m2_;
  int p0_, p1_, p2_;
};
#define BM 128
#define BN 128
#define BKK 64
__global__ __launch_bounds__(256, 2) void k_gemm(
    const unsigned short* __restrict__ A,
    GArgs ga,
    const float* __restrict__ u,
    const float* __restrict__ dl) {
  constexpr int K = 2048;
  const int z = blockIdx.z;
  const unsigned short* Bw = z == 0 ? ga.Bw0 : (z == 1 ? ga.Bw1 : ga.Bw2);
  void* outv = z == 0 ? ga.o0 : (z == 1 ? ga.o1 : ga.o2);
  const int mode = z == 0 ? ga.m0_ : (z == 1 ? ga.m1_ : ga.m2_);
  const int p = z == 0 ? ga.p0_ : (z == 1 ? ga.p1_ : ga.p2_);
  __shared__ unsigned short As[BM * BKK];   // 16 KB
  __shared__ unsigned short Bs[BN * BKK];   // 16 KB
  const int t = threadIdx.x;
  // XCD-chunked remap: XCD c (= lin%8) gets an 8n x 8m chunk.
  const int lin = (int)blockIdx.x + ((int)blockIdx.y << 4);
  const int xcd = lin & 7, rnk = lin >> 3;
  const int m0 = (((xcd >> 1) << 3) | (rnk >> 3)) * BM;
  const int n0 = (((xcd & 1) << 3) | (rnk & 7)) * BN;
  const int lane = t & 63;
  const int w = t >> 6;
  const int wr = (w >> 1) * 64, wc = (w & 1) * 64;
  const int lr = lane & 15;
  const int lg = lane >> 4;
  const int srow = t >> 3;
  const int sdst = (t & 7) * 8;
  const int ssrc = ((t & 7) ^ (srow & 7)) * 8;
  f4_t acc[4][4] = {};

  for (int k0 = 0; k0 < K; k0 += BKK) {
#pragma unroll
    for (int j = 0; j < 4; ++j) {
      int row = j * 32 + srow;
      GL16(A  + (size_t)(m0 + row) * K + k0 + ssrc, As + row * BKK + sdst);
      GL16(Bw + (size_t)(n0 + row) * K + k0 + ssrc, Bs + row * BKK + sdst);
    }
    __syncthreads();
#pragma unroll
    for (int kk = 0; kk < 2; ++kk) {
      bf8_t af[4], bfr[4];
#pragma unroll
      for (int m = 0; m < 4; ++m) {
        int row_ = wr + m * 16 + lr;
        af[m] = *(const bf8_t*)&As[row_ * BKK + (((kk * 4 + lg) ^ (lr & 7)) * 8)];
      }
#pragma unroll
      for (int n = 0; n < 4; ++n) {
        int row_ = wc + n * 16 + lr;
        bfr[n] = *(const bf8_t*)&Bs[row_ * BKK + (((kk * 4 + lg) ^ (lr & 7)) * 8)];
      }
#pragma unroll
      for (int m = 0; m < 4; ++m)
#pragma unroll
        for (int n = 0; n < 4; ++n)
          acc[m][n] = __builtin_amdgcn_mfma_f32_16x16x32_bf16(af[m], bfr[n], acc[m][n], 0, 0, 0);
    }
    __syncthreads();
  }

  // LoRA rank-16 as one zero-padded K=32 MFMA step (sum of both u K-halves)
  const int b = m0 >> 10;
  const int t0r = m0 & 1023;
  for (int idx = t; idx < 128 * 32; idx += 256) {
    int rr = idx >> 5, r = idx & 31;
    float val = 0.0f;
    if (r < 16) {
      size_t ub = (((size_t)b * 4 + p) * 16 + r) * 1024 + t0r + rr;
      val = u[ub] + u[UOFF + ub];
    }
    As[rr * 32 + r] = f2bf(val);
  }
  for (int idx = t; idx < 128 * 32; idx += 256) {
    int cc = idx >> 5, r = idx & 31;
    float val = (r < 16) ? dl[((size_t)b * 128 + p * 32 + 16 + r) * 2048 + n0 + cc] : 0.0f;
    Bs[cc * 32 + r] = f2bf(val);
  }
  __syncthreads();
  {
    bf8_t af[4], bfr[4];
#pragma unroll
    for (int m = 0; m < 4; ++m)
      af[m] = *(const bf8_t*)&As[(wr + m * 16 + lr) * 32 + lg * 8];
#pragma unroll
    for (int n = 0; n < 4; ++n)
      bfr[n] = *(const bf8_t*)&Bs[(wc + n * 16 + lr) * 32 + lg * 8];
#pragma unroll
    for (int m = 0; m < 4; ++m)
#pragma unroll
      for (int n = 0; n < 4; ++n)
        acc[m][n] = __builtin_amdgcn_mfma_f32_16x16x32_bf16(af[m], bfr[n], acc[m][n], 0, 0, 0);
  }

  // write C (C/D map: col = lane&15, row = (lane>>4)*4 + reg)
  unsigned short* out16 = (unsigned short*)outv;
  float* out32 = (float*)outv;
#pragma unroll
  for (int m = 0; m < 4; ++m) {
    int ri = wr + m * 16 + lg * 4;
#pragma unroll
    for (int j = 0; j < 4; ++j) {
      int grow = m0 + ri + j;
      int gb = grow >> 10, gt = grow & 1023;
#pragma unroll
      for (int n = 0; n < 4; ++n) {
        int gcol = n0 + wc + n * 16 + lr;
        float fv = acc[m][n][j];
        if (mode == 0) {
          size_t dst = (((size_t)gb * 16 + (gcol >> 7)) * 1024 + gt) * 128 + (gcol & 127);
          out16[dst] = f2bf(fv);
        } else if (mode == 1) {
          size_t dst = (((size_t)gb * 16 + (gcol >> 7)) * 128 + (gcol & 127)) * 1024 + gt;
          out16[dst] = f2bf(fv);
        } else {
          out32[(size_t)grow * 2048 + gcol] = fv;
        }
      }
    }
  }
}

// ---------- in-place RoPE on K only (B,H,T,128) bf16 ----------
__global__ void k_rope(unsigned short* __restrict__ X,
                       const float* __restrict__ cosT, const float* __restrict__ sinT) {
  int idx = blockIdx.x * 256 + threadIdx.x;
  int d0 = (idx & 7) * 8;
  int tt = (idx >> 3) & 1023;
  size_t base = (size_t)(idx >> 3) * 128 + d0;
  s8_t a = *(s8_t*)&X[base];
  s8_t bb = *(s8_t*)&X[base + 64];
  float4 c0 = *(const float4*)&cosT[tt * 64 + d0];
  float4 c1 = *(const float4*)&cosT[tt * 64 + d0 + 4];
  float4 sv0 = *(const float4*)&sinT[tt * 64 + d0];
  float4 sv1 = *(const float4*)&sinT[tt * 64 + d0 + 4];
  float cv[8] = {c0.x, c0.y, c0.z, c0.w, c1.x, c1.y, c1.z, c1.w};
  float sw[8] = {sv0.x, sv0.y, sv0.z, sv0.w, sv1.x, sv1.y, sv1.z, sv1.w};
  s8_t ra, rb;
#pragma unroll
  for (int j = 0; j < 8; ++j) {
    float av = bf2f((unsigned short)a[j]);
    float bv = bf2f((unsigned short)bb[j]);
    ra[j] = (short)f2bf(av * cv[j] - bv * sw[j]);
    rb[j] = (short)f2bf(bv * cv[j] + av * sw[j]);
  }
  *(s8_t*)&X[base] = ra;
  *(s8_t*)&X[base + 64] = rb;
}

// ---------- fused attention: reg-staged prefetch + in-reg Q-RoPE + T5/T13 ----
__global__ __launch_bounds__(512, 4) void k_attn(
    const unsigned short* __restrict__ Qg,
    const unsigned short* __restrict__ Kg,
    const unsigned short* __restrict__ Vt,
    const float* __restrict__ cosT,
    const float* __restrict__ sinT,
    unsigned short* __restrict__ Y) {
  const float scale = 0.08838834764831845f;
  const float L2E = 1.4426950408889634f;
  const int bid = blockIdx.x;
  const int wg = (bid & 7) * 64 + (bid >> 3);
  const int bh = wg >> 3;
  const int b = bh >> 4, h = bh & 15;
  const int t = threadIdx.x;
  const int w = t >> 6, lane = t & 63;
  const int lr = lane & 15, lg = lane >> 4;
  const int q0 = (wg & 7) * 128 + w * 16;
  const unsigned short* Q  = Qg + (size_t)bh * 131072;
  const unsigned short* Kp = Kg + (size_t)bh * 131072;
  const unsigned short* Vp = Vt + (size_t)bh * 131072;
  __shared__ __align__(16) unsigned short Ks[64 * 128];
  __shared__ __align__(16) unsigned short Vs[128 * 64];
  __shared__ __align__(16) unsigned short Ps[8][16 * 72];   // stride 72 >= 64 cols!
  unsigned short* Pw = Ps[w];

  // Q load + in-register RoPE (pairs d<->d+64 are qs[0]<->qs[2], qs[1]<->qs[3])
  bf8_t qf[4];
  {
    s8_t qs[4];
#pragma unroll
    for (int kk = 0; kk < 4; ++kk)
      qs[kk] = *(const s8_t*)&Q[(size_t)(q0 + lr) * 128 + kk * 32 + lg * 8];
    const float* ct = cosT + (size_t)(q0 + lr) * 64 + lg * 8;
    const float* st = sinT + (size_t)(q0 + lr) * 64 + lg * 8;
    float4 cl0 = *(const float4*)ct,        cl1 = *(const float4*)(ct + 4);
    float4 ch0 = *(const float4*)(ct + 32), ch1 = *(const float4*)(ct + 36);
    float4 sl0 = *(const float4*)st,        sl1 = *(const float4*)(st + 4);
    float4 sh0 = *(const float4*)(st + 32), sh1 = *(const float4*)(st + 36);
    float cl[8] = {cl0.x, cl0.y, cl0.z, cl0.w, cl1.x, cl1.y, cl1.z, cl1.w};
    float ch[8] = {ch0.x, ch0.y, ch0.z, ch0.w, ch1.x, ch1.y, ch1.z, ch1.w};
    float sl[8] = {sl0.x, sl0.y, sl0.z, sl0.w, sl1.x, sl1.y, sl1.z, sl1.w};
    float sh[8] = {sh0.x, sh0.y, sh0.z, sh0.w, sh1.x, sh1.y, sh1.z, sh1.w};
    s8_t r0, r1, r2, r3;
#pragma unroll
    for (int e = 0; e < 8; ++e) {
      float x0 = bf2f((unsigned short)qs[0][e]);
      float x1 = bf2f((unsigned short)qs[1][e]);
      float x2 = bf2f((unsigned short)qs[2][e]);
      float x3 = bf2f((unsigned short)qs[3][e]);
      r0[e] = (short)f2bf(x0 * cl[e] - x2 * sl[e]);
      r1[e] = (short)f2bf(x1 * ch[e] - x3 * sh[e]);
      r2[e] = (short)f2bf(x2 * cl[e] + x0 * sl[e]);
      r3[e] = (short)f2bf(x3 * ch[e] + x1 * sh[e]);
    }
    qf[0] = *(bf8_t*)&r0; qf[1] = *(bf8_t*)&r1;
    qf[2] = *(bf8_t*)&r2; qf[3] = *(bf8_t*)&r3;
  }

  f4_t o[8] = {};
  float m_run = -1e30f, l_run = 0.0f;

  auto ldK = [&](int s0, int i) {
    int idx = i * 512 + t, s = idx >> 4, c = t & 15;
    return *(const s8_t*)&Kp[(size_t)(s0 + s) * 128 + ((c ^ (s & 7)) * 8)];
  };
  auto ldV = [&](int s0, int i) {
    int idx = i * 512 + t, d = idx >> 3, c = t & 7;
    return *(const s8_t*)&Vp[(size_t)d * 1024 + s0 + ((c ^ (d & 7)) * 8)];
  };
  s8_t kr0 = ldK(0, 0), kr1 = ldK(0, 1), vr0 = ldV(0, 0), vr1 = ldV(0, 1);

  for (int s0 = 0; s0 < 1024; s0 += 64) {
    __builtin_amdgcn_s_barrier();
    *(s8_t*)&Ks[((size_t)t) * 8]        = kr0;
    *(s8_t*)&Ks[((size_t)512 + t) * 8]  = kr1;
    *(s8_t*)&Vs[((size_t)t) * 8]        = vr0;
    *(s8_t*)&Vs[((size_t)512 + t) * 8]  = vr1;
    int sn = (s0 < 960) ? s0 + 64 : 0;
    kr0 = ldK(sn, 0); kr1 = ldK(sn, 1); vr0 = ldV(sn, 0); vr1 = ldV(sn, 1);
    asm volatile("s_waitcnt lgkmcnt(0)" ::: "memory");
    __builtin_amdgcn_s_barrier();

    f4_t sf[4];
    __builtin_amdgcn_s_setprio(1);
#pragma unroll
    for (int ss = 0; ss < 4; ++ss) {
      f4_t c = {0.0f, 0.0f, 0.0f, 0.0f};
#pragma unroll
      for (int kk = 0; kk < 4; ++kk) {
        bf8_t kf = *(const bf8_t*)&Ks[(ss * 16 + lr) * 128 + (((kk * 4 + lg) ^ (lr & 7)) * 8)];
        c = __builtin_amdgcn_mfma_f32_16x16x32_bf16(kf, qf[kk], c, 0, 0, 0);
      }
      sf[ss] = c;
    }
    __builtin_amdgcn_s_setprio(0);
    float vmax = -1e30f;
#pragma unroll
    for (int ss = 0; ss < 4; ++ss)
#pragma unroll
      for (int j = 0; j < 4; ++j) vmax = fmaxf(vmax, sf[ss][j]);
    vmax = fmaxf(vmax, __shfl_xor(vmax, 16));
    vmax = fmaxf(vmax, __shfl_xor(vmax, 32));
    float pmax = vmax * scale;
    // T13 defer-max: skip rescale while tile max stays within 8 of running max
    if (!__all(pmax - m_run <= 8.0f)) {
      float m_new = fmaxf(m_run, pmax);
      float ratio = exp2f((m_run - m_new) * L2E);
      l_run *= ratio;
      float rq[4];
#pragma unroll
      for (int j = 0; j < 4; ++j) rq[j] = __shfl(ratio, lg * 4 + j);
#pragma unroll
      for (int n = 0; n < 8; ++n)
#pragma unroll
        for (int j = 0; j < 4; ++j) o[n][j] *= rq[j];
      m_run = m_new;
    }
    float lsum = 0.0f;
    float ps[4][4];
#pragma unroll
    for (int ss = 0; ss < 4; ++ss)
#pragma unroll
      for (int j = 0; j < 4; ++j) {
        float pv = exp2f((sf[ss][j] * scale - m_run) * L2E);
        ps[ss][j] = pv; lsum += pv;
      }
    lsum += __shfl_xor(lsum, 16);
    lsum += __shfl_xor(lsum, 32);
    l_run += lsum;
#pragma unroll
    for (int ss = 0; ss < 4; ++ss) {
      s4_t pk;
      pk.x = (short)f2bf(ps[ss][0]); pk.y = (short)f2bf(ps[ss][1]);
      pk.z = (short)f2bf(ps[ss][2]); pk.w = (short)f2bf(ps[ss][3]);
      *(s4_t*)&Pw[lr * 72 + ss * 16 + lg * 4] = pk;
    }
    bf8_t pa0 = *(const bf8_t*)&Pw[lr * 72 + lg * 8];
    bf8_t pa1 = *(const bf8_t*)&Pw[lr * 72 + 32 + lg * 8];
    __builtin_amdgcn_s_setprio(1);
#pragma unroll
    for (int n = 0; n < 8; ++n) {
      int d = n * 16 + lr;
      bf8_t v0 = *(const bf8_t*)&Vs[d * 64 + (((0 + lg) ^ (lr & 7)) * 8)];
      bf8_t v1 = *(const bf8_t*)&Vs[d * 64 + (((4 + lg) ^ (lr & 7)) * 8)];
      o[n] = __builtin_amdgcn_mfma_f32_16x16x32_bf16(pa0, v0, o[n], 0, 0, 0);
      o[n] = __builtin_amdgcn_mfma_f32_16x16x32_bf16(pa1, v1, o[n], 0, 0, 0);
    }
    __builtin_amdgcn_s_setprio(0);
  }

  float linv[4];
#pragma unroll
  for (int j = 0; j < 4; ++j) linv[j] = 1.0f / __shfl(l_run, lg * 4 + j);
#pragma unroll
  for (int n = 0; n < 8; ++n)
#pragma unroll
    for (int j = 0; j < 4; ++j) {
      int qg = q0 + lg * 4 + j;
      Y[((size_t)b * 1024 + qg) * 2048 + h * 128 + n * 16 + lr] =
          f2bf(o[n][j] * linv[j]);
    }
}

// ---------- launch ----------
extern "C" void kernel_launch(void* const* d_in, const int* in_sizes, int n_in,
                              void* d_out, int out_size, void* d_ws, size_t ws_size,
                              hipStream_t stream) {
  const float* x  = (const float*)d_in[0];
  const float* dl = (const float*)d_in[1];
  const float* W[4] = {(const float*)d_in[2], (const float*)d_in[3],
                       (const float*)d_in[4], (const float*)d_in[5]};
  char* ws = (char*)d_ws;
  size_t off = 0;
  auto take = [&](size_t bytes) {
    void* p = ws + off; off += (bytes + 255) & ~(size_t)255; return p;
  };
  unsigned short* xb = (unsigned short*)take(8388608ull * 2);
  unsigned short* Wb[4];
  for (int i = 0; i < 4; ++i) Wb[i] = (unsigned short*)take(4194304ull * 2);
  unsigned short* qb = (unsigned short*)take(8388608ull * 2);
  unsigned short* kb = (unsigned short*)take(8388608ull * 2);
  unsigned short* vT = (unsigned short*)take(8388608ull * 2);
  unsigned short* y  = (unsigned short*)take(8388608ull * 2);
  float* u    = (float*)take(2ull * UOFF * 4);
  float* cosT = (float*)take(1024ull * 64 * 4);
  float* sinT = (float*)take(1024ull * 64 * 4);
  unsigned short* dlb = (unsigned short*)take(1048576ull * 2);
  if (off > ws_size) return;

  ConvArgs ca;
  ca.src[0] = x;  ca.dst[0] = xb;  ca.n4[0] = 2097152;
  for (int i = 0; i < 4; ++i) { ca.src[1 + i] = W[i]; ca.dst[1 + i] = Wb[i]; ca.n4[1 + i] = 1048576; }
  ca.src[5] = dl; ca.dst[5] = dlb; ca.n4[5] = 262144;
  ca.thr[0] = 8192; ca.thr[1] = 12288; ca.thr[2] = 16384; ca.thr[3] = 20480; ca.thr[4] = 24576;
  k_conv_all<<<25600, 256, 0, stream>>>(ca);
  k_rope_table<<<1024, 64, 0, stream>>>(cosT, sinT);
  k_lora_mfma<<<dim3(16, 4, 2), 256, 0, stream>>>(xb, dlb, u, 0, 3);

  GArgs gq;
  gq.Bw0 = Wb[0]; gq.o0 = qb;    gq.m0_ = 0; gq.p0_ = 0;
  gq.Bw1 = Wb[1]; gq.o1 = kb;    gq.m1_ = 0; gq.p1_ = 1;
  gq.Bw2 = Wb[2]; gq.o2 = vT;    gq.m2_ = 1; gq.p2_ = 2;
  k_gemm<<<dim3(16, 32, 3), 256, 0, stream>>>(xb, gq, u, dl);

  k_rope<<<2048, 256, 0, stream>>>(kb, cosT, sinT);
  k_attn<<<512, 512, 0, stream>>>(qb, kb, vT, cosT, sinT, y);
  k_lora_mfma<<<dim3(16, 4, 2), 256, 0, stream>>>(y, dlb, u, 3, 1);

  GArgs go;
  go.Bw0 = Wb[3]; go.o0 = d_out; go.m0_ = 2; go.p0_ = 3;
  go.Bw1 = Wb[3]; go.o1 = d_out; go.m1_ = 2; go.p1_ = 3;
  go.Bw2 = Wb[3]; go.o2 = d_out; go.m2_ = 2; go.p2_ = 3;
  k_gemm<<<dim3(16, 32, 1), 256, 0, stream>>>(y, go, u, dl);
}

// Round 12
// 308.672 us; speedup vs baseline: 1.7070x; 1.0118x over previous
//
#include <hip/hip_runtime.h>
#include <cstdint>
#include <cstddef>

// ---------- types ----------
typedef __attribute__((ext_vector_type(8))) __bf16 bf8_t;
typedef __attribute__((ext_vector_type(8))) short s8_t;
typedef __attribute__((ext_vector_type(4))) short s4_t;
typedef __attribute__((ext_vector_type(4))) float f4_t;

__device__ __forceinline__ float bf2f(unsigned short h) {
  union { unsigned u; float f; } v; v.u = (unsigned)h << 16; return v.f;
}
__device__ __forceinline__ unsigned short f2bf(float f) {
  union { float f; unsigned u; } v; v.f = f;
  return (unsigned short)((v.u + 0x7FFFu + ((v.u >> 16) & 1u)) >> 16);
}

#define GL16(gp, lp) __builtin_amdgcn_global_load_lds( \
    (__attribute__((address_space(1))) void*)(gp),     \
    (__attribute__((address_space(3))) void*)(lp), 16, 0, 0)

// ---------- fused fp32 -> bf16 conversion (x, W0..3, dl in one launch) ----------
struct ConvArgs {
  const float* src[6];
  unsigned short* dst[6];
  int n4[6];
  int thr[5];
};
__global__ void k_conv_all(ConvArgs a) {
  int blk = blockIdx.x, seg = 0;
#pragma unroll
  for (int s = 0; s < 5; ++s) seg += (blk >= a.thr[s]);
  int base = (seg == 0) ? 0 : a.thr[seg - 1];
  int i = (blk - base) * 256 + threadIdx.x;
  if (i >= a.n4[seg]) return;
  float4 v = reinterpret_cast<const float4*>(a.src[seg])[i];
  s4_t o;
  o.x = (short)f2bf(v.x); o.y = (short)f2bf(v.y);
  o.z = (short)f2bf(v.z); o.w = (short)f2bf(v.w);
  reinterpret_cast<s4_t*>(a.dst[seg])[i] = o;
}

// ---------- RoPE cos/sin table ----------
__global__ void k_rope_table(float* __restrict__ cosT, float* __restrict__ sinT) {
  int t = blockIdx.x, d = threadIdx.x;            // 1024 x 64
  float inv = exp2f(-(float)d * (13.287712379549449f / 64.0f));
  float ang = (float)t * inv;
  cosT[t * 64 + d] = cosf(ang);
  sinT[t * 64 + d] = sinf(ang);
}

// ---------- LoRA u = X @ dA^T via MFMA, split-K x4 (u: [4][B][4][16][1024]) ----
#define UOFF 262144
__global__ __launch_bounds__(256) void k_lora_mfma(
    const unsigned short* __restrict__ X,
    const unsigned short* __restrict__ dlb,
    float* __restrict__ u, int pstart, int pcount) {
  __shared__ __align__(16) unsigned short Xs[64 * 64];
  __shared__ __align__(16) unsigned short Da[64 * 64];
  const int t = threadIdx.x;
  const int b = blockIdx.y;
  const int z = blockIdx.z;          // K quarter
  const int m0 = blockIdx.x * 64;
  const int w = t >> 6, lane = t & 63, lr = lane & 15, lg = lane >> 4;
  const int nrow = pcount * 16;
  f4_t acc[4] = {};
  for (int k0 = z * 512; k0 < z * 512 + 512; k0 += 64) {
    __syncthreads();
#pragma unroll
    for (int i = 0; i < 2; ++i) {
      int idx = i * 256 + t;
      int row = idx >> 3, c = idx & 7;
      GL16(X + ((size_t)b * 1024 + m0 + row) * 2048 + k0 + ((c ^ (row & 7)) * 8),
           Xs + (size_t)idx * 8);
      int ric = row < nrow ? row : nrow - 1;
      int g = (pstart + (ric >> 4)) * 32 + (ric & 15);
      GL16(dlb + ((size_t)b * 128 + g) * 2048 + k0 + ((c ^ (ric & 7)) * 8),
           Da + (size_t)idx * 8);
    }
    __syncthreads();
#pragma unroll
    for (int kk = 0; kk < 2; ++kk) {
      bf8_t af = *(const bf8_t*)&Xs[(w * 16 + lr) * 64 + (((kk * 4 + lg) ^ (lr & 7)) * 8)];
#pragma unroll
      for (int n = 0; n < 4; ++n) {
        if (n < pcount) {
          bf8_t bfv = *(const bf8_t*)&Da[(n * 16 + lr) * 64 + (((kk * 4 + lg) ^ (lr & 7)) * 8)];
          acc[n] = __builtin_amdgcn_mfma_f32_16x16x32_bf16(af, bfv, acc[n], 0, 0, 0);
        }
      }
    }
  }
#pragma unroll
  for (int n = 0; n < 4; ++n) {
    if (n < pcount) {
#pragma unroll
      for (int j = 0; j < 4; ++j)
        u[(size_t)z * UOFF +
          (((size_t)b * 4 + pstart + n) * 16 + lr) * 1024 + m0 + w * 16 + lg * 4 + j] = acc[n][j];
    }
  }
}

// ---------- 128x128 bf16 GEMM, 2-phase + XOR swizzle + XCD chunking + LoRA ----
struct GArgs {
  const unsigned short *Bw0, *Bw1, *Bw2;
  void *o0, *o1, *o2;
  int m0_, m1_, m2_;
  int p0_, p1_, p2_;
};
#define BM 128
#define BN 128
#define BKK 64
__global__ __launch_bounds__(256, 2) void k_gemm(
    const unsigned short* __restrict__ A,
    GArgs ga,
    const float* __restrict__ u,
    const float* __restrict__ dl) {
  constexpr int K = 2048;
  const int z = blockIdx.z;
  const unsigned short* Bw = z == 0 ? ga.Bw0 : (z == 1 ? ga.Bw1 : ga.Bw2);
  void* outv = z == 0 ? ga.o0 : (z == 1 ? ga.o1 : ga.o2);
  const int mode = z == 0 ? ga.m0_ : (z == 1 ? ga.m1_ : ga.m2_);
  const int p = z == 0 ? ga.p0_ : (z == 1 ? ga.p1_ : ga.p2_);
  __shared__ unsigned short As[BM * BKK];   // 16 KB
  __shared__ unsigned short Bs[BN * BKK];   // 16 KB
  const int t = threadIdx.x;
  // XCD-chunked remap: XCD c (= lin%8) gets an 8n x 8m chunk.
  const int lin = (int)blockIdx.x + ((int)blockIdx.y << 4);
  const int xcd = lin & 7, rnk = lin >> 3;
  const int m0 = (((xcd >> 1) << 3) | (rnk >> 3)) * BM;
  const int n0 = (((xcd & 1) << 3) | (rnk & 7)) * BN;
  const int lane = t & 63;
  const int w = t >> 6;
  const int wr = (w >> 1) * 64, wc = (w & 1) * 64;
  const int lr = lane & 15;
  const int lg = lane >> 4;
  const int srow = t >> 3;
  const int sdst = (t & 7) * 8;
  const int ssrc = ((t & 7) ^ (srow & 7)) * 8;
  f4_t acc[4][4] = {};

  for (int k0 = 0; k0 < K; k0 += BKK) {
#pragma unroll
    for (int j = 0; j < 4; ++j) {
      int row = j * 32 + srow;
      GL16(A  + (size_t)(m0 + row) * K + k0 + ssrc, As + row * BKK + sdst);
      GL16(Bw + (size_t)(n0 + row) * K + k0 + ssrc, Bs + row * BKK + sdst);
    }
    __syncthreads();
#pragma unroll
    for (int kk = 0; kk < 2; ++kk) {
      bf8_t af[4], bfr[4];
#pragma unroll
      for (int m = 0; m < 4; ++m) {
        int row_ = wr + m * 16 + lr;
        af[m] = *(const bf8_t*)&As[row_ * BKK + (((kk * 4 + lg) ^ (lr & 7)) * 8)];
      }
#pragma unroll
      for (int n = 0; n < 4; ++n) {
        int row_ = wc + n * 16 + lr;
        bfr[n] = *(const bf8_t*)&Bs[row_ * BKK + (((kk * 4 + lg) ^ (lr & 7)) * 8)];
      }
#pragma unroll
      for (int m = 0; m < 4; ++m)
#pragma unroll
        for (int n = 0; n < 4; ++n)
          acc[m][n] = __builtin_amdgcn_mfma_f32_16x16x32_bf16(af[m], bfr[n], acc[m][n], 0, 0, 0);
    }
    __syncthreads();
  }

  // LoRA rank-16 as one zero-padded K=32 MFMA step (sum of 4 u K-quarters)
  const int b = m0 >> 10;
  const int t0r = m0 & 1023;
  for (int idx = t; idx < 128 * 32; idx += 256) {
    int rr = idx >> 5, r = idx & 31;
    float val = 0.0f;
    if (r < 16) {
      size_t ub = (((size_t)b * 4 + p) * 16 + r) * 1024 + t0r + rr;
      val = (u[ub] + u[UOFF + ub]) + (u[2 * UOFF + ub] + u[3 * UOFF + ub]);
    }
    As[rr * 32 + r] = f2bf(val);
  }
  for (int idx = t; idx < 128 * 32; idx += 256) {
    int cc = idx >> 5, r = idx & 31;
    float val = (r < 16) ? dl[((size_t)b * 128 + p * 32 + 16 + r) * 2048 + n0 + cc] : 0.0f;
    Bs[cc * 32 + r] = f2bf(val);
  }
  __syncthreads();
  {
    bf8_t af[4], bfr[4];
#pragma unroll
    for (int m = 0; m < 4; ++m)
      af[m] = *(const bf8_t*)&As[(wr + m * 16 + lr) * 32 + lg * 8];
#pragma unroll
    for (int n = 0; n < 4; ++n)
      bfr[n] = *(const bf8_t*)&Bs[(wc + n * 16 + lr) * 32 + lg * 8];
#pragma unroll
    for (int m = 0; m < 4; ++m)
#pragma unroll
      for (int n = 0; n < 4; ++n)
        acc[m][n] = __builtin_amdgcn_mfma_f32_16x16x32_bf16(af[m], bfr[n], acc[m][n], 0, 0, 0);
  }

  // write C (C/D map: col = lane&15, row = (lane>>4)*4 + reg)
  unsigned short* out16 = (unsigned short*)outv;
  float* out32 = (float*)outv;
#pragma unroll
  for (int m = 0; m < 4; ++m) {
    int ri = wr + m * 16 + lg * 4;
#pragma unroll
    for (int j = 0; j < 4; ++j) {
      int grow = m0 + ri + j;
      int gb = grow >> 10, gt = grow & 1023;
#pragma unroll
      for (int n = 0; n < 4; ++n) {
        int gcol = n0 + wc + n * 16 + lr;
        float fv = acc[m][n][j];
        if (mode == 0) {
          size_t dst = (((size_t)gb * 16 + (gcol >> 7)) * 1024 + gt) * 128 + (gcol & 127);
          out16[dst] = f2bf(fv);
        } else if (mode == 1) {
          size_t dst = (((size_t)gb * 16 + (gcol >> 7)) * 128 + (gcol & 127)) * 1024 + gt;
          out16[dst] = f2bf(fv);
        } else {
          out32[(size_t)grow * 2048 + gcol] = fv;
        }
      }
    }
  }
}

// ---------- in-place RoPE on K only (B,H,T,128) bf16 ----------
__global__ void k_rope(unsigned short* __restrict__ X,
                       const float* __restrict__ cosT, const float* __restrict__ sinT) {
  int idx = blockIdx.x * 256 + threadIdx.x;
  int d0 = (idx & 7) * 8;
  int tt = (idx >> 3) & 1023;
  size_t base = (size_t)(idx >> 3) * 128 + d0;
  s8_t a = *(s8_t*)&X[base];
  s8_t bb = *(s8_t*)&X[base + 64];
  float4 c0 = *(const float4*)&cosT[tt * 64 + d0];
  float4 c1 = *(const float4*)&cosT[tt * 64 + d0 + 4];
  float4 sv0 = *(const float4*)&sinT[tt * 64 + d0];
  float4 sv1 = *(const float4*)&sinT[tt * 64 + d0 + 4];
  float cv[8] = {c0.x, c0.y, c0.z, c0.w, c1.x, c1.y, c1.z, c1.w};
  float sw[8] = {sv0.x, sv0.y, sv0.z, sv0.w, sv1.x, sv1.y, sv1.z, sv1.w};
  s8_t ra, rb;
#pragma unroll
  for (int j = 0; j < 8; ++j) {
    float av = bf2f((unsigned short)a[j]);
    float bv = bf2f((unsigned short)bb[j]);
    ra[j] = (short)f2bf(av * cv[j] - bv * sw[j]);
    rb[j] = (short)f2bf(bv * cv[j] + av * sw[j]);
  }
  *(s8_t*)&X[base] = ra;
  *(s8_t*)&X[base + 64] = rb;
}

// ---------- fused attention: fixed-shift softmax (shift-invariance), ----------
// reg-staged prefetch, in-reg Q-RoPE, T5. m = const 12 >> max(S*scale)~5.9.
__global__ __launch_bounds__(512, 4) void k_attn(
    const unsigned short* __restrict__ Qg,
    const unsigned short* __restrict__ Kg,
    const unsigned short* __restrict__ Vt,
    const float* __restrict__ cosT,
    const float* __restrict__ sinT,
    unsigned short* __restrict__ Y) {
  const float scale = 0.08838834764831845f;
  const float L2E = 1.4426950408889634f;
  const float MFIX = 12.0f;
  const int bid = blockIdx.x;
  const int wg = (bid & 7) * 64 + (bid >> 3);
  const int bh = wg >> 3;
  const int b = bh >> 4, h = bh & 15;
  const int t = threadIdx.x;
  const int w = t >> 6, lane = t & 63;
  const int lr = lane & 15, lg = lane >> 4;
  const int q0 = (wg & 7) * 128 + w * 16;
  const unsigned short* Q  = Qg + (size_t)bh * 131072;
  const unsigned short* Kp = Kg + (size_t)bh * 131072;
  const unsigned short* Vp = Vt + (size_t)bh * 131072;
  __shared__ __align__(16) unsigned short Ks[64 * 128];
  __shared__ __align__(16) unsigned short Vs[128 * 64];
  __shared__ __align__(16) unsigned short Ps[8][16 * 72];
  unsigned short* Pw = Ps[w];

  // Q load + in-register RoPE (pairs d<->d+64 are qs[0]<->qs[2], qs[1]<->qs[3])
  bf8_t qf[4];
  {
    s8_t qs[4];
#pragma unroll
    for (int kk = 0; kk < 4; ++kk)
      qs[kk] = *(const s8_t*)&Q[(size_t)(q0 + lr) * 128 + kk * 32 + lg * 8];
    const float* ct = cosT + (size_t)(q0 + lr) * 64 + lg * 8;
    const float* st = sinT + (size_t)(q0 + lr) * 64 + lg * 8;
    float4 cl0 = *(const float4*)ct,        cl1 = *(const float4*)(ct + 4);
    float4 ch0 = *(const float4*)(ct + 32), ch1 = *(const float4*)(ct + 36);
    float4 sl0 = *(const float4*)st,        sl1 = *(const float4*)(st + 4);
    float4 sh0 = *(const float4*)(st + 32), sh1 = *(const float4*)(st + 36);
    float cl[8] = {cl0.x, cl0.y, cl0.z, cl0.w, cl1.x, cl1.y, cl1.z, cl1.w};
    float ch[8] = {ch0.x, ch0.y, ch0.z, ch0.w, ch1.x, ch1.y, ch1.z, ch1.w};
    float sl[8] = {sl0.x, sl0.y, sl0.z, sl0.w, sl1.x, sl1.y, sl1.z, sl1.w};
    float sh[8] = {sh0.x, sh0.y, sh0.z, sh0.w, sh1.x, sh1.y, sh1.z, sh1.w};
    s8_t r0, r1, r2, r3;
#pragma unroll
    for (int e = 0; e < 8; ++e) {
      float x0 = bf2f((unsigned short)qs[0][e]);
      float x1 = bf2f((unsigned short)qs[1][e]);
      float x2 = bf2f((unsigned short)qs[2][e]);
      float x3 = bf2f((unsigned short)qs[3][e]);
      r0[e] = (short)f2bf(x0 * cl[e] - x2 * sl[e]);
      r1[e] = (short)f2bf(x1 * ch[e] - x3 * sh[e]);
      r2[e] = (short)f2bf(x2 * cl[e] + x0 * sl[e]);
      r3[e] = (short)f2bf(x3 * ch[e] + x1 * sh[e]);
    }
    qf[0] = *(bf8_t*)&r0; qf[1] = *(bf8_t*)&r1;
    qf[2] = *(bf8_t*)&r2; qf[3] = *(bf8_t*)&r3;
  }

  f4_t o[8] = {};
  float l_part = 0.0f;   // per-lane partial sum; cross-lane reduce ONCE at end

  auto ldK = [&](int s0, int i) {
    int idx = i * 512 + t, s = idx >> 4, c = t & 15;
    return *(const s8_t*)&Kp[(size_t)(s0 + s) * 128 + ((c ^ (s & 7)) * 8)];
  };
  auto ldV = [&](int s0, int i) {
    int idx = i * 512 + t, d = idx >> 3, c = t & 7;
    return *(const s8_t*)&Vp[(size_t)d * 1024 + s0 + ((c ^ (d & 7)) * 8)];
  };
  s8_t kr0 = ldK(0, 0), kr1 = ldK(0, 1), vr0 = ldV(0, 0), vr1 = ldV(0, 1);

  for (int s0 = 0; s0 < 1024; s0 += 64) {
    __builtin_amdgcn_s_barrier();
    *(s8_t*)&Ks[((size_t)t) * 8]        = kr0;
    *(s8_t*)&Ks[((size_t)512 + t) * 8]  = kr1;
    *(s8_t*)&Vs[((size_t)t) * 8]        = vr0;
    *(s8_t*)&Vs[((size_t)512 + t) * 8]  = vr1;
    int sn = (s0 < 960) ? s0 + 64 : 0;
    kr0 = ldK(sn, 0); kr1 = ldK(sn, 1); vr0 = ldV(sn, 0); vr1 = ldV(sn, 1);
    asm volatile("s_waitcnt lgkmcnt(0)" ::: "memory");
    __builtin_amdgcn_s_barrier();

    f4_t sf[4];
    __builtin_amdgcn_s_setprio(1);
#pragma unroll
    for (int ss = 0; ss < 4; ++ss) {
      f4_t c = {0.0f, 0.0f, 0.0f, 0.0f};
#pragma unroll
      for (int kk = 0; kk < 4; ++kk) {
        bf8_t kf = *(const bf8_t*)&Ks[(ss * 16 + lr) * 128 + (((kk * 4 + lg) ^ (lr & 7)) * 8)];
        c = __builtin_amdgcn_mfma_f32_16x16x32_bf16(kf, qf[kk], c, 0, 0, 0);
      }
      sf[ss] = c;
    }
    __builtin_amdgcn_s_setprio(0);
    // fixed-shift softmax: P = exp2((S*scale - 12)*log2e); exact by shift-invariance
#pragma unroll
    for (int ss = 0; ss < 4; ++ss) {
      s4_t pk;
      float p0 = exp2f((sf[ss][0] * scale - MFIX) * L2E);
      float p1 = exp2f((sf[ss][1] * scale - MFIX) * L2E);
      float p2 = exp2f((sf[ss][2] * scale - MFIX) * L2E);
      float p3 = exp2f((sf[ss][3] * scale - MFIX) * L2E);
      l_part += (p0 + p1) + (p2 + p3);
      pk.x = (short)f2bf(p0); pk.y = (short)f2bf(p1);
      pk.z = (short)f2bf(p2); pk.w = (short)f2bf(p3);
      *(s4_t*)&Pw[lr * 72 + ss * 16 + lg * 4] = pk;
    }
    bf8_t pa0 = *(const bf8_t*)&Pw[lr * 72 + lg * 8];
    bf8_t pa1 = *(const bf8_t*)&Pw[lr * 72 + 32 + lg * 8];
    __builtin_amdgcn_s_setprio(1);
#pragma unroll
    for (int n = 0; n < 8; ++n) {
      int d = n * 16 + lr;
      bf8_t v0 = *(const bf8_t*)&Vs[d * 64 + (((0 + lg) ^ (lr & 7)) * 8)];
      bf8_t v1 = *(const bf8_t*)&Vs[d * 64 + (((4 + lg) ^ (lr & 7)) * 8)];
      o[n] = __builtin_amdgcn_mfma_f32_16x16x32_bf16(pa0, v0, o[n], 0, 0, 0);
      o[n] = __builtin_amdgcn_mfma_f32_16x16x32_bf16(pa1, v1, o[n], 0, 0, 0);
    }
    __builtin_amdgcn_s_setprio(0);
  }

  // single cross-lane l reduction (lanes {lr, lr+16, lr+32, lr+48} share q=lr)
  float l_tot = l_part;
  l_tot += __shfl_xor(l_tot, 16);
  l_tot += __shfl_xor(l_tot, 32);
  float linv[4];
#pragma unroll
  for (int j = 0; j < 4; ++j) linv[j] = 1.0f / __shfl(l_tot, lg * 4 + j);
#pragma unroll
  for (int n = 0; n < 8; ++n)
#pragma unroll
    for (int j = 0; j < 4; ++j) {
      int qg = q0 + lg * 4 + j;
      Y[((size_t)b * 1024 + qg) * 2048 + h * 128 + n * 16 + lr] =
          f2bf(o[n][j] * linv[j]);
    }
}

// ---------- launch ----------
extern "C" void kernel_launch(void* const* d_in, const int* in_sizes, int n_in,
                              void* d_out, int out_size, void* d_ws, size_t ws_size,
                              hipStream_t stream) {
  const float* x  = (const float*)d_in[0];
  const float* dl = (const float*)d_in[1];
  const float* W[4] = {(const float*)d_in[2], (const float*)d_in[3],
                       (const float*)d_in[4], (const float*)d_in[5]};
  char* ws = (char*)d_ws;
  size_t off = 0;
  auto take = [&](size_t bytes) {
    void* p = ws + off; off += (bytes + 255) & ~(size_t)255; return p;
  };
  unsigned short* xb = (unsigned short*)take(8388608ull * 2);
  unsigned short* Wb[4];
  for (int i = 0; i < 4; ++i) Wb[i] = (unsigned short*)take(4194304ull * 2);
  unsigned short* qb = (unsigned short*)take(8388608ull * 2);
  unsigned short* kb = (unsigned short*)take(8388608ull * 2);
  unsigned short* vT = (unsigned short*)take(8388608ull * 2);
  unsigned short* y  = (unsigned short*)take(8388608ull * 2);
  float* u    = (float*)take(4ull * UOFF * 4);
  float* cosT = (float*)take(1024ull * 64 * 4);
  float* sinT = (float*)take(1024ull * 64 * 4);
  unsigned short* dlb = (unsigned short*)take(1048576ull * 2);
  if (off > ws_size) return;

  ConvArgs ca;
  ca.src[0] = x;  ca.dst[0] = xb;  ca.n4[0] = 2097152;
  for (int i = 0; i < 4; ++i) { ca.src[1 + i] = W[i]; ca.dst[1 + i] = Wb[i]; ca.n4[1 + i] = 1048576; }
  ca.src[5] = dl; ca.dst[5] = dlb; ca.n4[5] = 262144;
  ca.thr[0] = 8192; ca.thr[1] = 12288; ca.thr[2] = 16384; ca.thr[3] = 20480; ca.thr[4] = 24576;
  k_conv_all<<<25600, 256, 0, stream>>>(ca);
  k_rope_table<<<1024, 64, 0, stream>>>(cosT, sinT);
  k_lora_mfma<<<dim3(16, 4, 4), 256, 0, stream>>>(xb, dlb, u, 0, 3);

  GArgs gq;
  gq.Bw0 = Wb[0]; gq.o0 = qb;    gq.m0_ = 0; gq.p0_ = 0;
  gq.Bw1 = Wb[1]; gq.o1 = kb;    gq.m1_ = 0; gq.p1_ = 1;
  gq.Bw2 = Wb[2]; gq.o2 = vT;    gq.m2_ = 1; gq.p2_ = 2;
  k_gemm<<<dim3(16, 32, 3), 256, 0, stream>>>(xb, gq, u, dl);

  k_rope<<<2048, 256, 0, stream>>>(kb, cosT, sinT);
  k_attn<<<512, 512, 0, stream>>>(qb, kb, vT, cosT, sinT, y);
  k_lora_mfma<<<dim3(16, 4, 4), 256, 0, stream>>>(y, dlb, u, 3, 1);

  GArgs go;
  go.Bw0 = Wb[3]; go.o0 = d_out; go.m0_ = 2; go.p0_ = 3;
  go.Bw1 = Wb[3]; go.o1 = d_out; go.m1_ = 2; go.p1_ = 3;
  go.Bw2 = Wb[3]; go.o2 = d_out; go.m2_ = 2; go.p2_ = 3;
  k_gemm<<<dim3(16, 32, 1), 256, 0, stream>>>(y, go, u, dl);
}

// Round 13
// 306.307 us; speedup vs baseline: 1.7202x; 1.0077x over previous
//
#include <hip/hip_runtime.h>
#include <cstdint>
#include <cstddef>

// ---------- types ----------
typedef __attribute__((ext_vector_type(8))) __bf16 bf8_t;
typedef __attribute__((ext_vector_type(8))) short s8_t;
typedef __attribute__((ext_vector_type(4))) short s4_t;
typedef __attribute__((ext_vector_type(4))) float f4_t;

__device__ __forceinline__ float bf2f(unsigned short h) {
  union { unsigned u; float f; } v; v.u = (unsigned)h << 16; return v.f;
}
__device__ __forceinline__ unsigned short f2bf(float f) {
  union { float f; unsigned u; } v; v.f = f;
  return (unsigned short)((v.u + 0x7FFFu + ((v.u >> 16) & 1u)) >> 16);
}

#define GL16(gp, lp) __builtin_amdgcn_global_load_lds( \
    (__attribute__((address_space(1))) void*)(gp),     \
    (__attribute__((address_space(3))) void*)(lp), 16, 0, 0)

// ---------- fused fp32 -> bf16 conversion (x, W0..3, dl in one launch) ----------
struct ConvArgs {
  const float* src[6];
  unsigned short* dst[6];
  int n4[6];
  int thr[5];
};
__global__ void k_conv_all(ConvArgs a) {
  int blk = blockIdx.x, seg = 0;
#pragma unroll
  for (int s = 0; s < 5; ++s) seg += (blk >= a.thr[s]);
  int base = (seg == 0) ? 0 : a.thr[seg - 1];
  int i = (blk - base) * 256 + threadIdx.x;
  if (i >= a.n4[seg]) return;
  float4 v = reinterpret_cast<const float4*>(a.src[seg])[i];
  s4_t o;
  o.x = (short)f2bf(v.x); o.y = (short)f2bf(v.y);
  o.z = (short)f2bf(v.z); o.w = (short)f2bf(v.w);
  reinterpret_cast<s4_t*>(a.dst[seg])[i] = o;
}

// ---------- RoPE cos/sin table ----------
__global__ void k_rope_table(float* __restrict__ cosT, float* __restrict__ sinT) {
  int t = blockIdx.x, d = threadIdx.x;            // 1024 x 64
  float inv = exp2f(-(float)d * (13.287712379549449f / 64.0f));
  float ang = (float)t * inv;
  cosT[t * 64 + d] = cosf(ang);
  sinT[t * 64 + d] = sinf(ang);
}

// ---------- LoRA u = X @ dA^T via MFMA, split-K x4 (u: [4][B][4][16][1024]) ----
#define UOFF 262144
__global__ __launch_bounds__(256) void k_lora_mfma(
    const unsigned short* __restrict__ X,
    const unsigned short* __restrict__ dlb,
    float* __restrict__ u, int pstart, int pcount) {
  __shared__ __align__(16) unsigned short Xs[64 * 64];
  __shared__ __align__(16) unsigned short Da[64 * 64];
  const int t = threadIdx.x;
  const int b = blockIdx.y;
  const int z = blockIdx.z;          // K quarter
  const int m0 = blockIdx.x * 64;
  const int w = t >> 6, lane = t & 63, lr = lane & 15, lg = lane >> 4;
  const int nrow = pcount * 16;
  f4_t acc[4] = {};
  for (int k0 = z * 512; k0 < z * 512 + 512; k0 += 64) {
    __syncthreads();
#pragma unroll
    for (int i = 0; i < 2; ++i) {
      int idx = i * 256 + t;
      int row = idx >> 3, c = idx & 7;
      GL16(X + ((size_t)b * 1024 + m0 + row) * 2048 + k0 + ((c ^ (row & 7)) * 8),
           Xs + (size_t)idx * 8);
      int ric = row < nrow ? row : nrow - 1;
      int g = (pstart + (ric >> 4)) * 32 + (ric & 15);
      GL16(dlb + ((size_t)b * 128 + g) * 2048 + k0 + ((c ^ (ric & 7)) * 8),
           Da + (size_t)idx * 8);
    }
    __syncthreads();
#pragma unroll
    for (int kk = 0; kk < 2; ++kk) {
      bf8_t af = *(const bf8_t*)&Xs[(w * 16 + lr) * 64 + (((kk * 4 + lg) ^ (lr & 7)) * 8)];
#pragma unroll
      for (int n = 0; n < 4; ++n) {
        if (n < pcount) {
          bf8_t bfv = *(const bf8_t*)&Da[(n * 16 + lr) * 64 + (((kk * 4 + lg) ^ (lr & 7)) * 8)];
          acc[n] = __builtin_amdgcn_mfma_f32_16x16x32_bf16(af, bfv, acc[n], 0, 0, 0);
        }
      }
    }
  }
#pragma unroll
  for (int n = 0; n < 4; ++n) {
    if (n < pcount) {
#pragma unroll
      for (int j = 0; j < 4; ++j)
        u[(size_t)z * UOFF +
          (((size_t)b * 4 + pstart + n) * 16 + lr) * 1024 + m0 + w * 16 + lg * 4 + j] = acc[n][j];
    }
  }
}

// ---------- 128x128 bf16 GEMM, 2-phase + XOR swizzle + XCD chunking + LoRA ----
struct GArgs {
  const unsigned short *Bw0, *Bw1, *Bw2;
  void *o0, *o1, *o2;
  int m0_, m1_, m2_;
  int p0_, p1_, p2_;
};
#define BM 128
#define BN 128
#define BKK 64
__global__ __launch_bounds__(256, 2) void k_gemm(
    const unsigned short* __restrict__ A,
    GArgs ga,
    const float* __restrict__ u,
    const float* __restrict__ dl) {
  constexpr int K = 2048;
  const int z = blockIdx.z;
  const unsigned short* Bw = z == 0 ? ga.Bw0 : (z == 1 ? ga.Bw1 : ga.Bw2);
  void* outv = z == 0 ? ga.o0 : (z == 1 ? ga.o1 : ga.o2);
  const int mode = z == 0 ? ga.m0_ : (z == 1 ? ga.m1_ : ga.m2_);
  const int p = z == 0 ? ga.p0_ : (z == 1 ? ga.p1_ : ga.p2_);
  __shared__ unsigned short As[BM * BKK];   // 16 KB
  __shared__ unsigned short Bs[BN * BKK];   // 16 KB
  const int t = threadIdx.x;
  // XCD-chunked remap: XCD c (= lin%8) gets an 8n x 8m chunk.
  const int lin = (int)blockIdx.x + ((int)blockIdx.y << 4);
  const int xcd = lin & 7, rnk = lin >> 3;
  const int m0 = (((xcd >> 1) << 3) | (rnk >> 3)) * BM;
  const int n0 = (((xcd & 1) << 3) | (rnk & 7)) * BN;
  const int lane = t & 63;
  const int w = t >> 6;
  const int wr = (w >> 1) * 64, wc = (w & 1) * 64;
  const int lr = lane & 15;
  const int lg = lane >> 4;
  const int srow = t >> 3;
  const int sdst = (t & 7) * 8;
  const int ssrc = ((t & 7) ^ (srow & 7)) * 8;
  f4_t acc[4][4] = {};

  for (int k0 = 0; k0 < K; k0 += BKK) {
#pragma unroll
    for (int j = 0; j < 4; ++j) {
      int row = j * 32 + srow;
      GL16(A  + (size_t)(m0 + row) * K + k0 + ssrc, As + row * BKK + sdst);
      GL16(Bw + (size_t)(n0 + row) * K + k0 + ssrc, Bs + row * BKK + sdst);
    }
    __syncthreads();
#pragma unroll
    for (int kk = 0; kk < 2; ++kk) {
      bf8_t af[4], bfr[4];
#pragma unroll
      for (int m = 0; m < 4; ++m) {
        int row_ = wr + m * 16 + lr;
        af[m] = *(const bf8_t*)&As[row_ * BKK + (((kk * 4 + lg) ^ (lr & 7)) * 8)];
      }
#pragma unroll
      for (int n = 0; n < 4; ++n) {
        int row_ = wc + n * 16 + lr;
        bfr[n] = *(const bf8_t*)&Bs[row_ * BKK + (((kk * 4 + lg) ^ (lr & 7)) * 8)];
      }
#pragma unroll
      for (int m = 0; m < 4; ++m)
#pragma unroll
        for (int n = 0; n < 4; ++n)
          acc[m][n] = __builtin_amdgcn_mfma_f32_16x16x32_bf16(af[m], bfr[n], acc[m][n], 0, 0, 0);
    }
    __syncthreads();
  }

  // LoRA rank-16 as one zero-padded K=32 MFMA step (sum of 4 u K-quarters)
  const int b = m0 >> 10;
  const int t0r = m0 & 1023;
  for (int idx = t; idx < 128 * 32; idx += 256) {
    int rr = idx >> 5, r = idx & 31;
    float val = 0.0f;
    if (r < 16) {
      size_t ub = (((size_t)b * 4 + p) * 16 + r) * 1024 + t0r + rr;
      val = (u[ub] + u[UOFF + ub]) + (u[2 * UOFF + ub] + u[3 * UOFF + ub]);
    }
    As[rr * 32 + r] = f2bf(val);
  }
  for (int idx = t; idx < 128 * 32; idx += 256) {
    int cc = idx >> 5, r = idx & 31;
    float val = (r < 16) ? dl[((size_t)b * 128 + p * 32 + 16 + r) * 2048 + n0 + cc] : 0.0f;
    Bs[cc * 32 + r] = f2bf(val);
  }
  __syncthreads();
  {
    bf8_t af[4], bfr[4];
#pragma unroll
    for (int m = 0; m < 4; ++m)
      af[m] = *(const bf8_t*)&As[(wr + m * 16 + lr) * 32 + lg * 8];
#pragma unroll
    for (int n = 0; n < 4; ++n)
      bfr[n] = *(const bf8_t*)&Bs[(wc + n * 16 + lr) * 32 + lg * 8];
#pragma unroll
    for (int m = 0; m < 4; ++m)
#pragma unroll
      for (int n = 0; n < 4; ++n)
        acc[m][n] = __builtin_amdgcn_mfma_f32_16x16x32_bf16(af[m], bfr[n], acc[m][n], 0, 0, 0);
  }

  // write C (C/D map: col = lane&15, row = (lane>>4)*4 + reg)
  unsigned short* out16 = (unsigned short*)outv;
  float* out32 = (float*)outv;
#pragma unroll
  for (int m = 0; m < 4; ++m) {
    int ri = wr + m * 16 + lg * 4;
#pragma unroll
    for (int j = 0; j < 4; ++j) {
      int grow = m0 + ri + j;
      int gb = grow >> 10, gt = grow & 1023;
#pragma unroll
      for (int n = 0; n < 4; ++n) {
        int gcol = n0 + wc + n * 16 + lr;
        float fv = acc[m][n][j];
        if (mode == 0) {
          size_t dst = (((size_t)gb * 16 + (gcol >> 7)) * 1024 + gt) * 128 + (gcol & 127);
          out16[dst] = f2bf(fv);
        } else if (mode == 1) {
          size_t dst = (((size_t)gb * 16 + (gcol >> 7)) * 128 + (gcol & 127)) * 1024 + gt;
          out16[dst] = f2bf(fv);
        } else {
          out32[(size_t)grow * 2048 + gcol] = fv;
        }
      }
    }
  }
}

// ---------- in-place RoPE on K only (B,H,T,128) bf16 ----------
__global__ void k_rope(unsigned short* __restrict__ X,
                       const float* __restrict__ cosT, const float* __restrict__ sinT) {
  int idx = blockIdx.x * 256 + threadIdx.x;
  int d0 = (idx & 7) * 8;
  int tt = (idx >> 3) & 1023;
  size_t base = (size_t)(idx >> 3) * 128 + d0;
  s8_t a = *(s8_t*)&X[base];
  s8_t bb = *(s8_t*)&X[base + 64];
  float4 c0 = *(const float4*)&cosT[tt * 64 + d0];
  float4 c1 = *(const float4*)&cosT[tt * 64 + d0 + 4];
  float4 sv0 = *(const float4*)&sinT[tt * 64 + d0];
  float4 sv1 = *(const float4*)&sinT[tt * 64 + d0 + 4];
  float cv[8] = {c0.x, c0.y, c0.z, c0.w, c1.x, c1.y, c1.z, c1.w};
  float sw[8] = {sv0.x, sv0.y, sv0.z, sv0.w, sv1.x, sv1.y, sv1.z, sv1.w};
  s8_t ra, rb;
#pragma unroll
  for (int j = 0; j < 8; ++j) {
    float av = bf2f((unsigned short)a[j]);
    float bv = bf2f((unsigned short)bb[j]);
    ra[j] = (short)f2bf(av * cv[j] - bv * sw[j]);
    rb[j] = (short)f2bf(bv * cv[j] + av * sw[j]);
  }
  *(s8_t*)&X[base] = ra;
  *(s8_t*)&X[base + 64] = rb;
}

// ---------- fused attention: fixed-shift softmax + cvt_pk + l-via-MFMA ------
__global__ __launch_bounds__(512, 4) void k_attn(
    const unsigned short* __restrict__ Qg,
    const unsigned short* __restrict__ Kg,
    const unsigned short* __restrict__ Vt,
    const float* __restrict__ cosT,
    const float* __restrict__ sinT,
    unsigned short* __restrict__ Y) {
  const float scale = 0.08838834764831845f;
  const float L2E = 1.4426950408889634f;
  const float C1 = scale * L2E;            // fold scale into exp2 arg
  const float C2 = 12.0f * L2E;            // fixed shift (max|S*scale| ~ 5.9)
  const int bid = blockIdx.x;
  const int wg = (bid & 7) * 64 + (bid >> 3);
  const int bh = wg >> 3;
  const int b = bh >> 4, h = bh & 15;
  const int t = threadIdx.x;
  const int w = t >> 6, lane = t & 63;
  const int lr = lane & 15, lg = lane >> 4;
  const int q0 = (wg & 7) * 128 + w * 16;
  const unsigned short* Q  = Qg + (size_t)bh * 131072;
  const unsigned short* Kp = Kg + (size_t)bh * 131072;
  const unsigned short* Vp = Vt + (size_t)bh * 131072;
  __shared__ __align__(16) unsigned short Ks[64 * 128];
  __shared__ __align__(16) unsigned short Vs[128 * 64];
  __shared__ __align__(16) unsigned short Ps[8][16 * 72];
  unsigned short* Pw = Ps[w];

  // ones B-frag for l-sum MFMA (bf16 1.0 = 0x3F80)
  s8_t one_s;
#pragma unroll
  for (int e = 0; e < 8; ++e) one_s[e] = (short)0x3F80;
  const bf8_t ones = *(bf8_t*)&one_s;

  // Q load + in-register RoPE (pairs d<->d+64 are qs[0]<->qs[2], qs[1]<->qs[3])
  bf8_t qf[4];
  {
    s8_t qs[4];
#pragma unroll
    for (int kk = 0; kk < 4; ++kk)
      qs[kk] = *(const s8_t*)&Q[(size_t)(q0 + lr) * 128 + kk * 32 + lg * 8];
    const float* ct = cosT + (size_t)(q0 + lr) * 64 + lg * 8;
    const float* st = sinT + (size_t)(q0 + lr) * 64 + lg * 8;
    float4 cl0 = *(const float4*)ct,        cl1 = *(const float4*)(ct + 4);
    float4 ch0 = *(const float4*)(ct + 32), ch1 = *(const float4*)(ct + 36);
    float4 sl0 = *(const float4*)st,        sl1 = *(const float4*)(st + 4);
    float4 sh0 = *(const float4*)(st + 32), sh1 = *(const float4*)(st + 36);
    float cl[8] = {cl0.x, cl0.y, cl0.z, cl0.w, cl1.x, cl1.y, cl1.z, cl1.w};
    float ch[8] = {ch0.x, ch0.y, ch0.z, ch0.w, ch1.x, ch1.y, ch1.z, ch1.w};
    float sl[8] = {sl0.x, sl0.y, sl0.z, sl0.w, sl1.x, sl1.y, sl1.z, sl1.w};
    float sh[8] = {sh0.x, sh0.y, sh0.z, sh0.w, sh1.x, sh1.y, sh1.z, sh1.w};
    s8_t r0, r1, r2, r3;
#pragma unroll
    for (int e = 0; e < 8; ++e) {
      float x0 = bf2f((unsigned short)qs[0][e]);
      float x1 = bf2f((unsigned short)qs[1][e]);
      float x2 = bf2f((unsigned short)qs[2][e]);
      float x3 = bf2f((unsigned short)qs[3][e]);
      r0[e] = (short)f2bf(x0 * cl[e] - x2 * sl[e]);
      r1[e] = (short)f2bf(x1 * ch[e] - x3 * sh[e]);
      r2[e] = (short)f2bf(x2 * cl[e] + x0 * sl[e]);
      r3[e] = (short)f2bf(x3 * ch[e] + x1 * sh[e]);
    }
    qf[0] = *(bf8_t*)&r0; qf[1] = *(bf8_t*)&r1;
    qf[2] = *(bf8_t*)&r2; qf[3] = *(bf8_t*)&r3;
  }

  f4_t o[8] = {};
  f4_t lacc = {};   // row sums of P via ones-MFMA; row map same as o

  auto ldK = [&](int s0, int i) {
    int idx = i * 512 + t, s = idx >> 4, c = t & 15;
    return *(const s8_t*)&Kp[(size_t)(s0 + s) * 128 + ((c ^ (s & 7)) * 8)];
  };
  auto ldV = [&](int s0, int i) {
    int idx = i * 512 + t, d = idx >> 3, c = t & 7;
    return *(const s8_t*)&Vp[(size_t)d * 1024 + s0 + ((c ^ (d & 7)) * 8)];
  };
  s8_t kr0 = ldK(0, 0), kr1 = ldK(0, 1), vr0 = ldV(0, 0), vr1 = ldV(0, 1);

  for (int s0 = 0; s0 < 1024; s0 += 64) {
    __builtin_amdgcn_s_barrier();
    *(s8_t*)&Ks[((size_t)t) * 8]        = kr0;
    *(s8_t*)&Ks[((size_t)512 + t) * 8]  = kr1;
    *(s8_t*)&Vs[((size_t)t) * 8]        = vr0;
    *(s8_t*)&Vs[((size_t)512 + t) * 8]  = vr1;
    int sn = (s0 < 960) ? s0 + 64 : 0;
    kr0 = ldK(sn, 0); kr1 = ldK(sn, 1); vr0 = ldV(sn, 0); vr1 = ldV(sn, 1);
    asm volatile("s_waitcnt lgkmcnt(0)" ::: "memory");
    __builtin_amdgcn_s_barrier();

    f4_t sf[4];
    __builtin_amdgcn_s_setprio(1);
#pragma unroll
    for (int ss = 0; ss < 4; ++ss) {
      f4_t c = {0.0f, 0.0f, 0.0f, 0.0f};
#pragma unroll
      for (int kk = 0; kk < 4; ++kk) {
        bf8_t kf = *(const bf8_t*)&Ks[(ss * 16 + lr) * 128 + (((kk * 4 + lg) ^ (lr & 7)) * 8)];
        c = __builtin_amdgcn_mfma_f32_16x16x32_bf16(kf, qf[kk], c, 0, 0, 0);
      }
      sf[ss] = c;
    }
    __builtin_amdgcn_s_setprio(0);
    // fixed-shift softmax: P = exp2(S*C1 - C2); pack via HW cvt_pk (RNE)
#pragma unroll
    for (int ss = 0; ss < 4; ++ss) {
      float p0 = exp2f(sf[ss][0] * C1 - C2);
      float p1 = exp2f(sf[ss][1] * C1 - C2);
      float p2 = exp2f(sf[ss][2] * C1 - C2);
      float p3 = exp2f(sf[ss][3] * C1 - C2);
      unsigned lo, hi;
      asm("v_cvt_pk_bf16_f32 %0, %1, %2" : "=v"(lo) : "v"(p0), "v"(p1));
      asm("v_cvt_pk_bf16_f32 %0, %1, %2" : "=v"(hi) : "v"(p2), "v"(p3));
      unsigned pk2[2] = {lo, hi};
      *(s4_t*)&Pw[lr * 72 + ss * 16 + lg * 4] = *(s4_t*)pk2;
    }
    bf8_t pa0 = *(const bf8_t*)&Pw[lr * 72 + lg * 8];
    bf8_t pa1 = *(const bf8_t*)&Pw[lr * 72 + 32 + lg * 8];
    __builtin_amdgcn_s_setprio(1);
#pragma unroll
    for (int n = 0; n < 8; ++n) {
      int d = n * 16 + lr;
      bf8_t v0 = *(const bf8_t*)&Vs[d * 64 + (((0 + lg) ^ (lr & 7)) * 8)];
      bf8_t v1 = *(const bf8_t*)&Vs[d * 64 + (((4 + lg) ^ (lr & 7)) * 8)];
      o[n] = __builtin_amdgcn_mfma_f32_16x16x32_bf16(pa0, v0, o[n], 0, 0, 0);
      o[n] = __builtin_amdgcn_mfma_f32_16x16x32_bf16(pa1, v1, o[n], 0, 0, 0);
    }
    // l row-sums: D[q][*] += sum_s P[q][s]  (B = ones)
    lacc = __builtin_amdgcn_mfma_f32_16x16x32_bf16(pa0, ones, lacc, 0, 0, 0);
    lacc = __builtin_amdgcn_mfma_f32_16x16x32_bf16(pa1, ones, lacc, 0, 0, 0);
    __builtin_amdgcn_s_setprio(0);
  }

  float linv[4];
#pragma unroll
  for (int j = 0; j < 4; ++j) linv[j] = 1.0f / lacc[j];   // row = lg*4+j, same as o
#pragma unroll
  for (int n = 0; n < 8; ++n)
#pragma unroll
    for (int j = 0; j < 4; ++j) {
      int qg = q0 + lg * 4 + j;
      Y[((size_t)b * 1024 + qg) * 2048 + h * 128 + n * 16 + lr] =
          f2bf(o[n][j] * linv[j]);
    }
}

// ---------- launch ----------
extern "C" void kernel_launch(void* const* d_in, const int* in_sizes, int n_in,
                              void* d_out, int out_size, void* d_ws, size_t ws_size,
                              hipStream_t stream) {
  const float* x  = (const float*)d_in[0];
  const float* dl = (const float*)d_in[1];
  const float* W[4] = {(const float*)d_in[2], (const float*)d_in[3],
                       (const float*)d_in[4], (const float*)d_in[5]};
  char* ws = (char*)d_ws;
  size_t off = 0;
  auto take = [&](size_t bytes) {
    void* p = ws + off; off += (bytes + 255) & ~(size_t)255; return p;
  };
  unsigned short* xb = (unsigned short*)take(8388608ull * 2);
  unsigned short* Wb[4];
  for (int i = 0; i < 4; ++i) Wb[i] = (unsigned short*)take(4194304ull * 2);
  unsigned short* qb = (unsigned short*)take(8388608ull * 2);
  unsigned short* kb = (unsigned short*)take(8388608ull * 2);
  unsigned short* vT = (unsigned short*)take(8388608ull * 2);
  unsigned short* y  = (unsigned short*)take(8388608ull * 2);
  float* u    = (float*)take(4ull * UOFF * 4);
  float* cosT = (float*)take(1024ull * 64 * 4);
  float* sinT = (float*)take(1024ull * 64 * 4);
  unsigned short* dlb = (unsigned short*)take(1048576ull * 2);
  if (off > ws_size) return;

  ConvArgs ca;
  ca.src[0] = x;  ca.dst[0] = xb;  ca.n4[0] = 2097152;
  for (int i = 0; i < 4; ++i) { ca.src[1 + i] = W[i]; ca.dst[1 + i] = Wb[i]; ca.n4[1 + i] = 1048576; }
  ca.src[5] = dl; ca.dst[5] = dlb; ca.n4[5] = 262144;
  ca.thr[0] = 8192; ca.thr[1] = 12288; ca.thr[2] = 16384; ca.thr[3] = 20480; ca.thr[4] = 24576;
  k_conv_all<<<25600, 256, 0, stream>>>(ca);
  k_rope_table<<<1024, 64, 0, stream>>>(cosT, sinT);
  k_lora_mfma<<<dim3(16, 4, 4), 256, 0, stream>>>(xb, dlb, u, 0, 3);

  GArgs gq;
  gq.Bw0 = Wb[0]; gq.o0 = qb;    gq.m0_ = 0; gq.p0_ = 0;
  gq.Bw1 = Wb[1]; gq.o1 = kb;    gq.m1_ = 0; gq.p1_ = 1;
  gq.Bw2 = Wb[2]; gq.o2 = vT;    gq.m2_ = 1; gq.p2_ = 2;
  k_gemm<<<dim3(16, 32, 3), 256, 0, stream>>>(xb, gq, u, dl);

  k_rope<<<2048, 256, 0, stream>>>(kb, cosT, sinT);
  k_attn<<<512, 512, 0, stream>>>(qb, kb, vT, cosT, sinT, y);
  k_lora_mfma<<<dim3(16, 4, 4), 256, 0, stream>>>(y, dlb, u, 3, 1);

  GArgs go;
  go.Bw0 = Wb[3]; go.o0 = d_out; go.m0_ = 2; go.p0_ = 3;
  go.Bw1 = Wb[3]; go.o1 = d_out; go.m1_ = 2; go.p1_ = 3;
  go.Bw2 = Wb[3]; go.o2 = d_out; go.m2_ = 2; go.p2_ = 3;
  k_gemm<<<dim3(16, 32, 1), 256, 0, stream>>>(y, go, u, dl);
}

// Round 14
// 305.930 us; speedup vs baseline: 1.7223x; 1.0012x over previous
//
#include <hip/hip_runtime.h>
#include <cstdint>
#include <cstddef>

// ---------- types ----------
typedef __attribute__((ext_vector_type(8))) __bf16 bf8_t;
typedef __attribute__((ext_vector_type(8))) short s8_t;
typedef __attribute__((ext_vector_type(4))) short s4_t;
typedef __attribute__((ext_vector_type(4))) float f4_t;

__device__ __forceinline__ float bf2f(unsigned short h) {
  union { unsigned u; float f; } v; v.u = (unsigned)h << 16; return v.f;
}
__device__ __forceinline__ unsigned short f2bf(float f) {
  union { float f; unsigned u; } v; v.f = f;
  return (unsigned short)((v.u + 0x7FFFu + ((v.u >> 16) & 1u)) >> 16);
}

#define GL16(gp, lp) __builtin_amdgcn_global_load_lds( \
    (__attribute__((address_space(1))) void*)(gp),     \
    (__attribute__((address_space(3))) void*)(lp), 16, 0, 0)

// ---------- fused fp32 -> bf16 conversion (x, W0..3, dl in one launch) ----------
struct ConvArgs {
  const float* src[6];
  unsigned short* dst[6];
  int n4[6];
  int thr[5];
};
__global__ void k_conv_all(ConvArgs a) {
  int blk = blockIdx.x, seg = 0;
#pragma unroll
  for (int s = 0; s < 5; ++s) seg += (blk >= a.thr[s]);
  int base = (seg == 0) ? 0 : a.thr[seg - 1];
  int i = (blk - base) * 256 + threadIdx.x;
  if (i >= a.n4[seg]) return;
  float4 v = reinterpret_cast<const float4*>(a.src[seg])[i];
  s4_t o;
  o.x = (short)f2bf(v.x); o.y = (short)f2bf(v.y);
  o.z = (short)f2bf(v.z); o.w = (short)f2bf(v.w);
  reinterpret_cast<s4_t*>(a.dst[seg])[i] = o;
}

// ---------- RoPE cos/sin table ----------
__global__ void k_rope_table(float* __restrict__ cosT, float* __restrict__ sinT) {
  int t = blockIdx.x, d = threadIdx.x;            // 1024 x 64
  float inv = exp2f(-(float)d * (13.287712379549449f / 64.0f));
  float ang = (float)t * inv;
  cosT[t * 64 + d] = cosf(ang);
  sinT[t * 64 + d] = sinf(ang);
}

// ---------- LoRA u = X @ dA^T via MFMA, split-K x4 (u: [4][B][4][16][1024]) ----
#define UOFF 262144
__global__ __launch_bounds__(256) void k_lora_mfma(
    const unsigned short* __restrict__ X,
    const unsigned short* __restrict__ dlb,
    float* __restrict__ u, int pstart, int pcount) {
  __shared__ __align__(16) unsigned short Xs[64 * 64];
  __shared__ __align__(16) unsigned short Da[64 * 64];
  const int t = threadIdx.x;
  const int b = blockIdx.y;
  const int z = blockIdx.z;          // K quarter
  const int m0 = blockIdx.x * 64;
  const int w = t >> 6, lane = t & 63, lr = lane & 15, lg = lane >> 4;
  const int nrow = pcount * 16;
  f4_t acc[4] = {};
  for (int k0 = z * 512; k0 < z * 512 + 512; k0 += 64) {
    __syncthreads();
#pragma unroll
    for (int i = 0; i < 2; ++i) {
      int idx = i * 256 + t;
      int row = idx >> 3, c = idx & 7;
      GL16(X + ((size_t)b * 1024 + m0 + row) * 2048 + k0 + ((c ^ (row & 7)) * 8),
           Xs + (size_t)idx * 8);
      int ric = row < nrow ? row : nrow - 1;
      int g = (pstart + (ric >> 4)) * 32 + (ric & 15);
      GL16(dlb + ((size_t)b * 128 + g) * 2048 + k0 + ((c ^ (ric & 7)) * 8),
           Da + (size_t)idx * 8);
    }
    __syncthreads();
#pragma unroll
    for (int kk = 0; kk < 2; ++kk) {
      bf8_t af = *(const bf8_t*)&Xs[(w * 16 + lr) * 64 + (((kk * 4 + lg) ^ (lr & 7)) * 8)];
#pragma unroll
      for (int n = 0; n < 4; ++n) {
        if (n < pcount) {
          bf8_t bfv = *(const bf8_t*)&Da[(n * 16 + lr) * 64 + (((kk * 4 + lg) ^ (lr & 7)) * 8)];
          acc[n] = __builtin_amdgcn_mfma_f32_16x16x32_bf16(af, bfv, acc[n], 0, 0, 0);
        }
      }
    }
  }
#pragma unroll
  for (int n = 0; n < 4; ++n) {
    if (n < pcount) {
#pragma unroll
      for (int j = 0; j < 4; ++j)
        u[(size_t)z * UOFF +
          (((size_t)b * 4 + pstart + n) * 16 + lr) * 1024 + m0 + w * 16 + lg * 4 + j] = acc[n][j];
    }
  }
}

// ---------- 128x128 bf16 GEMM, 2-phase + XOR swizzle + XCD chunking + LoRA ----
struct GArgs {
  const unsigned short *Bw0, *Bw1, *Bw2;
  void *o0, *o1, *o2;
  int m0_, m1_, m2_;
  int p0_, p1_, p2_;
};
#define BM 128
#define BN 128
#define BKK 64
__global__ __launch_bounds__(256, 2) void k_gemm(
    const unsigned short* __restrict__ A,
    GArgs ga,
    const float* __restrict__ u,
    const float* __restrict__ dl) {
  constexpr int K = 2048;
  const int z = blockIdx.z;
  const unsigned short* Bw = z == 0 ? ga.Bw0 : (z == 1 ? ga.Bw1 : ga.Bw2);
  void* outv = z == 0 ? ga.o0 : (z == 1 ? ga.o1 : ga.o2);
  const int mode = z == 0 ? ga.m0_ : (z == 1 ? ga.m1_ : ga.m2_);
  const int p = z == 0 ? ga.p0_ : (z == 1 ? ga.p1_ : ga.p2_);
  __shared__ unsigned short As[BM * BKK];   // 16 KB
  __shared__ unsigned short Bs[BN * BKK];   // 16 KB
  const int t = threadIdx.x;
  // XCD-chunked remap: XCD c (= lin%8) gets an 8n x 8m chunk.
  const int lin = (int)blockIdx.x + ((int)blockIdx.y << 4);
  const int xcd = lin & 7, rnk = lin >> 3;
  const int m0 = (((xcd >> 1) << 3) | (rnk >> 3)) * BM;
  const int n0 = (((xcd & 1) << 3) | (rnk & 7)) * BN;
  const int lane = t & 63;
  const int w = t >> 6;
  const int wr = (w >> 1) * 64, wc = (w & 1) * 64;
  const int lr = lane & 15;
  const int lg = lane >> 4;
  const int srow = t >> 3;
  const int sdst = (t & 7) * 8;
  const int ssrc = ((t & 7) ^ (srow & 7)) * 8;
  f4_t acc[4][4] = {};

  for (int k0 = 0; k0 < K; k0 += BKK) {
#pragma unroll
    for (int j = 0; j < 4; ++j) {
      int row = j * 32 + srow;
      GL16(A  + (size_t)(m0 + row) * K + k0 + ssrc, As + row * BKK + sdst);
      GL16(Bw + (size_t)(n0 + row) * K + k0 + ssrc, Bs + row * BKK + sdst);
    }
    __syncthreads();
#pragma unroll
    for (int kk = 0; kk < 2; ++kk) {
      bf8_t af[4], bfr[4];
#pragma unroll
      for (int m = 0; m < 4; ++m) {
        int row_ = wr + m * 16 + lr;
        af[m] = *(const bf8_t*)&As[row_ * BKK + (((kk * 4 + lg) ^ (lr & 7)) * 8)];
      }
#pragma unroll
      for (int n = 0; n < 4; ++n) {
        int row_ = wc + n * 16 + lr;
        bfr[n] = *(const bf8_t*)&Bs[row_ * BKK + (((kk * 4 + lg) ^ (lr & 7)) * 8)];
      }
#pragma unroll
      for (int m = 0; m < 4; ++m)
#pragma unroll
        for (int n = 0; n < 4; ++n)
          acc[m][n] = __builtin_amdgcn_mfma_f32_16x16x32_bf16(af[m], bfr[n], acc[m][n], 0, 0, 0);
    }
    __syncthreads();
  }

  // LoRA rank-16 as one zero-padded K=32 MFMA step (sum of 4 u K-quarters)
  const int b = m0 >> 10;
  const int t0r = m0 & 1023;
  for (int idx = t; idx < 128 * 32; idx += 256) {
    int rr = idx >> 5, r = idx & 31;
    float val = 0.0f;
    if (r < 16) {
      size_t ub = (((size_t)b * 4 + p) * 16 + r) * 1024 + t0r + rr;
      val = (u[ub] + u[UOFF + ub]) + (u[2 * UOFF + ub] + u[3 * UOFF + ub]);
    }
    As[rr * 32 + r] = f2bf(val);
  }
  for (int idx = t; idx < 128 * 32; idx += 256) {
    int cc = idx >> 5, r = idx & 31;
    float val = (r < 16) ? dl[((size_t)b * 128 + p * 32 + 16 + r) * 2048 + n0 + cc] : 0.0f;
    Bs[cc * 32 + r] = f2bf(val);
  }
  __syncthreads();
  {
    bf8_t af[4], bfr[4];
#pragma unroll
    for (int m = 0; m < 4; ++m)
      af[m] = *(const bf8_t*)&As[(wr + m * 16 + lr) * 32 + lg * 8];
#pragma unroll
    for (int n = 0; n < 4; ++n)
      bfr[n] = *(const bf8_t*)&Bs[(wc + n * 16 + lr) * 32 + lg * 8];
#pragma unroll
    for (int m = 0; m < 4; ++m)
#pragma unroll
      for (int n = 0; n < 4; ++n)
        acc[m][n] = __builtin_amdgcn_mfma_f32_16x16x32_bf16(af[m], bfr[n], acc[m][n], 0, 0, 0);
  }

  // write C (C/D map: col = lane&15, row = (lane>>4)*4 + reg)
  unsigned short* out16 = (unsigned short*)outv;
  float* out32 = (float*)outv;
#pragma unroll
  for (int m = 0; m < 4; ++m) {
    int ri = wr + m * 16 + lg * 4;
#pragma unroll
    for (int j = 0; j < 4; ++j) {
      int grow = m0 + ri + j;
      int gb = grow >> 10, gt = grow & 1023;
#pragma unroll
      for (int n = 0; n < 4; ++n) {
        int gcol = n0 + wc + n * 16 + lr;
        float fv = acc[m][n][j];
        if (mode == 0) {
          size_t dst = (((size_t)gb * 16 + (gcol >> 7)) * 1024 + gt) * 128 + (gcol & 127);
          out16[dst] = f2bf(fv);
        } else if (mode == 1) {
          size_t dst = (((size_t)gb * 16 + (gcol >> 7)) * 128 + (gcol & 127)) * 1024 + gt;
          out16[dst] = f2bf(fv);
        } else {
          out32[(size_t)grow * 2048 + gcol] = fv;
        }
      }
    }
  }
}

// ---------- in-place RoPE on K only (B,H,T,128) bf16 ----------
__global__ void k_rope(unsigned short* __restrict__ X,
                       const float* __restrict__ cosT, const float* __restrict__ sinT) {
  int idx = blockIdx.x * 256 + threadIdx.x;
  int d0 = (idx & 7) * 8;
  int tt = (idx >> 3) & 1023;
  size_t base = (size_t)(idx >> 3) * 128 + d0;
  s8_t a = *(s8_t*)&X[base];
  s8_t bb = *(s8_t*)&X[base + 64];
  float4 c0 = *(const float4*)&cosT[tt * 64 + d0];
  float4 c1 = *(const float4*)&cosT[tt * 64 + d0 + 4];
  float4 sv0 = *(const float4*)&sinT[tt * 64 + d0];
  float4 sv1 = *(const float4*)&sinT[tt * 64 + d0 + 4];
  float cv[8] = {c0.x, c0.y, c0.z, c0.w, c1.x, c1.y, c1.z, c1.w};
  float sw[8] = {sv0.x, sv0.y, sv0.z, sv0.w, sv1.x, sv1.y, sv1.z, sv1.w};
  s8_t ra, rb;
#pragma unroll
  for (int j = 0; j < 8; ++j) {
    float av = bf2f((unsigned short)a[j]);
    float bv = bf2f((unsigned short)bb[j]);
    ra[j] = (short)f2bf(av * cv[j] - bv * sw[j]);
    rb[j] = (short)f2bf(bv * cv[j] + av * sw[j]);
  }
  *(s8_t*)&X[base] = ra;
  *(s8_t*)&X[base + 64] = rb;
}

// ---------- fused attention: 32 q-rows/wave (2 Q-frags), 4 waves/block ------
// LDS reads amortized 2x over MFMA; fixed-shift softmax; l via ones-MFMA.
__global__ __launch_bounds__(256, 2) void k_attn(
    const unsigned short* __restrict__ Qg,
    const unsigned short* __restrict__ Kg,
    const unsigned short* __restrict__ Vt,
    const float* __restrict__ cosT,
    const float* __restrict__ sinT,
    unsigned short* __restrict__ Y) {
  const float scale = 0.08838834764831845f;
  const float L2E = 1.4426950408889634f;
  const float C1 = scale * L2E;
  const float C2 = 12.0f * L2E;
  const int bid = blockIdx.x;
  const int wg = (bid & 7) * 64 + (bid >> 3);
  const int bh = wg >> 3;
  const int b = bh >> 4, h = bh & 15;
  const int t = threadIdx.x;              // 256
  const int w = t >> 6, lane = t & 63;    // w 0..3
  const int lr = lane & 15, lg = lane >> 4;
  const int q0 = (wg & 7) * 128 + w * 32; // 32 q-rows per wave
  const unsigned short* Q  = Qg + (size_t)bh * 131072;
  const unsigned short* Kp = Kg + (size_t)bh * 131072;
  const unsigned short* Vp = Vt + (size_t)bh * 131072;
  __shared__ __align__(16) unsigned short Ks[64 * 128];    // 16 KB
  __shared__ __align__(16) unsigned short Vs[128 * 64];    // 16 KB
  __shared__ __align__(16) unsigned short Ps[4][32 * 72];  // 18 KB
  unsigned short* Pw = Ps[w];

  s8_t one_s;
#pragma unroll
  for (int e = 0; e < 8; ++e) one_s[e] = (short)0x3F80;
  const bf8_t ones = *(bf8_t*)&one_s;

  // Q load + in-register RoPE for both 16-row fragments
  bf8_t qf[2][4];
#pragma unroll
  for (int qr = 0; qr < 2; ++qr) {
    int qrow = q0 + qr * 16 + lr;
    s8_t qs[4];
#pragma unroll
    for (int kk = 0; kk < 4; ++kk)
      qs[kk] = *(const s8_t*)&Q[(size_t)qrow * 128 + kk * 32 + lg * 8];
    const float* ct = cosT + (size_t)qrow * 64 + lg * 8;
    const float* st = sinT + (size_t)qrow * 64 + lg * 8;
    float4 cl0 = *(const float4*)ct,        cl1 = *(const float4*)(ct + 4);
    float4 ch0 = *(const float4*)(ct + 32), ch1 = *(const float4*)(ct + 36);
    float4 sl0 = *(const float4*)st,        sl1 = *(const float4*)(st + 4);
    float4 sh0 = *(const float4*)(st + 32), sh1 = *(const float4*)(st + 36);
    float cl[8] = {cl0.x, cl0.y, cl0.z, cl0.w, cl1.x, cl1.y, cl1.z, cl1.w};
    float ch[8] = {ch0.x, ch0.y, ch0.z, ch0.w, ch1.x, ch1.y, ch1.z, ch1.w};
    float sl[8] = {sl0.x, sl0.y, sl0.z, sl0.w, sl1.x, sl1.y, sl1.z, sl1.w};
    float sh[8] = {sh0.x, sh0.y, sh0.z, sh0.w, sh1.x, sh1.y, sh1.z, sh1.w};
    s8_t r0, r1, r2, r3;
#pragma unroll
    for (int e = 0; e < 8; ++e) {
      float x0 = bf2f((unsigned short)qs[0][e]);
      float x1 = bf2f((unsigned short)qs[1][e]);
      float x2 = bf2f((unsigned short)qs[2][e]);
      float x3 = bf2f((unsigned short)qs[3][e]);
      r0[e] = (short)f2bf(x0 * cl[e] - x2 * sl[e]);
      r1[e] = (short)f2bf(x1 * ch[e] - x3 * sh[e]);
      r2[e] = (short)f2bf(x2 * cl[e] + x0 * sl[e]);
      r3[e] = (short)f2bf(x3 * ch[e] + x1 * sh[e]);
    }
    qf[qr][0] = *(bf8_t*)&r0; qf[qr][1] = *(bf8_t*)&r1;
    qf[qr][2] = *(bf8_t*)&r2; qf[qr][3] = *(bf8_t*)&r3;
  }

  f4_t o[2][8] = {};
  f4_t lacc[2] = {};

  // stage K (64x128) and V (128x64): 256 threads x 4 x 8 elems each
  auto ldK = [&](int s0, int i) {
    int idx = i * 256 + t, s = idx >> 4, c = idx & 15;
    return *(const s8_t*)&Kp[(size_t)(s0 + s) * 128 + ((c ^ (s & 7)) * 8)];
  };
  auto ldV = [&](int s0, int i) {
    int idx = i * 256 + t, d = idx >> 3, c = idx & 7;
    return *(const s8_t*)&Vp[(size_t)d * 1024 + s0 + ((c ^ (d & 7)) * 8)];
  };
  s8_t kr[4], vr[4];
#pragma unroll
  for (int i = 0; i < 4; ++i) { kr[i] = ldK(0, i); vr[i] = ldV(0, i); }

  for (int s0 = 0; s0 < 1024; s0 += 64) {
    __builtin_amdgcn_s_barrier();
#pragma unroll
    for (int i = 0; i < 4; ++i) {
      *(s8_t*)&Ks[((size_t)(i * 256 + t)) * 8] = kr[i];
      *(s8_t*)&Vs[((size_t)(i * 256 + t)) * 8] = vr[i];
    }
    int sn = (s0 < 960) ? s0 + 64 : 0;
#pragma unroll
    for (int i = 0; i < 4; ++i) { kr[i] = ldK(sn, i); vr[i] = ldV(sn, i); }
    asm volatile("s_waitcnt lgkmcnt(0)" ::: "memory");
    __builtin_amdgcn_s_barrier();

    // QK^T: 16 kf reads feed 32 MFMAs (2 q-frags)
    f4_t sf[2][4];
    __builtin_amdgcn_s_setprio(1);
#pragma unroll
    for (int ss = 0; ss < 4; ++ss) {
      f4_t c0 = {0.0f, 0.0f, 0.0f, 0.0f};
      f4_t c1 = {0.0f, 0.0f, 0.0f, 0.0f};
#pragma unroll
      for (int kk = 0; kk < 4; ++kk) {
        bf8_t kf = *(const bf8_t*)&Ks[(ss * 16 + lr) * 128 + (((kk * 4 + lg) ^ (lr & 7)) * 8)];
        c0 = __builtin_amdgcn_mfma_f32_16x16x32_bf16(kf, qf[0][kk], c0, 0, 0, 0);
        c1 = __builtin_amdgcn_mfma_f32_16x16x32_bf16(kf, qf[1][kk], c1, 0, 0, 0);
      }
      sf[0][ss] = c0; sf[1][ss] = c1;
    }
    __builtin_amdgcn_s_setprio(0);
    // fixed-shift softmax, packed bf16 via HW cvt_pk
#pragma unroll
    for (int qr = 0; qr < 2; ++qr)
#pragma unroll
      for (int ss = 0; ss < 4; ++ss) {
        float p0 = exp2f(sf[qr][ss][0] * C1 - C2);
        float p1 = exp2f(sf[qr][ss][1] * C1 - C2);
        float p2 = exp2f(sf[qr][ss][2] * C1 - C2);
        float p3 = exp2f(sf[qr][ss][3] * C1 - C2);
        unsigned lo, hi;
        asm("v_cvt_pk_bf16_f32 %0, %1, %2" : "=v"(lo) : "v"(p0), "v"(p1));
        asm("v_cvt_pk_bf16_f32 %0, %1, %2" : "=v"(hi) : "v"(p2), "v"(p3));
        unsigned pk2[2] = {lo, hi};
        *(s4_t*)&Pw[(qr * 16 + lr) * 72 + ss * 16 + lg * 4] = *(s4_t*)pk2;
      }
    bf8_t pa[2][2];
#pragma unroll
    for (int qr = 0; qr < 2; ++qr) {
      pa[qr][0] = *(const bf8_t*)&Pw[(qr * 16 + lr) * 72 + lg * 8];
      pa[qr][1] = *(const bf8_t*)&Pw[(qr * 16 + lr) * 72 + 32 + lg * 8];
    }
    __builtin_amdgcn_s_setprio(1);
#pragma unroll
    for (int n = 0; n < 8; ++n) {
      int d = n * 16 + lr;
      bf8_t v0 = *(const bf8_t*)&Vs[d * 64 + (((0 + lg) ^ (lr & 7)) * 8)];
      bf8_t v1 = *(const bf8_t*)&Vs[d * 64 + (((4 + lg) ^ (lr & 7)) * 8)];
      o[0][n] = __builtin_amdgcn_mfma_f32_16x16x32_bf16(pa[0][0], v0, o[0][n], 0, 0, 0);
      o[0][n] = __builtin_amdgcn_mfma_f32_16x16x32_bf16(pa[0][1], v1, o[0][n], 0, 0, 0);
      o[1][n] = __builtin_amdgcn_mfma_f32_16x16x32_bf16(pa[1][0], v0, o[1][n], 0, 0, 0);
      o[1][n] = __builtin_amdgcn_mfma_f32_16x16x32_bf16(pa[1][1], v1, o[1][n], 0, 0, 0);
    }
#pragma unroll
    for (int qr = 0; qr < 2; ++qr) {
      lacc[qr] = __builtin_amdgcn_mfma_f32_16x16x32_bf16(pa[qr][0], ones, lacc[qr], 0, 0, 0);
      lacc[qr] = __builtin_amdgcn_mfma_f32_16x16x32_bf16(pa[qr][1], ones, lacc[qr], 0, 0, 0);
    }
    __builtin_amdgcn_s_setprio(0);
  }

#pragma unroll
  for (int qr = 0; qr < 2; ++qr) {
    float linv[4];
#pragma unroll
    for (int j = 0; j < 4; ++j) linv[j] = 1.0f / lacc[qr][j];
#pragma unroll
    for (int n = 0; n < 8; ++n)
#pragma unroll
      for (int j = 0; j < 4; ++j) {
        int qg = q0 + qr * 16 + lg * 4 + j;
        Y[((size_t)b * 1024 + qg) * 2048 + h * 128 + n * 16 + lr] =
            f2bf(o[qr][n][j] * linv[j]);
      }
  }
}

// ---------- launch ----------
extern "C" void kernel_launch(void* const* d_in, const int* in_sizes, int n_in,
                              void* d_out, int out_size, void* d_ws, size_t ws_size,
                              hipStream_t stream) {
  const float* x  = (const float*)d_in[0];
  const float* dl = (const float*)d_in[1];
  const float* W[4] = {(const float*)d_in[2], (const float*)d_in[3],
                       (const float*)d_in[4], (const float*)d_in[5]};
  char* ws = (char*)d_ws;
  size_t off = 0;
  auto take = [&](size_t bytes) {
    void* p = ws + off; off += (bytes + 255) & ~(size_t)255; return p;
  };
  unsigned short* xb = (unsigned short*)take(8388608ull * 2);
  unsigned short* Wb[4];
  for (int i = 0; i < 4; ++i) Wb[i] = (unsigned short*)take(4194304ull * 2);
  unsigned short* qb = (unsigned short*)take(8388608ull * 2);
  unsigned short* kb = (unsigned short*)take(8388608ull * 2);
  unsigned short* vT = (unsigned short*)take(8388608ull * 2);
  unsigned short* y  = (unsigned short*)take(8388608ull * 2);
  float* u    = (float*)take(4ull * UOFF * 4);
  float* cosT = (float*)take(1024ull * 64 * 4);
  float* sinT = (float*)take(1024ull * 64 * 4);
  unsigned short* dlb = (unsigned short*)take(1048576ull * 2);
  if (off > ws_size) return;

  ConvArgs ca;
  ca.src[0] = x;  ca.dst[0] = xb;  ca.n4[0] = 2097152;
  for (int i = 0; i < 4; ++i) { ca.src[1 + i] = W[i]; ca.dst[1 + i] = Wb[i]; ca.n4[1 + i] = 1048576; }
  ca.src[5] = dl; ca.dst[5] = dlb; ca.n4[5] = 262144;
  ca.thr[0] = 8192; ca.thr[1] = 12288; ca.thr[2] = 16384; ca.thr[3] = 20480; ca.thr[4] = 24576;
  k_conv_all<<<25600, 256, 0, stream>>>(ca);
  k_rope_table<<<1024, 64, 0, stream>>>(cosT, sinT);
  k_lora_mfma<<<dim3(16, 4, 4), 256, 0, stream>>>(xb, dlb, u, 0, 3);

  GArgs gq;
  gq.Bw0 = Wb[0]; gq.o0 = qb;    gq.m0_ = 0; gq.p0_ = 0;
  gq.Bw1 = Wb[1]; gq.o1 = kb;    gq.m1_ = 0; gq.p1_ = 1;
  gq.Bw2 = Wb[2]; gq.o2 = vT;    gq.m2_ = 1; gq.p2_ = 2;
  k_gemm<<<dim3(16, 32, 3), 256, 0, stream>>>(xb, gq, u, dl);

  k_rope<<<2048, 256, 0, stream>>>(kb, cosT, sinT);
  k_attn<<<512, 256, 0, stream>>>(qb, kb, vT, cosT, sinT, y);
  k_lora_mfma<<<dim3(16, 4, 4), 256, 0, stream>>>(y, dlb, u, 3, 1);

  GArgs go;
  go.Bw0 = Wb[3]; go.o0 = d_out; go.m0_ = 2; go.p0_ = 3;
  go.Bw1 = Wb[3]; go.o1 = d_out; go.m1_ = 2; go.p1_ = 3;
  go.Bw2 = Wb[3]; go.o2 = d_out; go.m2_ = 2; go.p2_ = 3;
  k_gemm<<<dim3(16, 32, 1), 256, 0, stream>>>(y, go, u, dl);
}